// Round 3
// baseline (2322.427 us; speedup 1.0000x reference)
//
#include <hip/hip_runtime.h>
#include <math.h>

// ---------------------------------------------------------------------------
// Register-tiled direct conv.
// Block: 256 threads, 32x32 spatial tile, OCB output channels.
// Thread t: x = t&31, y = (t>>5) + {0,8,16,24}  -> 4 pixels x OCB accs.
// Input staged in LDS in CC-channel chunks; weights are wave-uniform ->
// scalar loads (verified round 2: SGPR=112, weight loads scalarize).
// ACT: 0=none 1=relu 2=tanh 3=sigmoid
// ---------------------------------------------------------------------------
template<int K, int ACT, int OCB, int CC>
__global__ __launch_bounds__(256)
void conv2d_rt(const float* __restrict__ in, const float* __restrict__ w,
               const float* __restrict__ bias, float* __restrict__ out,
               int B, int Cin, int H, int Wd, int Cout)
{
    constexpr int PAD = K / 2;
    constexpr int TW = 32, TH = 32;
    constexpr int T  = TW + K - 1;      // staged width
    constexpr int TT = TH + K - 1;      // staged height
    constexpr int LDW = T + 2;          // pad stride (bank spread)
    constexpr int KK = K * K;
    __shared__ float tile[CC][TT][LDW];

    const int tid = threadIdx.x;
    const int lx = tid & 31;
    const int ly = tid >> 5;            // 0..7
    const int tilesX = (Wd + TW - 1) / TW;
    const int bx = blockIdx.x % tilesX, by = blockIdx.x / tilesX;
    const int x0 = bx * TW, y0 = by * TH;
    const int oc0 = blockIdx.y * OCB;
    const int b = blockIdx.z;

    // clamped weight bases (uniform -> SGPR)
    int woff[OCB];
#pragma unroll
    for (int o = 0; o < OCB; ++o) {
        int oc = oc0 + o;
        if (oc > Cout - 1) oc = Cout - 1;
        woff[o] = oc * Cin * KK;
    }

    float acc[4][OCB];
#pragma unroll
    for (int j = 0; j < 4; ++j)
#pragma unroll
        for (int o = 0; o < OCB; ++o) acc[j][o] = 0.f;

    for (int c0 = 0; c0 < Cin; c0 += CC) {
        __syncthreads();
        // stage CC channels of TT x T (xx fastest -> coalesced)
        for (int i = tid; i < CC * TT * T; i += 256) {
            int cc = i / (TT * T);
            int r  = i - cc * (TT * T);
            int yy = r / T, xx = r - yy * T;
            int iy = y0 + yy - PAD, ix = x0 + xx - PAD;
            int ci = c0 + cc;
            float v = 0.f;
            if (iy >= 0 && iy < H && ix >= 0 && ix < Wd && ci < Cin)
                v = in[((b * Cin + ci) * H + iy) * Wd + ix];
            tile[cc][yy][xx] = v;
        }
        __syncthreads();
        int ncc = Cin - c0; if (ncc > CC) ncc = CC;
        for (int cc = 0; cc < ncc; ++cc) {
            const float* wch = w + (c0 + cc) * KK;
#pragma unroll
            for (int ky = 0; ky < K; ++ky) {
#pragma unroll
                for (int kx = 0; kx < K; ++kx) {
                    float wv[OCB];
#pragma unroll
                    for (int o = 0; o < OCB; ++o)
                        wv[o] = wch[woff[o] + ky * K + kx];   // uniform -> s_load
#pragma unroll
                    for (int j = 0; j < 4; ++j) {
                        float v = tile[cc][ly + 8 * j + ky][lx + kx];
#pragma unroll
                        for (int o = 0; o < OCB; ++o)
                            acc[j][o] = fmaf(v, wv[o], acc[j][o]);
                    }
                }
            }
        }
    }

    const int ox = x0 + lx;
    if (ox < Wd) {
#pragma unroll
        for (int j = 0; j < 4; ++j) {
            int oy = y0 + ly + 8 * j;
            if (oy < H) {
#pragma unroll
                for (int o = 0; o < OCB; ++o) {
                    int oc = oc0 + o;
                    if (oc < Cout) {
                        float r = acc[j][o] + bias[oc];
                        if (ACT == 1) r = fmaxf(r, 0.f);
                        if (ACT == 2) r = tanhf(r);
                        if (ACT == 3) r = 1.f / (1.f + __expf(-r));
                        out[((b * Cout + oc) * H + oy) * Wd + ox] = r;
                    }
                }
            }
        }
    }
}

template<int K, int ACT, int CC>
static inline void conv_launch(const float* in, const float* w, const float* b, float* o,
                               int B, int Cin, int H, int W, int Cout, hipStream_t s)
{
    constexpr int OCB = 8;
    dim3 blk(256, 1, 1);
    int tcx = (W + 31) / 32, tcy = (H + 31) / 32;
    dim3 grd(tcx * tcy, (Cout + OCB - 1) / OCB, B);
    hipLaunchKernelGGL((conv2d_rt<K, ACT, OCB, CC>), grd, blk, 0, s,
                       in, w, b, o, B, Cin, H, W, Cout);
}

// ---------------------------------------------------------------------------
// 2x2 max pool, stride 2
// ---------------------------------------------------------------------------
__global__ void maxpool2_kernel(const float* __restrict__ in, float* __restrict__ out,
                                int total, int Ho, int Wo)
{
    int idx = blockIdx.x * 256 + threadIdx.x;
    if (idx >= total) return;
    int x = idx % Wo;
    int t = idx / Wo;
    int y = t % Ho;
    int bc = t / Ho;
    int Wi = Wo * 2;
    const float* p = in + ((bc * 2 * Ho + 2 * y) * Wi + 2 * x);
    out[idx] = fmaxf(fmaxf(p[0], p[1]), fmaxf(p[Wi], p[Wi + 1]));
}

// ---------------------------------------------------------------------------
// Fused 2x bilinear upsample (half-pixel centers, edge clamp) + channel concat
// ---------------------------------------------------------------------------
__global__ void upcat_kernel(const float* __restrict__ up, const float* __restrict__ skip,
                             float* __restrict__ dst, int B, int C1, int C2, int H, int W)
{
    int total = B * (C1 + C2) * H * W;
    int idx = blockIdx.x * 256 + threadIdx.x;
    if (idx >= total) return;
    int x = idx % W;
    int t = idx / W;
    int y = t % H;
    t /= H;
    int c = t % (C1 + C2);
    int b = t / (C1 + C2);
    float r;
    if (c < C1) {
        int Hi = H >> 1, Wi = W >> 1;
        float fy = 0.5f * y - 0.25f;
        float fx = 0.5f * x - 0.25f;
        float y0f = floorf(fy), x0f = floorf(fx);
        float wy = fy - y0f, wx = fx - x0f;
        int yA = (int)y0f, xA = (int)x0f;
        int yB = yA + 1, xB = xA + 1;
        yA = yA < 0 ? 0 : (yA > Hi - 1 ? Hi - 1 : yA);
        yB = yB < 0 ? 0 : (yB > Hi - 1 ? Hi - 1 : yB);
        xA = xA < 0 ? 0 : (xA > Wi - 1 ? Wi - 1 : xA);
        xB = xB < 0 ? 0 : (xB > Wi - 1 ? Wi - 1 : xB);
        const float* sp = up + ((b * C1 + c) * Hi) * Wi;
        float v00 = sp[yA * Wi + xA], v01 = sp[yA * Wi + xB];
        float v10 = sp[yB * Wi + xA], v11 = sp[yB * Wi + xB];
        r = (1.f - wy) * ((1.f - wx) * v00 + wx * v01) +
            wy * ((1.f - wx) * v10 + wx * v11);
    } else {
        r = skip[((b * C2 + (c - C1)) * H + y) * W + x];
    }
    dst[idx] = r;
}

// ---------------------------------------------------------------------------
// LRNN scans.  h = (1-p)*x + p*h_prev = fma(p, h_prev - x, x), h0 = 0.
// Reverse outputs stay spatially flipped (reference semantics).
// W-scans: fm channels {c, 32+c}; H-scans: {16+c, 48+c}.
// Software-pipelined: next iteration's loads issue before the serial
// recurrence chain (R2: these kernels were latency-bound, ~1 TB/s eff).
// ---------------------------------------------------------------------------
__global__ void lrnn_w_kernel(const float* __restrict__ X, const float* __restrict__ FM,
                              float* __restrict__ out, int B, int H, int W,
                              int rev, int init)
{
    int total = B * 16 * H;
    int idx = blockIdx.x * 256 + threadIdx.x;
    if (idx >= total) return;
    int y = idx % H;
    int c = (idx / H) & 15;
    int b = idx / (H * 16);
    const float4* xr  = (const float4*)(X  + (size_t)((b * 16 + c) * H + y) * W);
    const float4* p1r = (const float4*)(FM + (size_t)((b * 64 + c) * H + y) * W);
    const float4* p2r = (const float4*)(FM + (size_t)((b * 64 + 32 + c) * H + y) * W);
    float4* orow = (float4*)(out + (size_t)((b * 16 + c) * H + y) * W);
    int nv = W >> 2;
    float h1 = 0.f, h2 = 0.f;
    int rb0 = rev ? (nv - 1) : 0;
    float4 xv = xr[rb0], pa = p1r[rb0], pb = p2r[rb0];
    for (int v = 0; v < nv; ++v) {
        float4 xn = xv, pan = pa, pbn = pb;
        if (v + 1 < nv) {
            int rb = rev ? (nv - 2 - v) : (v + 1);
            xn = xr[rb]; pan = p1r[rb]; pbn = p2r[rb];
        }
        float4 ov;
        if (!init) ov = orow[v];
        float4 m;
        if (!rev) {
            h1 = fmaf(pa.x, h1 - xv.x, xv.x); h2 = fmaf(pb.x, h2 - xv.x, xv.x); m.x = fmaxf(h1, h2);
            h1 = fmaf(pa.y, h1 - xv.y, xv.y); h2 = fmaf(pb.y, h2 - xv.y, xv.y); m.y = fmaxf(h1, h2);
            h1 = fmaf(pa.z, h1 - xv.z, xv.z); h2 = fmaf(pb.z, h2 - xv.z, xv.z); m.z = fmaxf(h1, h2);
            h1 = fmaf(pa.w, h1 - xv.w, xv.w); h2 = fmaf(pb.w, h2 - xv.w, xv.w); m.w = fmaxf(h1, h2);
        } else {
            h1 = fmaf(pa.w, h1 - xv.w, xv.w); h2 = fmaf(pb.w, h2 - xv.w, xv.w); m.x = fmaxf(h1, h2);
            h1 = fmaf(pa.z, h1 - xv.z, xv.z); h2 = fmaf(pb.z, h2 - xv.z, xv.z); m.y = fmaxf(h1, h2);
            h1 = fmaf(pa.y, h1 - xv.y, xv.y); h2 = fmaf(pb.y, h2 - xv.y, xv.y); m.z = fmaxf(h1, h2);
            h1 = fmaf(pa.x, h1 - xv.x, xv.x); h2 = fmaf(pb.x, h2 - xv.x, xv.x); m.w = fmaxf(h1, h2);
        }
        if (!init) {
            m.x = fmaxf(m.x, ov.x); m.y = fmaxf(m.y, ov.y);
            m.z = fmaxf(m.z, ov.z); m.w = fmaxf(m.w, ov.w);
        }
        orow[v] = m;
        xv = xn; pa = pan; pb = pbn;
    }
}

__global__ void lrnn_h_kernel(const float* __restrict__ X, const float* __restrict__ FM,
                              float* __restrict__ out, int B, int H, int W, int rev)
{
    int total = B * 16 * W;
    int idx = blockIdx.x * 256 + threadIdx.x;
    if (idx >= total) return;
    int x = idx % W;
    int c = (idx / W) & 15;
    int b = idx / (W * 16);
    const float* xc  = X  + (size_t)((b * 16 + c) * H) * W + x;
    const float* p1c = FM + (size_t)((b * 64 + 16 + c) * H) * W + x;
    const float* p2c = FM + (size_t)((b * 64 + 48 + c) * H) * W + x;
    float* ocp = out + (size_t)((b * 16 + c) * H) * W + x;
    float h1 = 0.f, h2 = 0.f;
    // depth-2 pipeline: a = iter i, b = iter i+1
    int y0 = rev ? (H - 1) : 0;
    int y1 = rev ? (H - 2) : 1;
    float xa = xc[y0 * W], pa1 = p1c[y0 * W], pa2 = p2c[y0 * W], oa = ocp[0];
    float xb = xc[y1 * W], pb1 = p1c[y1 * W], pb2 = p2c[y1 * W], ob = ocp[W];
    for (int i = 0; i < H; ++i) {
        float xn = 0.f, pn1 = 0.f, pn2 = 0.f, on = 0.f;
        if (i + 2 < H) {
            int yr = rev ? (H - 3 - i) : (i + 2);
            xn = xc[yr * W]; pn1 = p1c[yr * W]; pn2 = p2c[yr * W]; on = ocp[(i + 2) * W];
        }
        h1 = fmaf(pa1, h1 - xa, xa);
        h2 = fmaf(pa2, h2 - xa, xa);
        ocp[i * W] = fmaxf(oa, fmaxf(h1, h2));
        xa = xb; pa1 = pb1; pa2 = pb2; oa = ob;
        xb = xn; pb1 = pn1; pb2 = pn2; ob = on;
    }
}

// ---------------------------------------------------------------------------
extern "C" void kernel_launch(void* const* d_in, const int* in_sizes, int n_in,
                              void* d_out, int out_size, void* d_ws, size_t ws_size,
                              hipStream_t stream)
{
    const float* img = (const float*)d_in[0];
    const float* w1 = (const float*)d_in[1];  const float* b1 = (const float*)d_in[2];
    const float* w2 = (const float*)d_in[3];  const float* b2 = (const float*)d_in[4];
    const float* w3 = (const float*)d_in[5];  const float* b3 = (const float*)d_in[6];
    const float* w4 = (const float*)d_in[7];  const float* b4 = (const float*)d_in[8];
    const float* w5 = (const float*)d_in[9];  const float* b5 = (const float*)d_in[10];
    const float* w6 = (const float*)d_in[11]; const float* b6 = (const float*)d_in[12];
    const float* w7 = (const float*)d_in[13]; const float* b7 = (const float*)d_in[14];
    const float* w8 = (const float*)d_in[15]; const float* b8 = (const float*)d_in[16];
    const float* w9 = (const float*)d_in[17]; const float* b9 = (const float*)d_in[18];
    const float* wi = (const float*)d_in[19]; const float* bi = (const float*)d_in[20];
    const float* wo = (const float*)d_in[21]; const float* bo = (const float*)d_in[22];

    float* ws = (float*)d_ws;
    const size_t MBf = (size_t)(1u << 20) / 4;  // floats per MiB
    // Bump allocation with reuse; peak = 228 MiB.
    float* x1   = ws;                 // [0,32)    [8,16,256,256]
    float* p1   = ws + 32 * MBf;      // [32,40)   [8,16,128,128]
    float* x2   = ws + 40 * MBf;      // [40,56)   [8,32,128,128]
    float* p2   = ws + 56 * MBf;      // [56,60)   [8,32,64,64]
    float* x3   = ws + 60 * MBf;      // [60,64)   [8,32,64,64]
    float* p3   = ws + 64 * MBf;      // [64,65)   [8,32,32,32]
    float* x4   = ws + 65 * MBf;      // [65,66)   [8,32,32,32]
    float* p4   = ws + 66 * MBf;      // [66,67)   [8,32,16,16]
    float* x5   = ws + 67 * MBf;      // [67,68)   [8,64,16,16]
    float* cat6 = ws + 68 * MBf;      // [68,71)   [8,96,32,32]
    float* x6   = ws + 71 * MBf;      // [71,72)   [8,32,32,32]
    float* cat7 = ws + 72 * MBf;      // [72,80)   [8,64,64,64]
    float* x7   = ws + 80 * MBf;      // [80,84)   [8,32,64,64]
    float* cat8 = ws + 84 * MBf;      // [84,116)  [8,64,128,128]  32 MiB
    float* x8   = ws + 116 * MBf;     // [116,132) [8,32,128,128]  16 MiB
    float* cat9 = ws + 132 * MBf;     // [132,228) [8,48,256,256]  96 MiB
    float* fm   = ws;                 // [0,128)   [8,64,256,256]  (x1..x8 dead)
    float* xin  = ws + 132 * MBf;     // [132,164) reuses cat9 (dead after fm conv)
    float* rnn  = ws + 164 * MBf;     // [164,196)
    float* outp = (float*)d_out;

    const int B = 8;

    // --- encoder ---
    conv_launch<5, 1, 3>(img, w1, b1, x1, B, 15, 256, 256, 16, stream);
    { int tot = B * 16 * 128 * 128;
      maxpool2_kernel<<<(tot + 255) / 256, 256, 0, stream>>>(x1, p1, tot, 128, 128); }
    conv_launch<3, 1, 4>(p1, w2, b2, x2, B, 16, 128, 128, 32, stream);
    { int tot = B * 32 * 64 * 64;
      maxpool2_kernel<<<(tot + 255) / 256, 256, 0, stream>>>(x2, p2, tot, 64, 64); }
    conv_launch<3, 1, 4>(p2, w3, b3, x3, B, 32, 64, 64, 32, stream);
    { int tot = B * 32 * 32 * 32;
      maxpool2_kernel<<<(tot + 255) / 256, 256, 0, stream>>>(x3, p3, tot, 32, 32); }
    conv_launch<3, 1, 4>(p3, w4, b4, x4, B, 32, 32, 32, 32, stream);
    { int tot = B * 32 * 16 * 16;
      maxpool2_kernel<<<(tot + 255) / 256, 256, 0, stream>>>(x4, p4, tot, 16, 16); }
    conv_launch<3, 1, 4>(p4, w5, b5, x5, B, 32, 16, 16, 64, stream);

    // --- decoder ---
    { int tot = B * 96 * 32 * 32;
      upcat_kernel<<<(tot + 255) / 256, 256, 0, stream>>>(x5, x4, cat6, B, 64, 32, 32, 32); }
    conv_launch<3, 1, 4>(cat6, w6, b6, x6, B, 96, 32, 32, 32, stream);
    { int tot = B * 64 * 64 * 64;
      upcat_kernel<<<(tot + 255) / 256, 256, 0, stream>>>(x6, x3, cat7, B, 32, 32, 64, 64); }
    conv_launch<3, 1, 4>(cat7, w7, b7, x7, B, 64, 64, 64, 32, stream);
    { int tot = B * 64 * 128 * 128;
      upcat_kernel<<<(tot + 255) / 256, 256, 0, stream>>>(x7, x2, cat8, B, 32, 32, 128, 128); }
    conv_launch<3, 1, 4>(cat8, w8, b8, x8, B, 64, 128, 128, 32, stream);
    { int tot = B * 48 * 256 * 256;
      upcat_kernel<<<(tot + 255) / 256, 256, 0, stream>>>(x8, x1, cat9, B, 32, 16, 256, 256); }
    conv_launch<3, 2, 4>(cat9, w9, b9, fm, B, 48, 256, 256, 64, stream);  // tanh -> fm

    // --- input projection ---
    conv_launch<3, 0, 3>(img, wi, bi, xin, B, 15, 256, 256, 16, stream);

    // --- spatial RNN: 8 directions, max-combined in place ---
    { int tot = B * 16 * 256; int g = (tot + 255) / 256;
      lrnn_w_kernel<<<g, 256, 0, stream>>>(xin, fm, rnn, B, 256, 256, 0, 1);
      lrnn_w_kernel<<<g, 256, 0, stream>>>(xin, fm, rnn, B, 256, 256, 1, 0);
      lrnn_h_kernel<<<g, 256, 0, stream>>>(xin, fm, rnn, B, 256, 256, 0);
      lrnn_h_kernel<<<g, 256, 0, stream>>>(xin, fm, rnn, B, 256, 256, 1); }

    // --- output head ---
    conv_launch<3, 3, 4>(rnn, wo, bo, outp, B, 16, 256, 256, 3, stream);
}

// Round 4
// 1433.490 us; speedup vs baseline: 1.6201x; 1.6201x over previous
//
#include <hip/hip_runtime.h>
#include <math.h>

typedef __attribute__((ext_vector_type(8)))  short bf16x8;
typedef __attribute__((ext_vector_type(16))) float f32x16;

__device__ __forceinline__ unsigned short f2bf(float f) {
    unsigned u = __float_as_uint(f);
    unsigned r = (u + 0x7FFFu + ((u >> 16) & 1u)) >> 16;
    return (unsigned short)r;
}
__device__ __forceinline__ float fast_tanh(float x) {
    float e = __expf(2.f * x);
    return 1.f - 2.f / (e + 1.f);
}

// ---------------------------------------------------------------------------
// Small-layer conv (R2 kernel): 16x16 spatial tile, 8 oc/block, CHUNK=4.
// ---------------------------------------------------------------------------
template<int K, int ACT, int OCB>
__global__ __launch_bounds__(256)
void conv2d_s(const float* __restrict__ in, const float* __restrict__ w,
              const float* __restrict__ bias, float* __restrict__ out,
              int B, int Cin, int H, int Wd, int Cout)
{
    constexpr int PAD = K / 2;
    constexpr int T = 16 + K - 1;
    constexpr int KK = K * K;
    constexpr int CH = 4;
    __shared__ float tile[CH][T][T + 1];

    const int tx = threadIdx.x, ty = threadIdx.y;
    const int tid = ty * 16 + tx;
    const int tilesX = (Wd + 15) >> 4;
    const int bx = blockIdx.x % tilesX, by = blockIdx.x / tilesX;
    const int x0 = bx * 16, y0 = by * 16;
    const int ox = x0 + tx, oy = y0 + ty;
    const int oc0 = blockIdx.y * OCB;
    const int b = blockIdx.z;

    int wb[OCB];
#pragma unroll
    for (int o = 0; o < OCB; ++o) {
        int oc = oc0 + o;
        if (oc > Cout - 1) oc = Cout - 1;
        wb[o] = oc * Cin * KK;
    }
    float acc[OCB];
#pragma unroll
    for (int o = 0; o < OCB; ++o) acc[o] = 0.f;

    for (int c0 = 0; c0 < Cin; c0 += CH) {
        int nc = Cin - c0; if (nc > CH) nc = CH;
        __syncthreads();
        for (int i = tid; i < nc * T * T; i += 256) {
            int cc = i / (T * T);
            int r = i - cc * T * T;
            int yy = r / T, xx = r - yy * T;
            int iy = y0 + yy - PAD, ix = x0 + xx - PAD;
            float v = 0.f;
            if (iy >= 0 && iy < H && ix >= 0 && ix < Wd)
                v = in[((b * Cin + c0 + cc) * H + iy) * Wd + ix];
            tile[cc][yy][xx] = v;
        }
        __syncthreads();
        for (int cc = 0; cc < nc; ++cc) {
            const float* wp = w + (c0 + cc) * KK;
#pragma unroll
            for (int ky = 0; ky < K; ++ky)
#pragma unroll
                for (int kx = 0; kx < K; ++kx) {
                    float v = tile[cc][ty + ky][tx + kx];
#pragma unroll
                    for (int o = 0; o < OCB; ++o)
                        acc[o] = fmaf(v, wp[wb[o] + ky * K + kx], acc[o]);
                }
        }
    }
    if (ox < Wd && oy < H) {
#pragma unroll
        for (int o = 0; o < OCB; ++o) {
            int oc = oc0 + o;
            if (oc < Cout) {
                float r = acc[o] + bias[oc];
                if (ACT == 1) r = fmaxf(r, 0.f);
                if (ACT == 2) r = fast_tanh(r);
                if (ACT == 3) r = 1.f / (1.f + __expf(-r));
                out[((b * Cout + oc) * H + oy) * Wd + ox] = r;
            }
        }
    }
}

template<int K, int ACT>
static inline void conv_s(const float* in, const float* w, const float* b, float* o,
                          int B, int Cin, int H, int W, int Cout, hipStream_t s)
{
    dim3 blk(16, 16, 1);
    int tcx = (W + 15) / 16, tcy = (H + 15) / 16;
    dim3 grd(tcx * tcy, (Cout + 7) / 8, B);
    hipLaunchKernelGGL((conv2d_s<K, ACT, 8>), grd, blk, 0, s, in, w, b, o, B, Cin, H, W, Cout);
}

// ---------------------------------------------------------------------------
// Big-layer conv (R3 kernel): 32x32 tile, 4 px x 8 oc per thread.
// ---------------------------------------------------------------------------
template<int K, int ACT, int OCB, int CC>
__global__ __launch_bounds__(256)
void conv2d_rt(const float* __restrict__ in, const float* __restrict__ w,
               const float* __restrict__ bias, float* __restrict__ out,
               int B, int Cin, int H, int Wd, int Cout)
{
    constexpr int PAD = K / 2;
    constexpr int TW = 32, TH = 32;
    constexpr int T  = TW + K - 1;
    constexpr int TT = TH + K - 1;
    constexpr int LDW = T + 2;
    constexpr int KK = K * K;
    __shared__ float tile[CC][TT][LDW];

    const int tid = threadIdx.x;
    const int lx = tid & 31;
    const int ly = tid >> 5;
    const int tilesX = (Wd + TW - 1) / TW;
    const int bx = blockIdx.x % tilesX, by = blockIdx.x / tilesX;
    const int x0 = bx * TW, y0 = by * TH;
    const int oc0 = blockIdx.y * OCB;
    const int b = blockIdx.z;

    int woff[OCB];
#pragma unroll
    for (int o = 0; o < OCB; ++o) {
        int oc = oc0 + o;
        if (oc > Cout - 1) oc = Cout - 1;
        woff[o] = oc * Cin * KK;
    }
    float acc[4][OCB];
#pragma unroll
    for (int j = 0; j < 4; ++j)
#pragma unroll
        for (int o = 0; o < OCB; ++o) acc[j][o] = 0.f;

    for (int c0 = 0; c0 < Cin; c0 += CC) {
        __syncthreads();
        for (int i = tid; i < CC * TT * T; i += 256) {
            int cc = i / (TT * T);
            int r  = i - cc * (TT * T);
            int yy = r / T, xx = r - yy * T;
            int iy = y0 + yy - PAD, ix = x0 + xx - PAD;
            int ci = c0 + cc;
            float v = 0.f;
            if (iy >= 0 && iy < H && ix >= 0 && ix < Wd && ci < Cin)
                v = in[((b * Cin + ci) * H + iy) * Wd + ix];
            tile[cc][yy][xx] = v;
        }
        __syncthreads();
        int ncc = Cin - c0; if (ncc > CC) ncc = CC;
        for (int cc = 0; cc < ncc; ++cc) {
            const float* wch = w + (c0 + cc) * KK;
#pragma unroll
            for (int ky = 0; ky < K; ++ky)
#pragma unroll
                for (int kx = 0; kx < K; ++kx) {
                    float wv[OCB];
#pragma unroll
                    for (int o = 0; o < OCB; ++o)
                        wv[o] = wch[woff[o] + ky * K + kx];
#pragma unroll
                    for (int j = 0; j < 4; ++j) {
                        float v = tile[cc][ly + 8 * j + ky][lx + kx];
#pragma unroll
                        for (int o = 0; o < OCB; ++o)
                            acc[j][o] = fmaf(v, wv[o], acc[j][o]);
                    }
                }
        }
    }
    const int ox = x0 + lx;
    if (ox < Wd) {
#pragma unroll
        for (int j = 0; j < 4; ++j) {
            int oy = y0 + ly + 8 * j;
            if (oy < H) {
#pragma unroll
                for (int o = 0; o < OCB; ++o) {
                    int oc = oc0 + o;
                    if (oc < Cout) {
                        float r = acc[j][o] + bias[oc];
                        if (ACT == 1) r = fmaxf(r, 0.f);
                        if (ACT == 2) r = fast_tanh(r);
                        if (ACT == 3) r = 1.f / (1.f + __expf(-r));
                        out[((b * Cout + oc) * H + oy) * Wd + ox] = r;
                    }
                }
            }
        }
    }
}

template<int K, int ACT, int CC>
static inline void conv_rt(const float* in, const float* w, const float* b, float* o,
                           int B, int Cin, int H, int W, int Cout, hipStream_t s)
{
    constexpr int OCB = 8;
    dim3 blk(256, 1, 1);
    int tcx = (W + 31) / 32, tcy = (H + 31) / 32;
    dim3 grd(tcx * tcy, (Cout + OCB - 1) / OCB, B);
    hipLaunchKernelGGL((conv2d_rt<K, ACT, OCB, CC>), grd, blk, 0, s, in, w, b, o, B, Cin, H, W, Cout);
}

// ---------------------------------------------------------------------------
// maxpool / upcat (fp32 path, stages 6-8)
// ---------------------------------------------------------------------------
__global__ void maxpool2_kernel(const float* __restrict__ in, float* __restrict__ out,
                                int total, int Ho, int Wo)
{
    int idx = blockIdx.x * 256 + threadIdx.x;
    if (idx >= total) return;
    int x = idx % Wo;
    int t = idx / Wo;
    int y = t % Ho;
    int bc = t / Ho;
    int Wi = Wo * 2;
    const float* p = in + ((bc * 2 * Ho + 2 * y) * Wi + 2 * x);
    out[idx] = fmaxf(fmaxf(p[0], p[1]), fmaxf(p[Wi], p[Wi + 1]));
}

__device__ __forceinline__ float bilin(const float* __restrict__ sp, int y, int x, int Hi, int Wi)
{
    float fy = 0.5f * y - 0.25f;
    float fx = 0.5f * x - 0.25f;
    float y0f = floorf(fy), x0f = floorf(fx);
    float wy = fy - y0f, wx = fx - x0f;
    int yA = (int)y0f, xA = (int)x0f;
    int yB = yA + 1, xB = xA + 1;
    yA = yA < 0 ? 0 : (yA > Hi - 1 ? Hi - 1 : yA);
    yB = yB < 0 ? 0 : (yB > Hi - 1 ? Hi - 1 : yB);
    xA = xA < 0 ? 0 : (xA > Wi - 1 ? Wi - 1 : xA);
    xB = xB < 0 ? 0 : (xB > Wi - 1 ? Wi - 1 : xB);
    float v00 = sp[yA * Wi + xA], v01 = sp[yA * Wi + xB];
    float v10 = sp[yB * Wi + xA], v11 = sp[yB * Wi + xB];
    return (1.f - wy) * ((1.f - wx) * v00 + wx * v01) +
           wy * ((1.f - wx) * v10 + wx * v11);
}

__global__ void upcat_kernel(const float* __restrict__ up, const float* __restrict__ skip,
                             float* __restrict__ dst, int B, int C1, int C2, int H, int W)
{
    int total = B * (C1 + C2) * H * W;
    int idx = blockIdx.x * 256 + threadIdx.x;
    if (idx >= total) return;
    int x = idx % W;
    int t = idx / W;
    int y = t % H;
    t /= H;
    int c = t % (C1 + C2);
    int b = t / (C1 + C2);
    float r;
    if (c < C1) r = bilin(up + ((size_t)(b * C1 + c) * (H >> 1)) * (W >> 1), y, x, H >> 1, W >> 1);
    else        r = skip[((b * C2 + (c - C1)) * H + y) * W + x];
    dst[idx] = r;
}

// ---------------------------------------------------------------------------
// Stage-9 upcat -> bf16 transposed layout xt9[b][y][x][ci=48]
// ci 0..31 = bilinear-up(x8 [8,32,128,128]); ci 32..47 = x1 skip.
// ---------------------------------------------------------------------------
__global__ void upcat9_bf16(const float* __restrict__ x8, const float* __restrict__ x1,
                            unsigned short* __restrict__ dst)
{
    int idx = blockIdx.x * 256 + threadIdx.x;
    int total = 8 * 256 * 256 * 48;
    if (idx >= total) return;
    int c = idx % 48;
    int t = idx / 48;
    int x = t & 255; t >>= 8;
    int y = t & 255; t >>= 8;
    int b = t;
    float r;
    if (c < 32) r = bilin(x8 + ((size_t)(b * 32 + c) * 128) * 128, y, x, 128, 128);
    else        r = x1[((b * 16 + (c - 32)) * 256 + y) * 256 + x];
    dst[idx] = f2bf(r);
}

// ---------------------------------------------------------------------------
// Pack w9 [64][48][3][3] fp32 -> bf16 A-fragments for mfma_f32_32x32x16_bf16.
// wpk[(((s*3+kst)*2+mt)*64 + lane)*8 + j] = w9[oc=mt*32+(lane&31)]
//   [ci=kst*16+(lane>>5)*8+j][dy=s/3][dx=s%3]
// ---------------------------------------------------------------------------
__global__ void wprep9(const float* __restrict__ w9, unsigned short* __restrict__ wpk)
{
    int idx = blockIdx.x * 256 + threadIdx.x;
    if (idx >= 27648) return;
    int j = idx & 7;
    int t = idx >> 3;
    int lane = t & 63; t >>= 6;
    int mt = t & 1; t >>= 1;
    int kst = t % 3;
    int s = t / 3;
    int oc = mt * 32 + (lane & 31);
    int ci = kst * 16 + (lane >> 5) * 8 + j;
    wpk[idx] = f2bf(w9[(oc * 48 + ci) * 9 + s]);
}

// ---------------------------------------------------------------------------
// conv9 via MFMA: 3x3 conv as 9 shifted GEMMs, K=48 (3 x 16-steps).
// Block: 4 waves, covers one row y, 128-px strip, all 64 oc.
// Wave w: pixels x0 + w*32 + [0,32); both 32-oc m-tiles (acc0, acc1).
// LDS: input window [3 rows][130 x][48 ci] bf16.
// Output: fm fp32 NCHW with tanh.
// ---------------------------------------------------------------------------
__global__ __launch_bounds__(256)
void conv9_mfma(const unsigned short* __restrict__ xt9,
                const unsigned short* __restrict__ wpk,
                const float* __restrict__ bias,
                float* __restrict__ fm)
{
    __shared__ __align__(16) unsigned short smem[3 * 130 * 48];  // 37440 B

    const int tid  = threadIdx.x;
    const int lane = tid & 63;
    const int wv   = tid >> 6;          // wave 0..3
    const int n    = lane & 31;         // pixel within wave tile
    const int q    = lane >> 5;         // k half
    const int y    = blockIdx.x >> 1;
    const int x0   = (blockIdx.x & 1) * 128;
    const int b    = blockIdx.y;

    // ---- stage input window: rows y-1..y+1, x0-1..x0+128, 48 ci (bf16) ----
    for (int i = tid; i < 3 * 130 * 6; i += 256) {
        int r   = i / 780;
        int rem = i - r * 780;
        int xi  = rem / 6;
        int g   = rem - xi * 6;
        int yg = y + r - 1;
        int xg = x0 - 1 + xi;
        uint4 v = make_uint4(0, 0, 0, 0);
        if (yg >= 0 && yg < 256 && xg >= 0 && xg < 256)
            v = *(const uint4*)(xt9 + (((size_t)(b * 256 + yg) * 256 + xg) * 48 + g * 8));
        *(uint4*)(&smem[(r * 130 + xi) * 48 + g * 8]) = v;
    }
    __syncthreads();

    f32x16 acc0, acc1;
#pragma unroll
    for (int i = 0; i < 16; ++i) { acc0[i] = 0.f; acc1[i] = 0.f; }

    const unsigned short* wbase = wpk + lane * 8;

#pragma unroll
    for (int s = 0; s < 9; ++s) {
        const int dy = s / 3, dx = s % 3;
        const int xl = wv * 32 + n + dx;
#pragma unroll
        for (int kst = 0; kst < 3; ++kst) {
            const int kc = kst * 16;
            bf16x8 bfrag = *(const bf16x8*)(&smem[(dy * 130 + xl) * 48 + kc + q * 8]);
            bf16x8 a0 = *(const bf16x8*)(wbase + ((s * 3 + kst) * 2 + 0) * 512);
            bf16x8 a1 = *(const bf16x8*)(wbase + ((s * 3 + kst) * 2 + 1) * 512);
            acc0 = __builtin_amdgcn_mfma_f32_32x32x16_bf16(a0, bfrag, acc0, 0, 0, 0);
            acc1 = __builtin_amdgcn_mfma_f32_32x32x16_bf16(a1, bfrag, acc1, 0, 0, 0);
        }
    }

    // ---- epilogue: C/D layout col=lane&31 (px), row=(reg&3)+8*(reg>>2)+4*q ----
    const int px = x0 + wv * 32 + n;
#pragma unroll
    for (int reg = 0; reg < 16; ++reg) {
        int row = (reg & 3) + 8 * (reg >> 2) + 4 * q;
        int oc0 = row, oc1 = 32 + row;
        fm[(((size_t)b * 64 + oc0) * 256 + y) * 256 + px] = fast_tanh(acc0[reg] + bias[oc0]);
        fm[(((size_t)b * 64 + oc1) * 256 + y) * 256 + px] = fast_tanh(acc1[reg] + bias[oc1]);
    }
}

// ---------------------------------------------------------------------------
// Fused W-direction LRNN pair (fwd + rev), initializes out.
// h = fma(p, h-x, x); rev outputs stay spatially flipped (step order).
// fm channels {c, 32+c}.
// ---------------------------------------------------------------------------
__global__ void lrnn_wb(const float* __restrict__ X, const float* __restrict__ FM,
                        float* __restrict__ out, int B, int H, int W)
{
    int total = B * 16 * H;
    int idx = blockIdx.x * 256 + threadIdx.x;
    if (idx >= total) return;
    int y = idx % H;
    int c = (idx / H) & 15;
    int b = idx / (H * 16);
    const float4* xr  = (const float4*)(X  + (size_t)((b * 16 + c) * H + y) * W);
    const float4* p1r = (const float4*)(FM + (size_t)((b * 64 + c) * H + y) * W);
    const float4* p2r = (const float4*)(FM + (size_t)((b * 64 + 32 + c) * H + y) * W);
    float4* orow = (float4*)(out + (size_t)((b * 16 + c) * H + y) * W);
    int nv = W >> 2;
    float h1 = 0.f, h2 = 0.f, g1 = 0.f, g2 = 0.f;
    float4 xf = xr[0],      paf = p1r[0],      pbf = p2r[0];
    float4 xv = xr[nv - 1], pav = p1r[nv - 1], pbv = p2r[nv - 1];
    for (int v = 0; v < nv; ++v) {
        float4 xf_n = xf, paf_n = paf, pbf_n = pbf;
        float4 xv_n = xv, pav_n = pav, pbv_n = pbv;
        if (v + 1 < nv) {
            xf_n = xr[v + 1];      paf_n = p1r[v + 1];      pbf_n = p2r[v + 1];
            xv_n = xr[nv - 2 - v]; pav_n = p1r[nv - 2 - v]; pbv_n = p2r[nv - 2 - v];
        }
        float4 m;
        h1 = fmaf(paf.x, h1 - xf.x, xf.x); h2 = fmaf(pbf.x, h2 - xf.x, xf.x);
        g1 = fmaf(pav.w, g1 - xv.w, xv.w); g2 = fmaf(pbv.w, g2 - xv.w, xv.w);
        m.x = fmaxf(fmaxf(h1, h2), fmaxf(g1, g2));
        h1 = fmaf(paf.y, h1 - xf.y, xf.y); h2 = fmaf(pbf.y, h2 - xf.y, xf.y);
        g1 = fmaf(pav.z, g1 - xv.z, xv.z); g2 = fmaf(pbv.z, g2 - xv.z, xv.z);
        m.y = fmaxf(fmaxf(h1, h2), fmaxf(g1, g2));
        h1 = fmaf(paf.z, h1 - xf.z, xf.z); h2 = fmaf(pbf.z, h2 - xf.z, xf.z);
        g1 = fmaf(pav.y, g1 - xv.y, xv.y); g2 = fmaf(pbv.y, g2 - xv.y, xv.y);
        m.z = fmaxf(fmaxf(h1, h2), fmaxf(g1, g2));
        h1 = fmaf(paf.w, h1 - xf.w, xf.w); h2 = fmaf(pbf.w, h2 - xf.w, xf.w);
        g1 = fmaf(pav.x, g1 - xv.x, xv.x); g2 = fmaf(pbv.x, g2 - xv.x, xv.x);
        m.w = fmaxf(fmaxf(h1, h2), fmaxf(g1, g2));
        orow[v] = m;
        xf = xf_n; paf = paf_n; pbf = pbf_n;
        xv = xv_n; pav = pav_n; pbv = pbv_n;
    }
}

// ---------------------------------------------------------------------------
// Fused H-direction LRNN pair (fwd + rev), max-accumulates into out.
// fm channels {16+c, 48+c}. Coalesced across x; depth-2 prefetch.
// ---------------------------------------------------------------------------
__global__ void lrnn_hb(const float* __restrict__ X, const float* __restrict__ FM,
                        float* __restrict__ out, int B, int H, int W)
{
    int total = B * 16 * W;
    int idx = blockIdx.x * 256 + threadIdx.x;
    if (idx >= total) return;
    int x = idx % W;
    int c = (idx / W) & 15;
    int b = idx / (W * 16);
    const float* xc  = X  + (size_t)((b * 16 + c) * H) * W + x;
    const float* p1c = FM + (size_t)((b * 64 + 16 + c) * H) * W + x;
    const float* p2c = FM + (size_t)((b * 64 + 48 + c) * H) * W + x;
    float* ocp = out + (size_t)((b * 16 + c) * H) * W + x;
    float hf1 = 0.f, hf2 = 0.f, hr1 = 0.f, hr2 = 0.f;
    // depth-2 pipeline
    float xfa = xc[0], pf1a = p1c[0], pf2a = p2c[0];
    float xra = xc[(H - 1) * W], pr1a = p1c[(H - 1) * W], pr2a = p2c[(H - 1) * W];
    float oa = ocp[0];
    float xfb = xc[W], pf1b = p1c[W], pf2b = p2c[W];
    float xrb = xc[(H - 2) * W], pr1b = p1c[(H - 2) * W], pr2b = p2c[(H - 2) * W];
    float ob = ocp[W];
    for (int i = 0; i < H; ++i) {
        float xfn = 0.f, pf1n = 0.f, pf2n = 0.f, xrn = 0.f, pr1n = 0.f, pr2n = 0.f, on = 0.f;
        if (i + 2 < H) {
            int yf = (i + 2) * W, yr = (H - 3 - i) * W;
            xfn = xc[yf]; pf1n = p1c[yf]; pf2n = p2c[yf];
            xrn = xc[yr]; pr1n = p1c[yr]; pr2n = p2c[yr];
            on = ocp[yf];
        }
        hf1 = fmaf(pf1a, hf1 - xfa, xfa);
        hf2 = fmaf(pf2a, hf2 - xfa, xfa);
        hr1 = fmaf(pr1a, hr1 - xra, xra);
        hr2 = fmaf(pr2a, hr2 - xra, xra);
        ocp[i * W] = fmaxf(fmaxf(oa, fmaxf(hf1, hf2)), fmaxf(hr1, hr2));
        xfa = xfb; pf1a = pf1b; pf2a = pf2b; xra = xrb; pr1a = pr1b; pr2a = pr2b; oa = ob;
        xfb = xfn; pf1b = pf1n; pf2b = pf2n; xrb = xrn; pr1b = pr1n; pr2b = pr2n; ob = on;
    }
}

// ---------------------------------------------------------------------------
extern "C" void kernel_launch(void* const* d_in, const int* in_sizes, int n_in,
                              void* d_out, int out_size, void* d_ws, size_t ws_size,
                              hipStream_t stream)
{
    const float* img = (const float*)d_in[0];
    const float* w1 = (const float*)d_in[1];  const float* b1 = (const float*)d_in[2];
    const float* w2 = (const float*)d_in[3];  const float* b2 = (const float*)d_in[4];
    const float* w3 = (const float*)d_in[5];  const float* b3 = (const float*)d_in[6];
    const float* w4 = (const float*)d_in[7];  const float* b4 = (const float*)d_in[8];
    const float* w5 = (const float*)d_in[9];  const float* b5 = (const float*)d_in[10];
    const float* w6 = (const float*)d_in[11]; const float* b6 = (const float*)d_in[12];
    const float* w7 = (const float*)d_in[13]; const float* b7 = (const float*)d_in[14];
    const float* w8 = (const float*)d_in[15]; const float* b8 = (const float*)d_in[16];
    const float* w9 = (const float*)d_in[17]; const float* b9 = (const float*)d_in[18];
    const float* wi = (const float*)d_in[19]; const float* bi = (const float*)d_in[20];
    const float* wo = (const float*)d_in[21]; const float* bo = (const float*)d_in[22];

    char* wsb = (char*)d_ws;
    const size_t MB = (size_t)(1u << 20);
    float* x1   = (float*)(wsb);              // [0,32)
    float* p1   = (float*)(wsb + 32 * MB);    // [32,40)
    float* x2   = (float*)(wsb + 40 * MB);    // [40,56)
    float* p2   = (float*)(wsb + 56 * MB);    // [56,60)
    float* x3   = (float*)(wsb + 60 * MB);    // [60,64)
    float* p3   = (float*)(wsb + 64 * MB);    // [64,65)
    float* x4   = (float*)(wsb + 65 * MB);    // [65,66)
    float* p4   = (float*)(wsb + 66 * MB);    // [66,67)
    float* x5   = (float*)(wsb + 67 * MB);    // [67,68)
    float* cat6 = (float*)(wsb + 68 * MB);    // [68,71)
    float* x6   = (float*)(wsb + 71 * MB);    // [71,72)
    float* cat7 = (float*)(wsb + 72 * MB);    // [72,80)
    float* x7   = (float*)(wsb + 80 * MB);    // [80,84)
    float* cat8 = (float*)(wsb + 84 * MB);    // [84,116)  32 MiB
    float* x8   = (float*)(wsb + 116 * MB);   // [116,132) 16 MiB
    unsigned short* xt9 = (unsigned short*)(wsb + 132 * MB);  // [132,182.33) bf16
    unsigned short* wpk = (unsigned short*)(wsb + 182 * MB + 512 * 1024);  // 55 KB
    float* fm   = (float*)(wsb);              // [0,128)  (x1..x8 dead)
    float* xin  = (float*)(wsb + 164 * MB);   // [164,196) (xt9/wpk dead after conv9)
    float* rnn  = (float*)(wsb + 196 * MB);   // [196,228)
    float* outp = (float*)d_out;

    const int B = 8;

    // --- encoder ---
    conv_rt<5, 1, 3>(img, w1, b1, x1, B, 15, 256, 256, 16, stream);
    { int tot = B * 16 * 128 * 128;
      maxpool2_kernel<<<(tot + 255) / 256, 256, 0, stream>>>(x1, p1, tot, 128, 128); }
    conv_rt<3, 1, 4>(p1, w2, b2, x2, B, 16, 128, 128, 32, stream);
    { int tot = B * 32 * 64 * 64;
      maxpool2_kernel<<<(tot + 255) / 256, 256, 0, stream>>>(x2, p2, tot, 64, 64); }
    conv_s<3, 1>(p2, w3, b3, x3, B, 32, 64, 64, 32, stream);
    { int tot = B * 32 * 32 * 32;
      maxpool2_kernel<<<(tot + 255) / 256, 256, 0, stream>>>(x3, p3, tot, 32, 32); }
    conv_s<3, 1>(p3, w4, b4, x4, B, 32, 32, 32, 32, stream);
    { int tot = B * 32 * 16 * 16;
      maxpool2_kernel<<<(tot + 255) / 256, 256, 0, stream>>>(x4, p4, tot, 16, 16); }
    conv_s<3, 1>(p4, w5, b5, x5, B, 32, 16, 16, 64, stream);

    // --- decoder ---
    { int tot = B * 96 * 32 * 32;
      upcat_kernel<<<(tot + 255) / 256, 256, 0, stream>>>(x5, x4, cat6, B, 64, 32, 32, 32); }
    conv_s<3, 1>(cat6, w6, b6, x6, B, 96, 32, 32, 32, stream);
    { int tot = B * 64 * 64 * 64;
      upcat_kernel<<<(tot + 255) / 256, 256, 0, stream>>>(x6, x3, cat7, B, 32, 32, 64, 64); }
    conv_s<3, 1>(cat7, w7, b7, x7, B, 64, 64, 64, 32, stream);
    { int tot = B * 64 * 128 * 128;
      upcat_kernel<<<(tot + 255) / 256, 256, 0, stream>>>(x7, x2, cat8, B, 32, 32, 128, 128); }
    conv_rt<3, 1, 4>(cat8, w8, b8, x8, B, 64, 128, 128, 32, stream);

    // --- stage 9: bf16 transposed upcat + packed weights + MFMA conv ---
    { int tot = 8 * 256 * 256 * 48;
      upcat9_bf16<<<(tot + 255) / 256, 256, 0, stream>>>(x8, x1, xt9); }
    wprep9<<<108, 256, 0, stream>>>(w9, wpk);
    { dim3 grd(512, 8);
      conv9_mfma<<<grd, 256, 0, stream>>>(xt9, wpk, b9, fm); }

    // --- input projection ---
    conv_rt<3, 0, 3>(img, wi, bi, xin, B, 15, 256, 256, 16, stream);

    // --- spatial RNN: 8 directions via 2 fused kernels ---
    { int tot = B * 16 * 256; int g = (tot + 255) / 256;
      lrnn_wb<<<g, 256, 0, stream>>>(xin, fm, rnn, B, 256, 256);
      lrnn_hb<<<g, 256, 0, stream>>>(xin, fm, rnn, B, 256, 256); }

    // --- output head ---
    conv_rt<3, 3, 4>(rnn, wo, bo, outp, B, 16, 256, 256, 3, stream);
}

// Round 5
// 1073.113 us; speedup vs baseline: 2.1642x; 1.3358x over previous
//
#include <hip/hip_runtime.h>
#include <math.h>

typedef __attribute__((ext_vector_type(8)))  short bf16x8;
typedef __attribute__((ext_vector_type(8)))  unsigned short u16x8;
typedef __attribute__((ext_vector_type(16))) float f32x16;

__device__ __forceinline__ unsigned short f2bf(float f) {
    unsigned u = __float_as_uint(f);
    unsigned r = (u + 0x7FFFu + ((u >> 16) & 1u)) >> 16;
    return (unsigned short)r;
}
__device__ __forceinline__ float bf2f(unsigned short h) {
    return __uint_as_float(((unsigned)h) << 16);
}
__device__ __forceinline__ unsigned pack2(unsigned short a, unsigned short b) {
    return (unsigned)a | ((unsigned)b << 16);
}
__device__ __forceinline__ float fast_tanh(float x) {
    float e = __expf(2.f * x);
    return 1.f - 2.f / (e + 1.f);
}

// ---------------------------------------------------------------------------
// Small-layer conv: 16x16 spatial tile, 8 oc/block (stages 3-7).
// ---------------------------------------------------------------------------
template<int K, int ACT, int OCB>
__global__ __launch_bounds__(256)
void conv2d_s(const float* __restrict__ in, const float* __restrict__ w,
              const float* __restrict__ bias, float* __restrict__ out,
              int B, int Cin, int H, int Wd, int Cout)
{
    constexpr int PAD = K / 2;
    constexpr int T = 16 + K - 1;
    constexpr int KK = K * K;
    constexpr int CH = 4;
    __shared__ float tile[CH][T][T + 1];

    const int tx = threadIdx.x, ty = threadIdx.y;
    const int tid = ty * 16 + tx;
    const int tilesX = (Wd + 15) >> 4;
    const int bx = blockIdx.x % tilesX, by = blockIdx.x / tilesX;
    const int x0 = bx * 16, y0 = by * 16;
    const int ox = x0 + tx, oy = y0 + ty;
    const int oc0 = blockIdx.y * OCB;
    const int b = blockIdx.z;

    int wb[OCB];
#pragma unroll
    for (int o = 0; o < OCB; ++o) {
        int oc = oc0 + o;
        if (oc > Cout - 1) oc = Cout - 1;
        wb[o] = oc * Cin * KK;
    }
    float acc[OCB];
#pragma unroll
    for (int o = 0; o < OCB; ++o) acc[o] = 0.f;

    for (int c0 = 0; c0 < Cin; c0 += CH) {
        int nc = Cin - c0; if (nc > CH) nc = CH;
        __syncthreads();
        for (int i = tid; i < nc * T * T; i += 256) {
            int cc = i / (T * T);
            int r = i - cc * T * T;
            int yy = r / T, xx = r - yy * T;
            int iy = y0 + yy - PAD, ix = x0 + xx - PAD;
            float v = 0.f;
            if (iy >= 0 && iy < H && ix >= 0 && ix < Wd)
                v = in[((b * Cin + c0 + cc) * H + iy) * Wd + ix];
            tile[cc][yy][xx] = v;
        }
        __syncthreads();
        for (int cc = 0; cc < nc; ++cc) {
            const float* wp = w + (c0 + cc) * KK;
#pragma unroll
            for (int ky = 0; ky < K; ++ky)
#pragma unroll
                for (int kx = 0; kx < K; ++kx) {
                    float v = tile[cc][ty + ky][tx + kx];
#pragma unroll
                    for (int o = 0; o < OCB; ++o)
                        acc[o] = fmaf(v, wp[wb[o] + ky * K + kx], acc[o]);
                }
        }
    }
    if (ox < Wd && oy < H) {
#pragma unroll
        for (int o = 0; o < OCB; ++o) {
            int oc = oc0 + o;
            if (oc < Cout) {
                float r = acc[o] + bias[oc];
                if (ACT == 1) r = fmaxf(r, 0.f);
                if (ACT == 2) r = fast_tanh(r);
                if (ACT == 3) r = 1.f / (1.f + __expf(-r));
                out[((b * Cout + oc) * H + oy) * Wd + ox] = r;
            }
        }
    }
}

template<int K, int ACT>
static inline void conv_s(const float* in, const float* w, const float* b, float* o,
                          int B, int Cin, int H, int W, int Cout, hipStream_t s)
{
    dim3 blk(16, 16, 1);
    int tcx = (W + 15) / 16, tcy = (H + 15) / 16;
    dim3 grd(tcx * tcy, (Cout + 7) / 8, B);
    hipLaunchKernelGGL((conv2d_s<K, ACT, 8>), grd, blk, 0, s, in, w, b, o, B, Cin, H, W, Cout);
}

// ---------------------------------------------------------------------------
// Big-layer fp32 conv (conv2, out-head): 32x32 tile, 4 px x 8 oc per thread.
// ---------------------------------------------------------------------------
template<int K, int ACT, int OCB, int CC>
__global__ __launch_bounds__(256)
void conv2d_rt(const float* __restrict__ in, const float* __restrict__ w,
               const float* __restrict__ bias, float* __restrict__ out,
               int B, int Cin, int H, int Wd, int Cout)
{
    constexpr int PAD = K / 2;
    constexpr int TW = 32, TH = 32;
    constexpr int T  = TW + K - 1;
    constexpr int TT = TH + K - 1;
    constexpr int LDW = T + 2;
    constexpr int KK = K * K;
    __shared__ float tile[CC][TT][LDW];

    const int tid = threadIdx.x;
    const int lx = tid & 31;
    const int ly = tid >> 5;
    const int tilesX = (Wd + TW - 1) / TW;
    const int bx = blockIdx.x % tilesX, by = blockIdx.x / tilesX;
    const int x0 = bx * TW, y0 = by * TH;
    const int oc0 = blockIdx.y * OCB;
    const int b = blockIdx.z;

    int woff[OCB];
#pragma unroll
    for (int o = 0; o < OCB; ++o) {
        int oc = oc0 + o;
        if (oc > Cout - 1) oc = Cout - 1;
        woff[o] = oc * Cin * KK;
    }
    float acc[4][OCB];
#pragma unroll
    for (int j = 0; j < 4; ++j)
#pragma unroll
        for (int o = 0; o < OCB; ++o) acc[j][o] = 0.f;

    for (int c0 = 0; c0 < Cin; c0 += CC) {
        __syncthreads();
        for (int i = tid; i < CC * TT * T; i += 256) {
            int cc = i / (TT * T);
            int r  = i - cc * (TT * T);
            int yy = r / T, xx = r - yy * T;
            int iy = y0 + yy - PAD, ix = x0 + xx - PAD;
            int ci = c0 + cc;
            float v = 0.f;
            if (iy >= 0 && iy < H && ix >= 0 && ix < Wd && ci < Cin)
                v = in[((b * Cin + ci) * H + iy) * Wd + ix];
            tile[cc][yy][xx] = v;
        }
        __syncthreads();
        int ncc = Cin - c0; if (ncc > CC) ncc = CC;
        for (int cc = 0; cc < ncc; ++cc) {
            const float* wch = w + (c0 + cc) * KK;
#pragma unroll
            for (int ky = 0; ky < K; ++ky)
#pragma unroll
                for (int kx = 0; kx < K; ++kx) {
                    float wv[OCB];
#pragma unroll
                    for (int o = 0; o < OCB; ++o)
                        wv[o] = wch[woff[o] + ky * K + kx];
#pragma unroll
                    for (int j = 0; j < 4; ++j) {
                        float v = tile[cc][ly + 8 * j + ky][lx + kx];
#pragma unroll
                        for (int o = 0; o < OCB; ++o)
                            acc[j][o] = fmaf(v, wv[o], acc[j][o]);
                    }
                }
        }
    }
    const int ox = x0 + lx;
    if (ox < Wd) {
#pragma unroll
        for (int j = 0; j < 4; ++j) {
            int oy = y0 + ly + 8 * j;
            if (oy < H) {
#pragma unroll
                for (int o = 0; o < OCB; ++o) {
                    int oc = oc0 + o;
                    if (oc < Cout) {
                        float r = acc[j][o] + bias[oc];
                        if (ACT == 1) r = fmaxf(r, 0.f);
                        if (ACT == 2) r = fast_tanh(r);
                        if (ACT == 3) r = 1.f / (1.f + __expf(-r));
                        out[((b * Cout + oc) * H + oy) * Wd + ox] = r;
                    }
                }
            }
        }
    }
}

template<int K, int ACT, int CC>
static inline void conv_rt(const float* in, const float* w, const float* b, float* o,
                           int B, int Cin, int H, int W, int Cout, hipStream_t s)
{
    constexpr int OCB = 8;
    dim3 blk(256, 1, 1);
    int tcx = (W + 31) / 32, tcy = (H + 31) / 32;
    dim3 grd(tcx * tcy, (Cout + OCB - 1) / OCB, B);
    hipLaunchKernelGGL((conv2d_rt<K, ACT, OCB, CC>), grd, blk, 0, s, in, w, b, o, B, Cin, H, W, Cout);
}

// ---------------------------------------------------------------------------
// maxpool / fp32 upcat (stages 6,7)
// ---------------------------------------------------------------------------
__global__ void maxpool2_kernel(const float* __restrict__ in, float* __restrict__ out,
                                int total, int Ho, int Wo)
{
    int idx = blockIdx.x * 256 + threadIdx.x;
    if (idx >= total) return;
    int x = idx % Wo;
    int t = idx / Wo;
    int y = t % Ho;
    int bc = t / Ho;
    int Wi = Wo * 2;
    const float* p = in + ((bc * 2 * Ho + 2 * y) * Wi + 2 * x);
    out[idx] = fmaxf(fmaxf(p[0], p[1]), fmaxf(p[Wi], p[Wi + 1]));
}

// bilinear half-pixel setup: returns 4 clamped corner indices + weights
__device__ __forceinline__ void bilin_setup(int y, int x, int Hi, int Wi,
                                            int& i00, int& i01, int& i10, int& i11,
                                            float& wy, float& wx)
{
    float fy = 0.5f * y - 0.25f;
    float fx = 0.5f * x - 0.25f;
    float y0f = floorf(fy), x0f = floorf(fx);
    wy = fy - y0f; wx = fx - x0f;
    int yA = (int)y0f, xA = (int)x0f;
    int yB = yA + 1, xB = xA + 1;
    yA = yA < 0 ? 0 : (yA > Hi - 1 ? Hi - 1 : yA);
    yB = yB < 0 ? 0 : (yB > Hi - 1 ? Hi - 1 : yB);
    xA = xA < 0 ? 0 : (xA > Wi - 1 ? Wi - 1 : xA);
    xB = xB < 0 ? 0 : (xB > Wi - 1 ? Wi - 1 : xB);
    i00 = yA * Wi + xA; i01 = yA * Wi + xB;
    i10 = yB * Wi + xA; i11 = yB * Wi + xB;
}

__device__ __forceinline__ float bilin(const float* __restrict__ sp, int y, int x, int Hi, int Wi)
{
    int i00, i01, i10, i11; float wy, wx;
    bilin_setup(y, x, Hi, Wi, i00, i01, i10, i11, wy, wx);
    return (1.f - wy) * ((1.f - wx) * sp[i00] + wx * sp[i01]) +
           wy * ((1.f - wx) * sp[i10] + wx * sp[i11]);
}

__global__ void upcat_kernel(const float* __restrict__ up, const float* __restrict__ skip,
                             float* __restrict__ dst, int B, int C1, int C2, int H, int W)
{
    int total = B * (C1 + C2) * H * W;
    int idx = blockIdx.x * 256 + threadIdx.x;
    if (idx >= total) return;
    int x = idx % W;
    int t = idx / W;
    int y = t % H;
    t /= H;
    int c = t % (C1 + C2);
    int b = t / (C1 + C2);
    float r;
    if (c < C1) r = bilin(up + ((size_t)(b * C1 + c) * (H >> 1)) * (W >> 1), y, x, H >> 1, W >> 1);
    else        r = skip[((b * C2 + (c - C1)) * H + y) * W + x];
    dst[idx] = r;
}

// ---------------------------------------------------------------------------
// img [8][15][256][256] fp32 -> imgT [b][y][x][16] bf16 (ch15 = 0)
// ---------------------------------------------------------------------------
__global__ void imgT_bf16(const float* __restrict__ img, unsigned short* __restrict__ dst)
{
    int idx = blockIdx.x * 256 + threadIdx.x;
    if (idx >= 8 * 256 * 256) return;
    int x = idx & 255, y = (idx >> 8) & 255, b = idx >> 16;
    unsigned short v[16];
#pragma unroll
    for (int c = 0; c < 15; ++c)
        v[c] = f2bf(img[(size_t)(b * 15 + c) * 65536 + y * 256 + x]);
    v[15] = 0;
    uint4 lo = make_uint4(pack2(v[0], v[1]), pack2(v[2], v[3]), pack2(v[4], v[5]), pack2(v[6], v[7]));
    uint4 hi = make_uint4(pack2(v[8], v[9]), pack2(v[10], v[11]), pack2(v[12], v[13]), pack2(v[14], v[15]));
    *(uint4*)(dst + (size_t)idx * 16)     = lo;
    *(uint4*)(dst + (size_t)idx * 16 + 8) = hi;
}

// ---------------------------------------------------------------------------
// Pack all MFMA weights (bf16 A-fragments, A[m=lane&31][k=(lane>>5)*8+j]).
// wpk9: 27648 (w9 64x48x3x3, 9 shifts x 3 kst x 2 m-tiles)
// wpk8: 18432 (w8 32x64x3x3, 9 shifts x 4 kst)
// wpk1: 12800 (w1 16x15x5x5 -> K=16 padded, 25 shifts; oc>=16 zero)
// wpki:  4608 (wi 16x15x3x3 -> K=16 padded, 9 shifts)
// ---------------------------------------------------------------------------
__global__ void wprep_all(const float* __restrict__ w9, const float* __restrict__ w8,
                          const float* __restrict__ w1, const float* __restrict__ wi,
                          unsigned short* __restrict__ wpk9, unsigned short* __restrict__ wpk8,
                          unsigned short* __restrict__ wpk1, unsigned short* __restrict__ wpki)
{
    int idx = blockIdx.x * 256 + threadIdx.x;
    if (idx < 27648) {
        int j = idx & 7;
        int t = idx >> 3;
        int lane = t & 63; t >>= 6;
        int mt = t & 1; t >>= 1;
        int kst = t % 3;
        int s = t / 3;
        int oc = mt * 32 + (lane & 31);
        int ci = kst * 16 + (lane >> 5) * 8 + j;
        wpk9[idx] = f2bf(w9[(oc * 48 + ci) * 9 + s]);
    } else if (idx < 46080) {
        int i = idx - 27648;
        int j = i & 7;
        int lane = (i >> 3) & 63;
        int t = i >> 9;
        int kst = t & 3;
        int s = t >> 2;
        int oc = lane & 31;
        int ci = kst * 16 + (lane >> 5) * 8 + j;
        wpk8[i] = f2bf(w8[(oc * 64 + ci) * 9 + s]);
    } else if (idx < 58880) {
        int i = idx - 46080;
        int j = i & 7;
        int lane = (i >> 3) & 63;
        int s = i >> 9;                 // 0..24
        int oc = lane & 31;
        int ci = (lane >> 5) * 8 + j;   // 0..15
        float v = 0.f;
        if (oc < 16 && ci < 15) v = w1[((oc * 15 + ci) * 5 + s / 5) * 5 + s % 5];
        wpk1[i] = f2bf(v);
    } else if (idx < 63488) {
        int i = idx - 58880;
        int j = i & 7;
        int lane = (i >> 3) & 63;
        int s = i >> 9;                 // 0..8
        int oc = lane & 31;
        int ci = (lane >> 5) * 8 + j;
        float v = 0.f;
        if (oc < 16 && ci < 15) v = wi[((oc * 15 + ci) * 3 + s / 3) * 3 + s % 3];
        wpki[i] = f2bf(v);
    }
}

// ---------------------------------------------------------------------------
// Fused conv1 (5x5, relu -> x1 NCHW fp32) + conv_i (3x3 -> xin NCHW fp32)
// from imgT. Block: row y, 128-px strip, 4 waves. 25+9 MFMAs per wave.
// LDS [g=2][5 rows][132 px][8ch] bf16 (px stride 16 B -> conflict-free b128).
// ---------------------------------------------------------------------------
__global__ __launch_bounds__(256)
void conv1i_mfma(const unsigned short* __restrict__ imgT,
                 const unsigned short* __restrict__ wpk1,
                 const unsigned short* __restrict__ wpki,
                 const float* __restrict__ b1, const float* __restrict__ bi,
                 float* __restrict__ x1, float* __restrict__ xin)
{
    __shared__ __align__(16) unsigned short smem[2 * 5 * 132 * 8];  // 21120 B

    const int tid  = threadIdx.x;
    const int lane = tid & 63;
    const int wv   = tid >> 6;
    const int n    = lane & 31;
    const int q    = lane >> 5;
    const int y    = blockIdx.x >> 1;
    const int x0   = (blockIdx.x & 1) * 128;
    const int b    = blockIdx.y;

    for (int i = tid; i < 5 * 132 * 2; i += 256) {
        int r   = i / 264;
        int rem = i - r * 264;
        int xi  = rem >> 1;
        int g   = rem & 1;
        int yg = y + r - 2;
        int xg = x0 - 2 + xi;
        uint4 v = make_uint4(0, 0, 0, 0);
        if (yg >= 0 && yg < 256 && xg >= 0 && xg < 256)
            v = *(const uint4*)(imgT + (((size_t)(b * 256 + yg) * 256 + xg) * 16 + g * 8));
        *(uint4*)(&smem[((g * 5 + r) * 132 + xi) * 8]) = v;
    }
    __syncthreads();

    f32x16 acc1, acci;
#pragma unroll
    for (int i = 0; i < 16; ++i) { acc1[i] = 0.f; acci[i] = 0.f; }

    const int pxl = wv * 32 + n;
    const unsigned short* wb1 = wpk1 + lane * 8;
    const unsigned short* wbi = wpki + lane * 8;

#pragma unroll
    for (int s = 0; s < 25; ++s) {
        const int dy = s / 5, dx = s % 5;
        bf16x8 bfrag = *(const bf16x8*)(&smem[((q * 5 + dy) * 132 + pxl + dx) * 8]);
        bf16x8 a = *(const bf16x8*)(wb1 + s * 512);
        acc1 = __builtin_amdgcn_mfma_f32_32x32x16_bf16(a, bfrag, acc1, 0, 0, 0);
    }
#pragma unroll
    for (int s = 0; s < 9; ++s) {
        const int dy = s / 3, dx = s % 3;
        bf16x8 bfrag = *(const bf16x8*)(&smem[((q * 5 + dy + 1) * 132 + pxl + dx + 1) * 8]);
        bf16x8 a = *(const bf16x8*)(wbi + s * 512);
        acci = __builtin_amdgcn_mfma_f32_32x32x16_bf16(a, bfrag, acci, 0, 0, 0);
    }

    const int px = x0 + pxl;
#pragma unroll
    for (int reg = 0; reg < 8; ++reg) {          // rows 0..15 only (Cout=16)
        int row = (reg & 3) + 8 * (reg >> 2) + 4 * q;
        x1 [((size_t)(b * 16 + row) * 256 + y) * 256 + px] = fmaxf(acc1[reg] + b1[row], 0.f);
        xin[((size_t)(b * 16 + row) * 256 + y) * 256 + px] = acci[reg] + bi[row];
    }
}

// ---------------------------------------------------------------------------
// upcat8 -> cat8t NHWC bf16 [b][128][128][64]
// ch 0..31 = bilinear-up(x7 NCHW fp32 [8,32,64,64]); ch 32..63 = x2 skip.
// ---------------------------------------------------------------------------
__global__ void upcat8_nhwc(const float* __restrict__ x7, const float* __restrict__ x2,
                            unsigned short* __restrict__ dst)
{
    int idx = blockIdx.x * 256 + threadIdx.x;
    if (idx >= 8 * 128 * 128) return;
    int x = idx & 127, y = (idx >> 7) & 127, b = idx >> 14;
    int i00, i01, i10, i11; float wy, wx;
    bilin_setup(y, x, 64, 64, i00, i01, i10, i11, wy, wx);
    const float* base7 = x7 + (size_t)b * 32 * 4096;
    const float* base2 = x2 + (size_t)b * 32 * 16384 + y * 128 + x;
    unsigned short* d = dst + (size_t)idx * 64;
#pragma unroll
    for (int g = 0; g < 8; ++g) {
        u16x8 r;
#pragma unroll
        for (int j = 0; j < 8; ++j) {
            int c = g * 8 + j;
            float v;
            if (c < 32) {
                const float* sp = base7 + c * 4096;
                v = (1.f - wy) * ((1.f - wx) * sp[i00] + wx * sp[i01]) +
                    wy * ((1.f - wx) * sp[i10] + wx * sp[i11]);
            } else {
                v = base2[(size_t)(c - 32) * 16384];
            }
            r[j] = f2bf(v);
        }
        *(u16x8*)(d + g * 8) = r;
    }
}

// ---------------------------------------------------------------------------
// conv8 MFMA: Cin=64 (4 kst), Cout=32 (1 m-tile), 128x128, relu.
// Block: one row, 128 px, 4 waves; 36 MFMA/wave. Out: x8t NHWC bf16.
// LDS [g=8][3][130][8].
// ---------------------------------------------------------------------------
__global__ __launch_bounds__(256)
void conv8_mfma(const unsigned short* __restrict__ cat8t,
                const unsigned short* __restrict__ wpk8,
                const float* __restrict__ bias,
                unsigned short* __restrict__ x8t)
{
    __shared__ __align__(16) unsigned short smem[8 * 3 * 130 * 8];  // 49920 B

    const int tid  = threadIdx.x;
    const int lane = tid & 63;
    const int wv   = tid >> 6;
    const int n    = lane & 31;
    const int q    = lane >> 5;
    const int y    = blockIdx.x;
    const int b    = blockIdx.y;

    for (int i = tid; i < 3 * 130 * 8; i += 256) {
        int r   = i / 1040;
        int rem = i - r * 1040;
        int xi  = rem >> 3;
        int g   = rem & 7;
        int yg = y + r - 1;
        int xg = xi - 1;
        uint4 v = make_uint4(0, 0, 0, 0);
        if (yg >= 0 && yg < 128 && xg >= 0 && xg < 128)
            v = *(const uint4*)(cat8t + (((size_t)(b * 128 + yg) * 128 + xg) * 64 + g * 8));
        *(uint4*)(&smem[((g * 3 + r) * 130 + xi) * 8]) = v;
    }
    __syncthreads();

    f32x16 acc;
#pragma unroll
    for (int i = 0; i < 16; ++i) acc[i] = 0.f;

    const int pxl = wv * 32 + n;
    const unsigned short* wbase = wpk8 + lane * 8;

#pragma unroll
    for (int s = 0; s < 9; ++s) {
        const int dy = s / 3, dx = s % 3;
        const int xi = pxl + dx;
#pragma unroll
        for (int kst = 0; kst < 4; ++kst) {
            const int g = kst * 2 + q;
            bf16x8 bfrag = *(const bf16x8*)(&smem[((g * 3 + dy) * 130 + xi) * 8]);
            bf16x8 a = *(const bf16x8*)(wbase + (s * 4 + kst) * 512);
            acc = __builtin_amdgcn_mfma_f32_32x32x16_bf16(a, bfrag, acc, 0, 0, 0);
        }
    }

    // epilogue: row = (reg&3) + 8*(reg>>2) + 4*q -> 4 contiguous oc per reg-quad
    size_t base = ((size_t)(b * 128 + y) * 128 + pxl) * 32;
#pragma unroll
    for (int rg = 0; rg < 4; ++rg) {
        int oc0 = 8 * rg + 4 * q;
        unsigned short s0 = f2bf(fmaxf(acc[rg * 4 + 0] + bias[oc0 + 0], 0.f));
        unsigned short s1 = f2bf(fmaxf(acc[rg * 4 + 1] + bias[oc0 + 1], 0.f));
        unsigned short s2 = f2bf(fmaxf(acc[rg * 4 + 2] + bias[oc0 + 2], 0.f));
        unsigned short s3 = f2bf(fmaxf(acc[rg * 4 + 3] + bias[oc0 + 3], 0.f));
        uint2 v = make_uint2(pack2(s0, s1), pack2(s2, s3));
        *(uint2*)(x8t + base + oc0) = v;
    }
}

// ---------------------------------------------------------------------------
// upcat9 -> xt9 NHWC bf16 [b][256][256][48]
// ch 0..31 = bilinear-up(x8t NHWC bf16 [8,128,128,32]); ch 32..47 = x1 NCHW.
// ---------------------------------------------------------------------------
__global__ void upcat9_nhwc(const unsigned short* __restrict__ x8t,
                            const float* __restrict__ x1,
                            unsigned short* __restrict__ dst)
{
    int idx = blockIdx.x * 256 + threadIdx.x;
    if (idx >= 8 * 256 * 256) return;
    int x = idx & 255, y = (idx >> 8) & 255, b = idx >> 16;
    int i00, i01, i10, i11; float wy, wx;
    bilin_setup(y, x, 128, 128, i00, i01, i10, i11, wy, wx);
    const unsigned short* sb = x8t + (size_t)b * 128 * 128 * 32;
    unsigned short* d = dst + (size_t)idx * 48;
    float w00 = (1.f - wy) * (1.f - wx), w01 = (1.f - wy) * wx;
    float w10 = wy * (1.f - wx),         w11 = wy * wx;
#pragma unroll
    for (int g = 0; g < 4; ++g) {
        u16x8 v00 = *(const u16x8*)(sb + (size_t)i00 * 32 + g * 8);
        u16x8 v01 = *(const u16x8*)(sb + (size_t)i01 * 32 + g * 8);
        u16x8 v10 = *(const u16x8*)(sb + (size_t)i10 * 32 + g * 8);
        u16x8 v11 = *(const u16x8*)(sb + (size_t)i11 * 32 + g * 8);
        u16x8 r;
#pragma unroll
        for (int j = 0; j < 8; ++j) {
            float v = w00 * bf2f(v00[j]) + w01 * bf2f(v01[j]) +
                      w10 * bf2f(v10[j]) + w11 * bf2f(v11[j]);
            r[j] = f2bf(v);
        }
        *(u16x8*)(d + g * 8) = r;
    }
    const float* x1b = x1 + (size_t)b * 16 * 65536 + y * 256 + x;
#pragma unroll
    for (int g = 0; g < 2; ++g) {
        u16x8 r;
#pragma unroll
        for (int j = 0; j < 8; ++j)
            r[j] = f2bf(x1b[(size_t)(g * 8 + j) * 65536]);
        *(u16x8*)(d + 32 + g * 8) = r;
    }
}

// ---------------------------------------------------------------------------
// conv9 MFMA: K=48 (3 kst), 64 oc (2 m-tiles), 256x256, tanh -> fm NCHW fp32.
// LDS [g=6][3][130][8].
// ---------------------------------------------------------------------------
__global__ __launch_bounds__(256)
void conv9_mfma(const unsigned short* __restrict__ xt9,
                const unsigned short* __restrict__ wpk,
                const float* __restrict__ bias,
                float* __restrict__ fm)
{
    __shared__ __align__(16) unsigned short smem[6 * 3 * 130 * 8];  // 37440 B

    const int tid  = threadIdx.x;
    const int lane = tid & 63;
    const int wv   = tid >> 6;
    const int n    = lane & 31;
    const int q    = lane >> 5;
    const int y    = blockIdx.x >> 1;
    const int x0   = (blockIdx.x & 1) * 128;
    const int b    = blockIdx.y;

    for (int i = tid; i < 3 * 130 * 6; i += 256) {
        int r   = i / 780;
        int rem = i - r * 780;
        int xi  = rem / 6;
        int g   = rem - xi * 6;
        int yg = y + r - 1;
        int xg = x0 - 1 + xi;
        uint4 v = make_uint4(0, 0, 0, 0);
        if (yg >= 0 && yg < 256 && xg >= 0 && xg < 256)
            v = *(const uint4*)(xt9 + (((size_t)(b * 256 + yg) * 256 + xg) * 48 + g * 8));
        *(uint4*)(&smem[((g * 3 + r) * 130 + xi) * 8]) = v;
    }
    __syncthreads();

    f32x16 acc0, acc1;
#pragma unroll
    for (int i = 0; i < 16; ++i) { acc0[i] = 0.f; acc1[i] = 0.f; }

    const int pxl = wv * 32 + n;
    const unsigned short* wbase = wpk + lane * 8;

#pragma unroll
    for (int s = 0; s < 9; ++s) {
        const int dy = s / 3, dx = s % 3;
        const int xi = pxl + dx;
#pragma unroll
        for (int kst = 0; kst < 3; ++kst) {
            const int g = kst * 2 + q;
            bf16x8 bfrag = *(const bf16x8*)(&smem[((g * 3 + dy) * 130 + xi) * 8]);
            bf16x8 a0 = *(const bf16x8*)(wbase + ((s * 3 + kst) * 2 + 0) * 512);
            bf16x8 a1 = *(const bf16x8*)(wbase + ((s * 3 + kst) * 2 + 1) * 512);
            acc0 = __builtin_amdgcn_mfma_f32_32x32x16_bf16(a0, bfrag, acc0, 0, 0, 0);
            acc1 = __builtin_amdgcn_mfma_f32_32x32x16_bf16(a1, bfrag, acc1, 0, 0, 0);
        }
    }

    const int px = x0 + pxl;
#pragma unroll
    for (int reg = 0; reg < 16; ++reg) {
        int row = (reg & 3) + 8 * (reg >> 2) + 4 * q;
        int oc0 = row, oc1 = 32 + row;
        fm[(((size_t)b * 64 + oc0) * 256 + y) * 256 + px] = fast_tanh(acc0[reg] + bias[oc0]);
        fm[(((size_t)b * 64 + oc1) * 256 + y) * 256 + px] = fast_tanh(acc1[reg] + bias[oc1]);
    }
}

// ---------------------------------------------------------------------------
// Fused W-direction LRNN pair (fwd + rev), initializes out.
// ---------------------------------------------------------------------------
__global__ void lrnn_wb(const float* __restrict__ X, const float* __restrict__ FM,
                        float* __restrict__ out, int B, int H, int W)
{
    int total = B * 16 * H;
    int idx = blockIdx.x * 256 + threadIdx.x;
    if (idx >= total) return;
    int y = idx % H;
    int c = (idx / H) & 15;
    int b = idx / (H * 16);
    const float4* xr  = (const float4*)(X  + (size_t)((b * 16 + c) * H + y) * W);
    const float4* p1r = (const float4*)(FM + (size_t)((b * 64 + c) * H + y) * W);
    const float4* p2r = (const float4*)(FM + (size_t)((b * 64 + 32 + c) * H + y) * W);
    float4* orow = (float4*)(out + (size_t)((b * 16 + c) * H + y) * W);
    int nv = W >> 2;
    float h1 = 0.f, h2 = 0.f, g1 = 0.f, g2 = 0.f;
    float4 xf = xr[0],      paf = p1r[0],      pbf = p2r[0];
    float4 xv = xr[nv - 1], pav = p1r[nv - 1], pbv = p2r[nv - 1];
    for (int v = 0; v < nv; ++v) {
        float4 xf_n = xf, paf_n = paf, pbf_n = pbf;
        float4 xv_n = xv, pav_n = pav, pbv_n = pbv;
        if (v + 1 < nv) {
            xf_n = xr[v + 1];      paf_n = p1r[v + 1];      pbf_n = p2r[v + 1];
            xv_n = xr[nv - 2 - v]; pav_n = p1r[nv - 2 - v]; pbv_n = p2r[nv - 2 - v];
        }
        float4 m;
        h1 = fmaf(paf.x, h1 - xf.x, xf.x); h2 = fmaf(pbf.x, h2 - xf.x, xf.x);
        g1 = fmaf(pav.w, g1 - xv.w, xv.w); g2 = fmaf(pbv.w, g2 - xv.w, xv.w);
        m.x = fmaxf(fmaxf(h1, h2), fmaxf(g1, g2));
        h1 = fmaf(paf.y, h1 - xf.y, xf.y); h2 = fmaf(pbf.y, h2 - xf.y, xf.y);
        g1 = fmaf(pav.z, g1 - xv.z, xv.z); g2 = fmaf(pbv.z, g2 - xv.z, xv.z);
        m.y = fmaxf(fmaxf(h1, h2), fmaxf(g1, g2));
        h1 = fmaf(paf.z, h1 - xf.z, xf.z); h2 = fmaf(pbf.z, h2 - xf.z, xf.z);
        g1 = fmaf(pav.y, g1 - xv.y, xv.y); g2 = fmaf(pbv.y, g2 - xv.y, xv.y);
        m.z = fmaxf(fmaxf(h1, h2), fmaxf(g1, g2));
        h1 = fmaf(paf.w, h1 - xf.w, xf.w); h2 = fmaf(pbf.w, h2 - xf.w, xf.w);
        g1 = fmaf(pav.x, g1 - xv.x, xv.x); g2 = fmaf(pbv.x, g2 - xv.x, xv.x);
        m.w = fmaxf(fmaxf(h1, h2), fmaxf(g1, g2));
        orow[v] = m;
        xf = xf_n; paf = paf_n; pbf = pbf_n;
        xv = xv_n; pav = pav_n; pbv = pbv_n;
    }
}

// ---------------------------------------------------------------------------
// Fused H-direction LRNN pair (fwd + rev), max-accumulates into out.
// ---------------------------------------------------------------------------
__global__ void lrnn_hb(const float* __restrict__ X, const float* __restrict__ FM,
                        float* __restrict__ out, int B, int H, int W)
{
    int total = B * 16 * W;
    int idx = blockIdx.x * 256 + threadIdx.x;
    if (idx >= total) return;
    int x = idx % W;
    int c = (idx / W) & 15;
    int b = idx / (W * 16);
    const float* xc  = X  + (size_t)((b * 16 + c) * H) * W + x;
    const float* p1c = FM + (size_t)((b * 64 + 16 + c) * H) * W + x;
    const float* p2c = FM + (size_t)((b * 64 + 48 + c) * H) * W + x;
    float* ocp = out + (size_t)((b * 16 + c) * H) * W + x;
    float hf1 = 0.f, hf2 = 0.f, hr1 = 0.f, hr2 = 0.f;
    float xfa = xc[0], pf1a = p1c[0], pf2a = p2c[0];
    float xra = xc[(H - 1) * W], pr1a = p1c[(H - 1) * W], pr2a = p2c[(H - 1) * W];
    float oa = ocp[0];
    float xfb = xc[W], pf1b = p1c[W], pf2b = p2c[W];
    float xrb = xc[(H - 2) * W], pr1b = p1c[(H - 2) * W], pr2b = p2c[(H - 2) * W];
    float ob = ocp[W];
    for (int i = 0; i < H; ++i) {
        float xfn = 0.f, pf1n = 0.f, pf2n = 0.f, xrn = 0.f, pr1n = 0.f, pr2n = 0.f, on = 0.f;
        if (i + 2 < H) {
            int yf = (i + 2) * W, yr = (H - 3 - i) * W;
            xfn = xc[yf]; pf1n = p1c[yf]; pf2n = p2c[yf];
            xrn = xc[yr]; pr1n = p1c[yr]; pr2n = p2c[yr];
            on = ocp[yf];
        }
        hf1 = fmaf(pf1a, hf1 - xfa, xfa);
        hf2 = fmaf(pf2a, hf2 - xfa, xfa);
        hr1 = fmaf(pr1a, hr1 - xra, xra);
        hr2 = fmaf(pr2a, hr2 - xra, xra);
        ocp[i * W] = fmaxf(fmaxf(oa, fmaxf(hf1, hf2)), fmaxf(hr1, hr2));
        xfa = xfb; pf1a = pf1b; pf2a = pf2b; xra = xrb; pr1a = pr1b; pr2a = pr2b; oa = ob;
        xfb = xfn; pf1b = pf1n; pf2b = pf2n; xrb = xrn; pr1b = pr1n; pr2b = pr2n; ob = on;
    }
}

// ---------------------------------------------------------------------------
extern "C" void kernel_launch(void* const* d_in, const int* in_sizes, int n_in,
                              void* d_out, int out_size, void* d_ws, size_t ws_size,
                              hipStream_t stream)
{
    const float* img = (const float*)d_in[0];
    const float* w1 = (const float*)d_in[1];  const float* b1 = (const float*)d_in[2];
    const float* w2 = (const float*)d_in[3];  const float* b2 = (const float*)d_in[4];
    const float* w3 = (const float*)d_in[5];  const float* b3 = (const float*)d_in[6];
    const float* w4 = (const float*)d_in[7];  const float* b4 = (const float*)d_in[8];
    const float* w5 = (const float*)d_in[9];  const float* b5 = (const float*)d_in[10];
    const float* w6 = (const float*)d_in[11]; const float* b6 = (const float*)d_in[12];
    const float* w7 = (const float*)d_in[13]; const float* b7 = (const float*)d_in[14];
    const float* w8 = (const float*)d_in[15]; const float* b8 = (const float*)d_in[16];
    const float* w9 = (const float*)d_in[17]; const float* b9 = (const float*)d_in[18];
    const float* wi = (const float*)d_in[19]; const float* bi = (const float*)d_in[20];
    const float* wo = (const float*)d_in[21]; const float* bo = (const float*)d_in[22];

    char* wsb = (char*)d_ws;
    const size_t MB = (size_t)(1u << 20);
    // live-range-checked layout, peak 209 MiB:
    float* x1    = (float*)(wsb);               // [0,32)    NCHW fp32
    float* p1    = (float*)(wsb + 32 * MB);     // [32,40)
    float* x2    = (float*)(wsb + 40 * MB);     // [40,56)
    float* p2    = (float*)(wsb + 56 * MB);     // [56,60)
    float* x3    = (float*)(wsb + 60 * MB);     // [60,64)
    float* p3    = (float*)(wsb + 64 * MB);     // [64,65)
    float* x4    = (float*)(wsb + 65 * MB);     // [65,66)
    float* p4    = (float*)(wsb + 66 * MB);     // [66,67)
    float* x5    = (float*)(wsb + 67 * MB);     // [67,68)
    float* cat6  = (float*)(wsb + 68 * MB);     // [68,71)
    float* x6    = (float*)(wsb + 71 * MB);     // [71,72)
    float* cat7  = (float*)(wsb + 72 * MB);     // [72,80)
    float* x7    = (float*)(wsb + 80 * MB);     // [80,84)
    unsigned short* cat8t = (unsigned short*)(wsb + 84 * MB);   // [84,100)  NHWC bf16
    unsigned short* x8t   = (unsigned short*)(wsb + 100 * MB);  // [100,108) NHWC bf16
    unsigned short* imgT  = (unsigned short*)(wsb + 128 * MB);  // [128,144) dead before xt9
    unsigned short* xt9   = (unsigned short*)(wsb + 128 * MB);  // [128,176) NHWC bf16
    float* fm    = (float*)(wsb);               // [0,128)  (x1..x8t dead at conv9)
    float* rnn   = (float*)(wsb + 128 * MB);    // [128,160) (xt9 dead after conv9)
    float* xin   = (float*)(wsb + 177 * MB);    // [177,209)
    unsigned short* wpk9 = (unsigned short*)(wsb + 176 * MB);   // 27648 sh
    unsigned short* wpk8 = wpk9 + 27648;
    unsigned short* wpk1 = wpk8 + 18432;
    unsigned short* wpki = wpk1 + 12800;
    float* outp = (float*)d_out;

    const int B = 8;

    // --- weight packs + img transpose ---
    wprep_all<<<248, 256, 0, stream>>>(w9, w8, w1, wi, wpk9, wpk8, wpk1, wpki);
    imgT_bf16<<<2048, 256, 0, stream>>>(img, imgT);

    // --- fused conv1 (relu) + input projection ---
    { dim3 grd(512, 8);
      conv1i_mfma<<<grd, 256, 0, stream>>>(imgT, wpk1, wpki, b1, bi, x1, xin); }

    // --- encoder (fp32 path) ---
    { int tot = B * 16 * 128 * 128;
      maxpool2_kernel<<<(tot + 255) / 256, 256, 0, stream>>>(x1, p1, tot, 128, 128); }
    conv_rt<3, 1, 4>(p1, w2, b2, x2, B, 16, 128, 128, 32, stream);
    { int tot = B * 32 * 64 * 64;
      maxpool2_kernel<<<(tot + 255) / 256, 256, 0, stream>>>(x2, p2, tot, 64, 64); }
    conv_s<3, 1>(p2, w3, b3, x3, B, 32, 64, 64, 32, stream);
    { int tot = B * 32 * 32 * 32;
      maxpool2_kernel<<<(tot + 255) / 256, 256, 0, stream>>>(x3, p3, tot, 32, 32); }
    conv_s<3, 1>(p3, w4, b4, x4, B, 32, 32, 32, 32, stream);
    { int tot = B * 32 * 16 * 16;
      maxpool2_kernel<<<(tot + 255) / 256, 256, 0, stream>>>(x4, p4, tot, 16, 16); }
    conv_s<3, 1>(p4, w5, b5, x5, B, 32, 16, 16, 64, stream);

    // --- decoder ---
    { int tot = B * 96 * 32 * 32;
      upcat_kernel<<<(tot + 255) / 256, 256, 0, stream>>>(x5, x4, cat6, B, 64, 32, 32, 32); }
    conv_s<3, 1>(cat6, w6, b6, x6, B, 96, 32, 32, 32, stream);
    { int tot = B * 64 * 64 * 64;
      upcat_kernel<<<(tot + 255) / 256, 256, 0, stream>>>(x6, x3, cat7, B, 32, 32, 64, 64); }
    conv_s<3, 1>(cat7, w7, b7, x7, B, 64, 64, 64, 32, stream);

    // --- stage 8: NHWC bf16 MFMA ---
    { int tot = 8 * 128 * 128;
      upcat8_nhwc<<<(tot + 255) / 256, 256, 0, stream>>>(x7, x2, cat8t); }
    { dim3 grd(128, 8);
      conv8_mfma<<<grd, 256, 0, stream>>>(cat8t, wpk8, b8, x8t); }

    // --- stage 9: NHWC bf16 MFMA ---
    { int tot = 8 * 256 * 256;
      upcat9_nhwc<<<(tot + 255) / 256, 256, 0, stream>>>(x8t, x1, xt9); }
    { dim3 grd(512, 8);
      conv9_mfma<<<grd, 256, 0, stream>>>(xt9, wpk9, b9, fm); }

    // --- spatial RNN: 8 directions via 2 fused kernels ---
    { int tot = B * 16 * 256; int g = (tot + 255) / 256;
      lrnn_wb<<<g, 256, 0, stream>>>(xin, fm, rnn, B, 256, 256);
      lrnn_hb<<<g, 256, 0, stream>>>(xin, fm, rnn, B, 256, 256); }

    // --- output head ---
    conv_rt<3, 3, 4>(rnn, wo, bo, outp, B, 16, 256, 256, 3, stream);
}

// Round 6
// 950.840 us; speedup vs baseline: 2.4425x; 1.1286x over previous
//
#include <hip/hip_runtime.h>
#include <math.h>

typedef __attribute__((ext_vector_type(8)))  short bf16x8;
typedef __attribute__((ext_vector_type(8)))  unsigned short u16x8;
typedef __attribute__((ext_vector_type(16))) float f32x16;

__device__ __forceinline__ unsigned short f2bf(float f) {
    unsigned u = __float_as_uint(f);
    unsigned r = (u + 0x7FFFu + ((u >> 16) & 1u)) >> 16;
    return (unsigned short)r;
}
__device__ __forceinline__ float bf2f(unsigned short h) {
    return __uint_as_float(((unsigned)h) << 16);
}
__device__ __forceinline__ unsigned pack2(unsigned short a, unsigned short b) {
    return (unsigned)a | ((unsigned)b << 16);
}
__device__ __forceinline__ float fast_tanh(float x) {
    float e = __expf(2.f * x);
    return 1.f - 2.f / (e + 1.f);
}

// ---------------------------------------------------------------------------
// Small-layer conv: 16x16 spatial tile, 8 oc/block (stages 3-7).
// ---------------------------------------------------------------------------
template<int K, int ACT, int OCB>
__global__ __launch_bounds__(256)
void conv2d_s(const float* __restrict__ in, const float* __restrict__ w,
              const float* __restrict__ bias, float* __restrict__ out,
              int B, int Cin, int H, int Wd, int Cout)
{
    constexpr int PAD = K / 2;
    constexpr int T = 16 + K - 1;
    constexpr int KK = K * K;
    constexpr int CH = 4;
    __shared__ float tile[CH][T][T + 1];

    const int tx = threadIdx.x, ty = threadIdx.y;
    const int tid = ty * 16 + tx;
    const int tilesX = (Wd + 15) >> 4;
    const int bx = blockIdx.x % tilesX, by = blockIdx.x / tilesX;
    const int x0 = bx * 16, y0 = by * 16;
    const int ox = x0 + tx, oy = y0 + ty;
    const int oc0 = blockIdx.y * OCB;
    const int b = blockIdx.z;

    int wb[OCB];
#pragma unroll
    for (int o = 0; o < OCB; ++o) {
        int oc = oc0 + o;
        if (oc > Cout - 1) oc = Cout - 1;
        wb[o] = oc * Cin * KK;
    }
    float acc[OCB];
#pragma unroll
    for (int o = 0; o < OCB; ++o) acc[o] = 0.f;

    for (int c0 = 0; c0 < Cin; c0 += CH) {
        int nc = Cin - c0; if (nc > CH) nc = CH;
        __syncthreads();
        for (int i = tid; i < nc * T * T; i += 256) {
            int cc = i / (T * T);
            int r = i - cc * T * T;
            int yy = r / T, xx = r - yy * T;
            int iy = y0 + yy - PAD, ix = x0 + xx - PAD;
            float v = 0.f;
            if (iy >= 0 && iy < H && ix >= 0 && ix < Wd)
                v = in[((b * Cin + c0 + cc) * H + iy) * Wd + ix];
            tile[cc][yy][xx] = v;
        }
        __syncthreads();
        for (int cc = 0; cc < nc; ++cc) {
            const float* wp = w + (c0 + cc) * KK;
#pragma unroll
            for (int ky = 0; ky < K; ++ky)
#pragma unroll
                for (int kx = 0; kx < K; ++kx) {
                    float v = tile[cc][ty + ky][tx + kx];
#pragma unroll
                    for (int o = 0; o < OCB; ++o)
                        acc[o] = fmaf(v, wp[wb[o] + ky * K + kx], acc[o]);
                }
        }
    }
    if (ox < Wd && oy < H) {
#pragma unroll
        for (int o = 0; o < OCB; ++o) {
            int oc = oc0 + o;
            if (oc < Cout) {
                float r = acc[o] + bias[oc];
                if (ACT == 1) r = fmaxf(r, 0.f);
                if (ACT == 2) r = fast_tanh(r);
                if (ACT == 3) r = 1.f / (1.f + __expf(-r));
                out[((b * Cout + oc) * H + oy) * Wd + ox] = r;
            }
        }
    }
}

template<int K, int ACT>
static inline void conv_s(const float* in, const float* w, const float* b, float* o,
                          int B, int Cin, int H, int W, int Cout, hipStream_t s)
{
    dim3 blk(16, 16, 1);
    int tcx = (W + 15) / 16, tcy = (H + 15) / 16;
    dim3 grd(tcx * tcy, (Cout + 7) / 8, B);
    hipLaunchKernelGGL((conv2d_s<K, ACT, 8>), grd, blk, 0, s, in, w, b, o, B, Cin, H, W, Cout);
}

// ---------------------------------------------------------------------------
// Big-layer fp32 conv (conv2, out-head): 32x32 tile, 4 px x 8 oc per thread.
// ---------------------------------------------------------------------------
template<int K, int ACT, int OCB, int CC>
__global__ __launch_bounds__(256)
void conv2d_rt(const float* __restrict__ in, const float* __restrict__ w,
               const float* __restrict__ bias, float* __restrict__ out,
               int B, int Cin, int H, int Wd, int Cout)
{
    constexpr int PAD = K / 2;
    constexpr int TW = 32, TH = 32;
    constexpr int T  = TW + K - 1;
    constexpr int TT = TH + K - 1;
    constexpr int LDW = T + 2;
    constexpr int KK = K * K;
    __shared__ float tile[CC][TT][LDW];

    const int tid = threadIdx.x;
    const int lx = tid & 31;
    const int ly = tid >> 5;
    const int tilesX = (Wd + TW - 1) / TW;
    const int bx = blockIdx.x % tilesX, by = blockIdx.x / tilesX;
    const int x0 = bx * TW, y0 = by * TH;
    const int oc0 = blockIdx.y * OCB;
    const int b = blockIdx.z;

    int woff[OCB];
#pragma unroll
    for (int o = 0; o < OCB; ++o) {
        int oc = oc0 + o;
        if (oc > Cout - 1) oc = Cout - 1;
        woff[o] = oc * Cin * KK;
    }
    float acc[4][OCB];
#pragma unroll
    for (int j = 0; j < 4; ++j)
#pragma unroll
        for (int o = 0; o < OCB; ++o) acc[j][o] = 0.f;

    for (int c0 = 0; c0 < Cin; c0 += CC) {
        __syncthreads();
        for (int i = tid; i < CC * TT * T; i += 256) {
            int cc = i / (TT * T);
            int r  = i - cc * (TT * T);
            int yy = r / T, xx = r - yy * T;
            int iy = y0 + yy - PAD, ix = x0 + xx - PAD;
            int ci = c0 + cc;
            float v = 0.f;
            if (iy >= 0 && iy < H && ix >= 0 && ix < Wd && ci < Cin)
                v = in[((b * Cin + ci) * H + iy) * Wd + ix];
            tile[cc][yy][xx] = v;
        }
        __syncthreads();
        int ncc = Cin - c0; if (ncc > CC) ncc = CC;
        for (int cc = 0; cc < ncc; ++cc) {
            const float* wch = w + (c0 + cc) * KK;
#pragma unroll
            for (int ky = 0; ky < K; ++ky)
#pragma unroll
                for (int kx = 0; kx < K; ++kx) {
                    float wv[OCB];
#pragma unroll
                    for (int o = 0; o < OCB; ++o)
                        wv[o] = wch[woff[o] + ky * K + kx];
#pragma unroll
                    for (int j = 0; j < 4; ++j) {
                        float v = tile[cc][ly + 8 * j + ky][lx + kx];
#pragma unroll
                        for (int o = 0; o < OCB; ++o)
                            acc[j][o] = fmaf(v, wv[o], acc[j][o]);
                    }
                }
        }
    }
    const int ox = x0 + lx;
    if (ox < Wd) {
#pragma unroll
        for (int j = 0; j < 4; ++j) {
            int oy = y0 + ly + 8 * j;
            if (oy < H) {
#pragma unroll
                for (int o = 0; o < OCB; ++o) {
                    int oc = oc0 + o;
                    if (oc < Cout) {
                        float r = acc[j][o] + bias[oc];
                        if (ACT == 1) r = fmaxf(r, 0.f);
                        if (ACT == 2) r = fast_tanh(r);
                        if (ACT == 3) r = 1.f / (1.f + __expf(-r));
                        out[((b * Cout + oc) * H + oy) * Wd + ox] = r;
                    }
                }
            }
        }
    }
}

template<int K, int ACT, int CC>
static inline void conv_rt(const float* in, const float* w, const float* b, float* o,
                           int B, int Cin, int H, int W, int Cout, hipStream_t s)
{
    constexpr int OCB = 8;
    dim3 blk(256, 1, 1);
    int tcx = (W + 31) / 32, tcy = (H + 31) / 32;
    dim3 grd(tcx * tcy, (Cout + OCB - 1) / OCB, B);
    hipLaunchKernelGGL((conv2d_rt<K, ACT, OCB, CC>), grd, blk, 0, s, in, w, b, o, B, Cin, H, W, Cout);
}

// ---------------------------------------------------------------------------
// maxpool / fp32 upcat (stages 6,7)
// ---------------------------------------------------------------------------
__global__ void maxpool2_kernel(const float* __restrict__ in, float* __restrict__ out,
                                int total, int Ho, int Wo)
{
    int idx = blockIdx.x * 256 + threadIdx.x;
    if (idx >= total) return;
    int x = idx % Wo;
    int t = idx / Wo;
    int y = t % Ho;
    int bc = t / Ho;
    int Wi = Wo * 2;
    const float* p = in + ((bc * 2 * Ho + 2 * y) * Wi + 2 * x);
    out[idx] = fmaxf(fmaxf(p[0], p[1]), fmaxf(p[Wi], p[Wi + 1]));
}

__device__ __forceinline__ void bilin_setup(int y, int x, int Hi, int Wi,
                                            int& i00, int& i01, int& i10, int& i11,
                                            float& wy, float& wx)
{
    float fy = 0.5f * y - 0.25f;
    float fx = 0.5f * x - 0.25f;
    float y0f = floorf(fy), x0f = floorf(fx);
    wy = fy - y0f; wx = fx - x0f;
    int yA = (int)y0f, xA = (int)x0f;
    int yB = yA + 1, xB = xA + 1;
    yA = yA < 0 ? 0 : (yA > Hi - 1 ? Hi - 1 : yA);
    yB = yB < 0 ? 0 : (yB > Hi - 1 ? Hi - 1 : yB);
    xA = xA < 0 ? 0 : (xA > Wi - 1 ? Wi - 1 : xA);
    xB = xB < 0 ? 0 : (xB > Wi - 1 ? Wi - 1 : xB);
    i00 = yA * Wi + xA; i01 = yA * Wi + xB;
    i10 = yB * Wi + xA; i11 = yB * Wi + xB;
}

__device__ __forceinline__ float bilin(const float* __restrict__ sp, int y, int x, int Hi, int Wi)
{
    int i00, i01, i10, i11; float wy, wx;
    bilin_setup(y, x, Hi, Wi, i00, i01, i10, i11, wy, wx);
    return (1.f - wy) * ((1.f - wx) * sp[i00] + wx * sp[i01]) +
           wy * ((1.f - wx) * sp[i10] + wx * sp[i11]);
}

__global__ void upcat_kernel(const float* __restrict__ up, const float* __restrict__ skip,
                             float* __restrict__ dst, int B, int C1, int C2, int H, int W)
{
    int total = B * (C1 + C2) * H * W;
    int idx = blockIdx.x * 256 + threadIdx.x;
    if (idx >= total) return;
    int x = idx % W;
    int t = idx / W;
    int y = t % H;
    t /= H;
    int c = t % (C1 + C2);
    int b = t / (C1 + C2);
    float r;
    if (c < C1) r = bilin(up + ((size_t)(b * C1 + c) * (H >> 1)) * (W >> 1), y, x, H >> 1, W >> 1);
    else        r = skip[((b * C2 + (c - C1)) * H + y) * W + x];
    dst[idx] = r;
}

// ---------------------------------------------------------------------------
// img [8][15][256][256] fp32 -> imgT [b][y][x][16] bf16 (ch15 = 0)
// ---------------------------------------------------------------------------
__global__ void imgT_bf16(const float* __restrict__ img, unsigned short* __restrict__ dst)
{
    int idx = blockIdx.x * 256 + threadIdx.x;
    if (idx >= 8 * 256 * 256) return;
    int x = idx & 255, y = (idx >> 8) & 255, b = idx >> 16;
    unsigned short v[16];
#pragma unroll
    for (int c = 0; c < 15; ++c)
        v[c] = f2bf(img[(size_t)(b * 15 + c) * 65536 + y * 256 + x]);
    v[15] = 0;
    uint4 lo = make_uint4(pack2(v[0], v[1]), pack2(v[2], v[3]), pack2(v[4], v[5]), pack2(v[6], v[7]));
    uint4 hi = make_uint4(pack2(v[8], v[9]), pack2(v[10], v[11]), pack2(v[12], v[13]), pack2(v[14], v[15]));
    *(uint4*)(dst + (size_t)idx * 16)     = lo;
    *(uint4*)(dst + (size_t)idx * 16 + 8) = hi;
}

// ---------------------------------------------------------------------------
// Pack all MFMA weights (bf16 A-fragments, A[m=lane&31][k=(lane>>5)*8+j]).
// ---------------------------------------------------------------------------
__global__ void wprep_all(const float* __restrict__ w9, const float* __restrict__ w8,
                          const float* __restrict__ w1, const float* __restrict__ wi,
                          unsigned short* __restrict__ wpk9, unsigned short* __restrict__ wpk8,
                          unsigned short* __restrict__ wpk1, unsigned short* __restrict__ wpki)
{
    int idx = blockIdx.x * 256 + threadIdx.x;
    if (idx < 27648) {
        int j = idx & 7;
        int t = idx >> 3;
        int lane = t & 63; t >>= 6;
        int mt = t & 1; t >>= 1;
        int kst = t % 3;
        int s = t / 3;
        int oc = mt * 32 + (lane & 31);
        int ci = kst * 16 + (lane >> 5) * 8 + j;
        wpk9[idx] = f2bf(w9[(oc * 48 + ci) * 9 + s]);
    } else if (idx < 46080) {
        int i = idx - 27648;
        int j = i & 7;
        int lane = (i >> 3) & 63;
        int t = i >> 9;
        int kst = t & 3;
        int s = t >> 2;
        int oc = lane & 31;
        int ci = kst * 16 + (lane >> 5) * 8 + j;
        wpk8[i] = f2bf(w8[(oc * 64 + ci) * 9 + s]);
    } else if (idx < 58880) {
        int i = idx - 46080;
        int j = i & 7;
        int lane = (i >> 3) & 63;
        int s = i >> 9;                 // 0..24
        int oc = lane & 31;
        int ci = (lane >> 5) * 8 + j;   // 0..15
        float v = 0.f;
        if (oc < 16 && ci < 15) v = w1[((oc * 15 + ci) * 5 + s / 5) * 5 + s % 5];
        wpk1[i] = f2bf(v);
    } else if (idx < 63488) {
        int i = idx - 58880;
        int j = i & 7;
        int lane = (i >> 3) & 63;
        int s = i >> 9;                 // 0..8
        int oc = lane & 31;
        int ci = (lane >> 5) * 8 + j;
        float v = 0.f;
        if (oc < 16 && ci < 15) v = wi[((oc * 15 + ci) * 3 + s / 3) * 3 + s % 3];
        wpki[i] = f2bf(v);
    }
}

// ---------------------------------------------------------------------------
// Fused conv1 (5x5, relu -> x1 NCHW fp32) + conv_i (3x3 -> xin NCHW fp32).
// ---------------------------------------------------------------------------
__global__ __launch_bounds__(256)
void conv1i_mfma(const unsigned short* __restrict__ imgT,
                 const unsigned short* __restrict__ wpk1,
                 const unsigned short* __restrict__ wpki,
                 const float* __restrict__ b1, const float* __restrict__ bi,
                 float* __restrict__ x1, float* __restrict__ xin)
{
    __shared__ __align__(16) unsigned short smem[2 * 5 * 132 * 8];  // 21120 B

    const int tid  = threadIdx.x;
    const int lane = tid & 63;
    const int wv   = tid >> 6;
    const int n    = lane & 31;
    const int q    = lane >> 5;
    const int y    = blockIdx.x >> 1;
    const int x0   = (blockIdx.x & 1) * 128;
    const int b    = blockIdx.y;

    for (int i = tid; i < 5 * 132 * 2; i += 256) {
        int r   = i / 264;
        int rem = i - r * 264;
        int xi  = rem >> 1;
        int g   = rem & 1;
        int yg = y + r - 2;
        int xg = x0 - 2 + xi;
        uint4 v = make_uint4(0, 0, 0, 0);
        if (yg >= 0 && yg < 256 && xg >= 0 && xg < 256)
            v = *(const uint4*)(imgT + (((size_t)(b * 256 + yg) * 256 + xg) * 16 + g * 8));
        *(uint4*)(&smem[((g * 5 + r) * 132 + xi) * 8]) = v;
    }
    __syncthreads();

    f32x16 acc1, acci;
#pragma unroll
    for (int i = 0; i < 16; ++i) { acc1[i] = 0.f; acci[i] = 0.f; }

    const int pxl = wv * 32 + n;
    const unsigned short* wb1 = wpk1 + lane * 8;
    const unsigned short* wbi = wpki + lane * 8;

#pragma unroll
    for (int s = 0; s < 25; ++s) {
        const int dy = s / 5, dx = s % 5;
        bf16x8 bfrag = *(const bf16x8*)(&smem[((q * 5 + dy) * 132 + pxl + dx) * 8]);
        bf16x8 a = *(const bf16x8*)(wb1 + s * 512);
        acc1 = __builtin_amdgcn_mfma_f32_32x32x16_bf16(a, bfrag, acc1, 0, 0, 0);
    }
#pragma unroll
    for (int s = 0; s < 9; ++s) {
        const int dy = s / 3, dx = s % 3;
        bf16x8 bfrag = *(const bf16x8*)(&smem[((q * 5 + dy + 1) * 132 + pxl + dx + 1) * 8]);
        bf16x8 a = *(const bf16x8*)(wbi + s * 512);
        acci = __builtin_amdgcn_mfma_f32_32x32x16_bf16(a, bfrag, acci, 0, 0, 0);
    }

    const int px = x0 + pxl;
#pragma unroll
    for (int reg = 0; reg < 8; ++reg) {          // rows 0..15 only (Cout=16)
        int row = (reg & 3) + 8 * (reg >> 2) + 4 * q;
        x1 [((size_t)(b * 16 + row) * 256 + y) * 256 + px] = fmaxf(acc1[reg] + b1[row], 0.f);
        xin[((size_t)(b * 16 + row) * 256 + y) * 256 + px] = acci[reg] + bi[row];
    }
}

// ---------------------------------------------------------------------------
// upcat8 -> cat8t NHWC bf16 [b][128][128][64]
// ---------------------------------------------------------------------------
__global__ void upcat8_nhwc(const float* __restrict__ x7, const float* __restrict__ x2,
                            unsigned short* __restrict__ dst)
{
    int idx = blockIdx.x * 256 + threadIdx.x;
    if (idx >= 8 * 128 * 128) return;
    int x = idx & 127, y = (idx >> 7) & 127, b = idx >> 14;
    int i00, i01, i10, i11; float wy, wx;
    bilin_setup(y, x, 64, 64, i00, i01, i10, i11, wy, wx);
    const float* base7 = x7 + (size_t)b * 32 * 4096;
    const float* base2 = x2 + (size_t)b * 32 * 16384 + y * 128 + x;
    unsigned short* d = dst + (size_t)idx * 64;
#pragma unroll
    for (int g = 0; g < 8; ++g) {
        u16x8 r;
#pragma unroll
        for (int j = 0; j < 8; ++j) {
            int c = g * 8 + j;
            float v;
            if (c < 32) {
                const float* sp = base7 + c * 4096;
                v = (1.f - wy) * ((1.f - wx) * sp[i00] + wx * sp[i01]) +
                    wy * ((1.f - wx) * sp[i10] + wx * sp[i11]);
            } else {
                v = base2[(size_t)(c - 32) * 16384];
            }
            r[j] = f2bf(v);
        }
        *(u16x8*)(d + g * 8) = r;
    }
}

// ---------------------------------------------------------------------------
// conv8 MFMA: Cin=64, Cout=32, 128x128, relu -> x8t NHWC bf16.
// ---------------------------------------------------------------------------
__global__ __launch_bounds__(256)
void conv8_mfma(const unsigned short* __restrict__ cat8t,
                const unsigned short* __restrict__ wpk8,
                const float* __restrict__ bias,
                unsigned short* __restrict__ x8t)
{
    __shared__ __align__(16) unsigned short smem[8 * 3 * 130 * 8];  // 49920 B

    const int tid  = threadIdx.x;
    const int lane = tid & 63;
    const int wv   = tid >> 6;
    const int n    = lane & 31;
    const int q    = lane >> 5;
    const int y    = blockIdx.x;
    const int b    = blockIdx.y;

    for (int i = tid; i < 3 * 130 * 8; i += 256) {
        int r   = i / 1040;
        int rem = i - r * 1040;
        int xi  = rem >> 3;
        int g   = rem & 7;
        int yg = y + r - 1;
        int xg = xi - 1;
        uint4 v = make_uint4(0, 0, 0, 0);
        if (yg >= 0 && yg < 128 && xg >= 0 && xg < 128)
            v = *(const uint4*)(cat8t + (((size_t)(b * 128 + yg) * 128 + xg) * 64 + g * 8));
        *(uint4*)(&smem[((g * 3 + r) * 130 + xi) * 8]) = v;
    }
    __syncthreads();

    f32x16 acc;
#pragma unroll
    for (int i = 0; i < 16; ++i) acc[i] = 0.f;

    const int pxl = wv * 32 + n;
    const unsigned short* wbase = wpk8 + lane * 8;

#pragma unroll
    for (int s = 0; s < 9; ++s) {
        const int dy = s / 3, dx = s % 3;
        const int xi = pxl + dx;
#pragma unroll
        for (int kst = 0; kst < 4; ++kst) {
            const int g = kst * 2 + q;
            bf16x8 bfrag = *(const bf16x8*)(&smem[((g * 3 + dy) * 130 + xi) * 8]);
            bf16x8 a = *(const bf16x8*)(wbase + (s * 4 + kst) * 512);
            acc = __builtin_amdgcn_mfma_f32_32x32x16_bf16(a, bfrag, acc, 0, 0, 0);
        }
    }

    size_t base = ((size_t)(b * 128 + y) * 128 + pxl) * 32;
#pragma unroll
    for (int rg = 0; rg < 4; ++rg) {
        int oc0 = 8 * rg + 4 * q;
        unsigned short s0 = f2bf(fmaxf(acc[rg * 4 + 0] + bias[oc0 + 0], 0.f));
        unsigned short s1 = f2bf(fmaxf(acc[rg * 4 + 1] + bias[oc0 + 1], 0.f));
        unsigned short s2 = f2bf(fmaxf(acc[rg * 4 + 2] + bias[oc0 + 2], 0.f));
        unsigned short s3 = f2bf(fmaxf(acc[rg * 4 + 3] + bias[oc0 + 3], 0.f));
        uint2 v = make_uint2(pack2(s0, s1), pack2(s2, s3));
        *(uint2*)(x8t + base + oc0) = v;
    }
}

// ---------------------------------------------------------------------------
// upcat9 -> xt9 NHWC bf16 [b][256][256][48]
// ---------------------------------------------------------------------------
__global__ void upcat9_nhwc(const unsigned short* __restrict__ x8t,
                            const float* __restrict__ x1,
                            unsigned short* __restrict__ dst)
{
    int idx = blockIdx.x * 256 + threadIdx.x;
    if (idx >= 8 * 256 * 256) return;
    int x = idx & 255, y = (idx >> 8) & 255, b = idx >> 16;
    int i00, i01, i10, i11; float wy, wx;
    bilin_setup(y, x, 128, 128, i00, i01, i10, i11, wy, wx);
    const unsigned short* sb = x8t + (size_t)b * 128 * 128 * 32;
    unsigned short* d = dst + (size_t)idx * 48;
    float w00 = (1.f - wy) * (1.f - wx), w01 = (1.f - wy) * wx;
    float w10 = wy * (1.f - wx),         w11 = wy * wx;
#pragma unroll
    for (int g = 0; g < 4; ++g) {
        u16x8 v00 = *(const u16x8*)(sb + (size_t)i00 * 32 + g * 8);
        u16x8 v01 = *(const u16x8*)(sb + (size_t)i01 * 32 + g * 8);
        u16x8 v10 = *(const u16x8*)(sb + (size_t)i10 * 32 + g * 8);
        u16x8 v11 = *(const u16x8*)(sb + (size_t)i11 * 32 + g * 8);
        u16x8 r;
#pragma unroll
        for (int j = 0; j < 8; ++j) {
            float v = w00 * bf2f(v00[j]) + w01 * bf2f(v01[j]) +
                      w10 * bf2f(v10[j]) + w11 * bf2f(v11[j]);
            r[j] = f2bf(v);
        }
        *(u16x8*)(d + g * 8) = r;
    }
    const float* x1b = x1 + (size_t)b * 16 * 65536 + y * 256 + x;
#pragma unroll
    for (int g = 0; g < 2; ++g) {
        u16x8 r;
#pragma unroll
        for (int j = 0; j < 8; ++j)
            r[j] = f2bf(x1b[(size_t)(g * 8 + j) * 65536]);
        *(u16x8*)(d + 32 + g * 8) = r;
    }
}

// ---------------------------------------------------------------------------
// conv9 MFMA: K=48, 64 oc, 256x256, tanh -> fm NCHW fp32.
// ---------------------------------------------------------------------------
__global__ __launch_bounds__(256)
void conv9_mfma(const unsigned short* __restrict__ xt9,
                const unsigned short* __restrict__ wpk,
                const float* __restrict__ bias,
                float* __restrict__ fm)
{
    __shared__ __align__(16) unsigned short smem[6 * 3 * 130 * 8];  // 37440 B

    const int tid  = threadIdx.x;
    const int lane = tid & 63;
    const int wv   = tid >> 6;
    const int n    = lane & 31;
    const int q    = lane >> 5;
    const int y    = blockIdx.x >> 1;
    const int x0   = (blockIdx.x & 1) * 128;
    const int b    = blockIdx.y;

    for (int i = tid; i < 3 * 130 * 6; i += 256) {
        int r   = i / 780;
        int rem = i - r * 780;
        int xi  = rem / 6;
        int g   = rem - xi * 6;
        int yg = y + r - 1;
        int xg = x0 - 1 + xi;
        uint4 v = make_uint4(0, 0, 0, 0);
        if (yg >= 0 && yg < 256 && xg >= 0 && xg < 256)
            v = *(const uint4*)(xt9 + (((size_t)(b * 256 + yg) * 256 + xg) * 48 + g * 8));
        *(uint4*)(&smem[((g * 3 + r) * 130 + xi) * 8]) = v;
    }
    __syncthreads();

    f32x16 acc0, acc1;
#pragma unroll
    for (int i = 0; i < 16; ++i) { acc0[i] = 0.f; acc1[i] = 0.f; }

    const int pxl = wv * 32 + n;
    const unsigned short* wbase = wpk + lane * 8;

#pragma unroll
    for (int s = 0; s < 9; ++s) {
        const int dy = s / 3, dx = s % 3;
        const int xi = pxl + dx;
#pragma unroll
        for (int kst = 0; kst < 3; ++kst) {
            const int g = kst * 2 + q;
            bf16x8 bfrag = *(const bf16x8*)(&smem[((g * 3 + dy) * 130 + xi) * 8]);
            bf16x8 a0 = *(const bf16x8*)(wbase + ((s * 3 + kst) * 2 + 0) * 512);
            bf16x8 a1 = *(const bf16x8*)(wbase + ((s * 3 + kst) * 2 + 1) * 512);
            acc0 = __builtin_amdgcn_mfma_f32_32x32x16_bf16(a0, bfrag, acc0, 0, 0, 0);
            acc1 = __builtin_amdgcn_mfma_f32_32x32x16_bf16(a1, bfrag, acc1, 0, 0, 0);
        }
    }

    const int px = x0 + pxl;
#pragma unroll
    for (int reg = 0; reg < 16; ++reg) {
        int row = (reg & 3) + 8 * (reg >> 2) + 4 * q;
        int oc0 = row, oc1 = 32 + row;
        fm[(((size_t)b * 64 + oc0) * 256 + y) * 256 + px] = fast_tanh(acc0[reg] + bias[oc0]);
        fm[(((size_t)b * 64 + oc1) * 256 + y) * 256 + px] = fast_tanh(acc1[reg] + bias[oc1]);
    }
}

// ---------------------------------------------------------------------------
// LDS-tiled W-direction LRNN pair (fwd+rev), initializes out (rnn).
// Block: one (b,c), 128-row band. Thread: r = t&127, d = t>>7.
// Walks 16 column-chunks; loads [128 rows][16 x] line-exact tiles for both
// directions (rev chunk mirrored), scans in registers, max-combines fwd/rev
// in LDS (m values overwrite the consumed x-tile), one coalesced store.
// fwd step s and rev step s both emit to out position s (rev stays flipped).
// Gates: fm channels {c, 32+c} for both directions.
// ---------------------------------------------------------------------------
__global__ __launch_bounds__(256)
void lrnn_wt(const float* __restrict__ X, const float* __restrict__ FM,
             float* __restrict__ out)
{
    __shared__ float tiles[2][3][16][130];   // [dir][stream][xi][row] 49920 B

    const int tid = threadIdx.x;
    const int r   = tid & 127;
    const int d   = tid >> 7;
    const int yb  = blockIdx.x & 1;
    const int c   = (blockIdx.x >> 1) & 15;
    const int b   = blockIdx.x >> 5;
    const int y0  = yb * 128;

    const size_t xin_base = ((size_t)(b * 16 + c) * 256 + y0) * 256;
    const size_t p1_base  = ((size_t)(b * 64 + c) * 256 + y0) * 256;
    const size_t p2_base  = ((size_t)(b * 64 + 32 + c) * 256 + y0) * 256;

    float h1 = 0.f, h2 = 0.f;

    for (int k = 0; k < 16; ++k) {
        const int xsf = 16 * k;
        const int xsr = 240 - 16 * k;

        // ---- stage: 2 dirs x 3 streams x 128 rows x 16 x (float4 loads) ----
        for (int i = tid; i < 3072; i += 256) {
            int f4 = i & 3;
            int rr = (i >> 2) & 127;
            int v  = i >> 9;           // 0..5
            int s  = v % 3;
            int dd = v / 3;
            int xs = dd ? xsr : xsf;
            const float* sp = (s == 0) ? X : FM;
            size_t off = (s == 0 ? xin_base : (s == 1 ? p1_base : p2_base))
                       + (size_t)rr * 256 + xs + f4 * 4;
            float4 vv = *(const float4*)(sp + off);
            tiles[dd][s][f4 * 4 + 0][rr] = vv.x;
            tiles[dd][s][f4 * 4 + 1][rr] = vv.y;
            tiles[dd][s][f4 * 4 + 2][rr] = vv.z;
            tiles[dd][s][f4 * 4 + 3][rr] = vv.w;
        }
        __syncthreads();

        // ---- scan 16 steps (wave-uniform branch: d = tid>>7) ----
        if (d == 0) {
#pragma unroll
            for (int xi = 0; xi < 16; ++xi) {
                float xv = tiles[0][0][xi][r];
                float p1 = tiles[0][1][xi][r];
                float p2 = tiles[0][2][xi][r];
                h1 = fmaf(p1, h1 - xv, xv);
                h2 = fmaf(p2, h2 - xv, xv);
                tiles[0][0][xi][r] = fmaxf(h1, h2);
            }
        } else {
#pragma unroll
            for (int xi = 0; xi < 16; ++xi) {
                float xv = tiles[1][0][15 - xi][r];
                float p1 = tiles[1][1][15 - xi][r];
                float p2 = tiles[1][2][15 - xi][r];
                h1 = fmaf(p1, h1 - xv, xv);
                h2 = fmaf(p2, h2 - xv, xv);
                tiles[1][0][15 - xi][r] = fmaxf(h1, h2);   // slot 15-xi holds step xi
            }
        }
        __syncthreads();

        // ---- combine fwd/rev + coalesced write of out chunk [128][16] ----
        for (int i = tid; i < 512; i += 256) {
            int f4 = i & 3;
            int rr = i >> 2;
            float4 m;
            m.x = fmaxf(tiles[0][0][f4 * 4 + 0][rr], tiles[1][0][15 - (f4 * 4 + 0)][rr]);
            m.y = fmaxf(tiles[0][0][f4 * 4 + 1][rr], tiles[1][0][15 - (f4 * 4 + 1)][rr]);
            m.z = fmaxf(tiles[0][0][f4 * 4 + 2][rr], tiles[1][0][15 - (f4 * 4 + 2)][rr]);
            m.w = fmaxf(tiles[0][0][f4 * 4 + 3][rr], tiles[1][0][15 - (f4 * 4 + 3)][rr]);
            *(float4*)(out + xin_base + (size_t)rr * 256 + xsf + f4 * 4) = m;
        }
        // next chunk's load barrier separates this combine from tile overwrite
    }
}

// ---------------------------------------------------------------------------
// Fused H-direction LRNN pair (fwd + rev), max-accumulates into out.
// ---------------------------------------------------------------------------
__global__ void lrnn_hb(const float* __restrict__ X, const float* __restrict__ FM,
                        float* __restrict__ out, int B, int H, int W)
{
    int total = B * 16 * W;
    int idx = blockIdx.x * 256 + threadIdx.x;
    if (idx >= total) return;
    int x = idx % W;
    int c = (idx / W) & 15;
    int b = idx / (W * 16);
    const float* xc  = X  + (size_t)((b * 16 + c) * H) * W + x;
    const float* p1c = FM + (size_t)((b * 64 + 16 + c) * H) * W + x;
    const float* p2c = FM + (size_t)((b * 64 + 48 + c) * H) * W + x;
    float* ocp = out + (size_t)((b * 16 + c) * H) * W + x;
    float hf1 = 0.f, hf2 = 0.f, hr1 = 0.f, hr2 = 0.f;
    float xfa = xc[0], pf1a = p1c[0], pf2a = p2c[0];
    float xra = xc[(H - 1) * W], pr1a = p1c[(H - 1) * W], pr2a = p2c[(H - 1) * W];
    float oa = ocp[0];
    float xfb = xc[W], pf1b = p1c[W], pf2b = p2c[W];
    float xrb = xc[(H - 2) * W], pr1b = p1c[(H - 2) * W], pr2b = p2c[(H - 2) * W];
    float ob = ocp[W];
    for (int i = 0; i < H; ++i) {
        float xfn = 0.f, pf1n = 0.f, pf2n = 0.f, xrn = 0.f, pr1n = 0.f, pr2n = 0.f, on = 0.f;
        if (i + 2 < H) {
            int yf = (i + 2) * W, yr = (H - 3 - i) * W;
            xfn = xc[yf]; pf1n = p1c[yf]; pf2n = p2c[yf];
            xrn = xc[yr]; pr1n = p1c[yr]; pr2n = p2c[yr];
            on = ocp[yf];
        }
        hf1 = fmaf(pf1a, hf1 - xfa, xfa);
        hf2 = fmaf(pf2a, hf2 - xfa, xfa);
        hr1 = fmaf(pr1a, hr1 - xra, xra);
        hr2 = fmaf(pr2a, hr2 - xra, xra);
        ocp[i * W] = fmaxf(fmaxf(oa, fmaxf(hf1, hf2)), fmaxf(hr1, hr2));
        xfa = xfb; pf1a = pf1b; pf2a = pf2b; xra = xrb; pr1a = pr1b; pr2a = pr2b; oa = ob;
        xfb = xfn; pf1b = pf1n; pf2b = pf2n; xrb = xrn; pr1b = pr1n; pr2b = pr2n; ob = on;
    }
}

// ---------------------------------------------------------------------------
extern "C" void kernel_launch(void* const* d_in, const int* in_sizes, int n_in,
                              void* d_out, int out_size, void* d_ws, size_t ws_size,
                              hipStream_t stream)
{
    const float* img = (const float*)d_in[0];
    const float* w1 = (const float*)d_in[1];  const float* b1 = (const float*)d_in[2];
    const float* w2 = (const float*)d_in[3];  const float* b2 = (const float*)d_in[4];
    const float* w3 = (const float*)d_in[5];  const float* b3 = (const float*)d_in[6];
    const float* w4 = (const float*)d_in[7];  const float* b4 = (const float*)d_in[8];
    const float* w5 = (const float*)d_in[9];  const float* b5 = (const float*)d_in[10];
    const float* w6 = (const float*)d_in[11]; const float* b6 = (const float*)d_in[12];
    const float* w7 = (const float*)d_in[13]; const float* b7 = (const float*)d_in[14];
    const float* w8 = (const float*)d_in[15]; const float* b8 = (const float*)d_in[16];
    const float* w9 = (const float*)d_in[17]; const float* b9 = (const float*)d_in[18];
    const float* wi = (const float*)d_in[19]; const float* bi = (const float*)d_in[20];
    const float* wo = (const float*)d_in[21]; const float* bo = (const float*)d_in[22];

    char* wsb = (char*)d_ws;
    const size_t MB = (size_t)(1u << 20);
    float* x1    = (float*)(wsb);               // [0,32)    NCHW fp32
    float* p1    = (float*)(wsb + 32 * MB);     // [32,40)
    float* x2    = (float*)(wsb + 40 * MB);     // [40,56)
    float* p2    = (float*)(wsb + 56 * MB);     // [56,60)
    float* x3    = (float*)(wsb + 60 * MB);     // [60,64)
    float* p3    = (float*)(wsb + 64 * MB);     // [64,65)
    float* x4    = (float*)(wsb + 65 * MB);     // [65,66)
    float* p4    = (float*)(wsb + 66 * MB);     // [66,67)
    float* x5    = (float*)(wsb + 67 * MB);     // [67,68)
    float* cat6  = (float*)(wsb + 68 * MB);     // [68,71)
    float* x6    = (float*)(wsb + 71 * MB);     // [71,72)
    float* cat7  = (float*)(wsb + 72 * MB);     // [72,80)
    float* x7    = (float*)(wsb + 80 * MB);     // [80,84)
    unsigned short* cat8t = (unsigned short*)(wsb + 84 * MB);   // [84,100)  NHWC bf16
    unsigned short* x8t   = (unsigned short*)(wsb + 100 * MB);  // [100,108) NHWC bf16
    unsigned short* imgT  = (unsigned short*)(wsb + 128 * MB);  // [128,144) dead before xt9
    unsigned short* xt9   = (unsigned short*)(wsb + 128 * MB);  // [128,176) NHWC bf16
    float* fm    = (float*)(wsb);               // [0,128)  (x1..x8t dead at conv9)
    float* rnn   = (float*)(wsb + 128 * MB);    // [128,160) (xt9 dead after conv9)
    float* xin   = (float*)(wsb + 177 * MB);    // [177,209)
    unsigned short* wpk9 = (unsigned short*)(wsb + 176 * MB);   // 27648 sh
    unsigned short* wpk8 = wpk9 + 27648;
    unsigned short* wpk1 = wpk8 + 18432;
    unsigned short* wpki = wpk1 + 12800;
    float* outp = (float*)d_out;

    const int B = 8;

    // --- weight packs + img transpose ---
    wprep_all<<<248, 256, 0, stream>>>(w9, w8, w1, wi, wpk9, wpk8, wpk1, wpki);
    imgT_bf16<<<2048, 256, 0, stream>>>(img, imgT);

    // --- fused conv1 (relu) + input projection ---
    { dim3 grd(512, 8);
      conv1i_mfma<<<grd, 256, 0, stream>>>(imgT, wpk1, wpki, b1, bi, x1, xin); }

    // --- encoder (fp32 path) ---
    { int tot = B * 16 * 128 * 128;
      maxpool2_kernel<<<(tot + 255) / 256, 256, 0, stream>>>(x1, p1, tot, 128, 128); }
    conv_rt<3, 1, 4>(p1, w2, b2, x2, B, 16, 128, 128, 32, stream);
    { int tot = B * 32 * 64 * 64;
      maxpool2_kernel<<<(tot + 255) / 256, 256, 0, stream>>>(x2, p2, tot, 64, 64); }
    conv_s<3, 1>(p2, w3, b3, x3, B, 32, 64, 64, 32, stream);
    { int tot = B * 32 * 32 * 32;
      maxpool2_kernel<<<(tot + 255) / 256, 256, 0, stream>>>(x3, p3, tot, 32, 32); }
    conv_s<3, 1>(p3, w4, b4, x4, B, 32, 32, 32, 32, stream);
    { int tot = B * 32 * 16 * 16;
      maxpool2_kernel<<<(tot + 255) / 256, 256, 0, stream>>>(x4, p4, tot, 16, 16); }
    conv_s<3, 1>(p4, w5, b5, x5, B, 32, 16, 16, 64, stream);

    // --- decoder ---
    { int tot = B * 96 * 32 * 32;
      upcat_kernel<<<(tot + 255) / 256, 256, 0, stream>>>(x5, x4, cat6, B, 64, 32, 32, 32); }
    conv_s<3, 1>(cat6, w6, b6, x6, B, 96, 32, 32, 32, stream);
    { int tot = B * 64 * 64 * 64;
      upcat_kernel<<<(tot + 255) / 256, 256, 0, stream>>>(x6, x3, cat7, B, 32, 32, 64, 64); }
    conv_s<3, 1>(cat7, w7, b7, x7, B, 64, 64, 64, 32, stream);

    // --- stage 8: NHWC bf16 MFMA ---
    { int tot = 8 * 128 * 128;
      upcat8_nhwc<<<(tot + 255) / 256, 256, 0, stream>>>(x7, x2, cat8t); }
    { dim3 grd(128, 8);
      conv8_mfma<<<grd, 256, 0, stream>>>(cat8t, wpk8, b8, x8t); }

    // --- stage 9: NHWC bf16 MFMA ---
    { int tot = 8 * 256 * 256;
      upcat9_nhwc<<<(tot + 255) / 256, 256, 0, stream>>>(x8t, x1, xt9); }
    { dim3 grd(512, 8);
      conv9_mfma<<<grd, 256, 0, stream>>>(xt9, wpk9, b9, fm); }

    // --- spatial RNN: W pair (LDS-tiled, coalesced) then H pair ---
    lrnn_wt<<<256, 256, 0, stream>>>(xin, fm, rnn);
    { int tot = B * 16 * 256; int g = (tot + 255) / 256;
      lrnn_hb<<<g, 256, 0, stream>>>(xin, fm, rnn, B, 256, 256); }

    // --- output head ---
    conv_rt<3, 3, 4>(rnn, wo, bo, outp, B, 16, 256, 256, 3, stream);
}

// Round 7
// 582.355 us; speedup vs baseline: 3.9880x; 1.6327x over previous
//
#include <hip/hip_runtime.h>
#include <math.h>

typedef __attribute__((ext_vector_type(8)))  short bf16x8;
typedef __attribute__((ext_vector_type(8)))  unsigned short u16x8;
typedef __attribute__((ext_vector_type(16))) float f32x16;

__device__ __forceinline__ unsigned short f2bf(float f) {
    unsigned u = __float_as_uint(f);
    unsigned r = (u + 0x7FFFu + ((u >> 16) & 1u)) >> 16;
    return (unsigned short)r;
}
__device__ __forceinline__ float bf2f(unsigned short h) {
    return __uint_as_float(((unsigned)h) << 16);
}
__device__ __forceinline__ unsigned pack2(unsigned short a, unsigned short b) {
    return (unsigned)a | ((unsigned)b << 16);
}
__device__ __forceinline__ float fast_tanh(float x) {
    float e = __expf(2.f * x);
    return 1.f - 2.f / (e + 1.f);
}

// ---------------------------------------------------------------------------
// Out-head fp32 conv (rnn NCHW fp32 -> sigmoid): 32x32 tile, 4px x 8oc.
// ---------------------------------------------------------------------------
template<int K, int ACT, int OCB, int CC>
__global__ __launch_bounds__(256)
void conv2d_rt(const float* __restrict__ in, const float* __restrict__ w,
               const float* __restrict__ bias, float* __restrict__ out,
               int B, int Cin, int H, int Wd, int Cout)
{
    constexpr int PAD = K / 2;
    constexpr int TW = 32, TH = 32;
    constexpr int T  = TW + K - 1;
    constexpr int TT = TH + K - 1;
    constexpr int LDW = T + 2;
    constexpr int KK = K * K;
    __shared__ float tile[CC][TT][LDW];

    const int tid = threadIdx.x;
    const int lx = tid & 31;
    const int ly = tid >> 5;
    const int tilesX = (Wd + TW - 1) / TW;
    const int bx = blockIdx.x % tilesX, by = blockIdx.x / tilesX;
    const int x0 = bx * TW, y0 = by * TH;
    const int oc0 = blockIdx.y * OCB;
    const int b = blockIdx.z;

    int woff[OCB];
#pragma unroll
    for (int o = 0; o < OCB; ++o) {
        int oc = oc0 + o;
        if (oc > Cout - 1) oc = Cout - 1;
        woff[o] = oc * Cin * KK;
    }
    float acc[4][OCB];
#pragma unroll
    for (int j = 0; j < 4; ++j)
#pragma unroll
        for (int o = 0; o < OCB; ++o) acc[j][o] = 0.f;

    for (int c0 = 0; c0 < Cin; c0 += CC) {
        __syncthreads();
        for (int i = tid; i < CC * TT * T; i += 256) {
            int cc = i / (TT * T);
            int r  = i - cc * (TT * T);
            int yy = r / T, xx = r - yy * T;
            int iy = y0 + yy - PAD, ix = x0 + xx - PAD;
            int ci = c0 + cc;
            float v = 0.f;
            if (iy >= 0 && iy < H && ix >= 0 && ix < Wd && ci < Cin)
                v = in[((b * Cin + ci) * H + iy) * Wd + ix];
            tile[cc][yy][xx] = v;
        }
        __syncthreads();
        int ncc = Cin - c0; if (ncc > CC) ncc = CC;
        for (int cc = 0; cc < ncc; ++cc) {
            const float* wch = w + (c0 + cc) * KK;
#pragma unroll
            for (int ky = 0; ky < K; ++ky)
#pragma unroll
                for (int kx = 0; kx < K; ++kx) {
                    float wv[OCB];
#pragma unroll
                    for (int o = 0; o < OCB; ++o)
                        wv[o] = wch[woff[o] + ky * K + kx];
#pragma unroll
                    for (int j = 0; j < 4; ++j) {
                        float v = tile[cc][ly + 8 * j + ky][lx + kx];
#pragma unroll
                        for (int o = 0; o < OCB; ++o)
                            acc[j][o] = fmaf(v, wv[o], acc[j][o]);
                    }
                }
        }
    }
    const int ox = x0 + lx;
    if (ox < Wd) {
#pragma unroll
        for (int j = 0; j < 4; ++j) {
            int oy = y0 + ly + 8 * j;
            if (oy < H) {
#pragma unroll
                for (int o = 0; o < OCB; ++o) {
                    int oc = oc0 + o;
                    if (oc < Cout) {
                        float r = acc[j][o] + bias[oc];
                        if (ACT == 1) r = fmaxf(r, 0.f);
                        if (ACT == 3) r = 1.f / (1.f + __expf(-r));
                        out[((b * Cout + oc) * H + oy) * Wd + ox] = r;
                    }
                }
            }
        }
    }
}

template<int K, int ACT, int CC>
static inline void conv_rt(const float* in, const float* w, const float* b, float* o,
                           int B, int Cin, int H, int W, int Cout, hipStream_t s)
{
    constexpr int OCB = 8;
    dim3 blk(256, 1, 1);
    int tcx = (W + 31) / 32, tcy = (H + 31) / 32;
    dim3 grd(tcx * tcy, (Cout + OCB - 1) / OCB, B);
    hipLaunchKernelGGL((conv2d_rt<K, ACT, OCB, CC>), grd, blk, 0, s, in, w, b, o, B, Cin, H, W, Cout);
}

// ---------------------------------------------------------------------------
// NHWC bf16 2x2 maxpool (stride 2). C8 = C/8 vector groups.
// ---------------------------------------------------------------------------
__global__ void pool_nhwc(const unsigned short* __restrict__ in,
                          unsigned short* __restrict__ out,
                          int Ho, int Wo, int C8)
{
    int idx = blockIdx.x * 256 + threadIdx.x;
    int total = 8 * Ho * Wo * C8;
    if (idx >= total) return;
    int g = idx % C8;
    int p = idx / C8;
    int x = p % Wo;
    int y = (p / Wo) % Ho;
    int b = p / (Wo * Ho);
    int Wi = Wo * 2, C = C8 * 8;
    const unsigned short* q0 = in + (((size_t)(b * Ho * 2 + 2 * y) * Wi + 2 * x) * C + g * 8);
    u16x8 v0 = *(const u16x8*)q0;
    u16x8 v1 = *(const u16x8*)(q0 + C);
    u16x8 v2 = *(const u16x8*)(q0 + (size_t)Wi * C);
    u16x8 v3 = *(const u16x8*)(q0 + (size_t)Wi * C + C);
    u16x8 r;
#pragma unroll
    for (int j = 0; j < 8; ++j)
        r[j] = f2bf(fmaxf(fmaxf(bf2f(v0[j]), bf2f(v1[j])), fmaxf(bf2f(v2[j]), bf2f(v3[j]))));
    *(u16x8*)(out + (size_t)idx * 8) = r;
}

__device__ __forceinline__ void bilin_setup(int y, int x, int Hi, int Wi,
                                            int& i00, int& i01, int& i10, int& i11,
                                            float& wy, float& wx)
{
    float fy = 0.5f * y - 0.25f;
    float fx = 0.5f * x - 0.25f;
    float y0f = floorf(fy), x0f = floorf(fx);
    wy = fy - y0f; wx = fx - x0f;
    int yA = (int)y0f, xA = (int)x0f;
    int yB = yA + 1, xB = xA + 1;
    yA = yA < 0 ? 0 : (yA > Hi - 1 ? Hi - 1 : yA);
    yB = yB < 0 ? 0 : (yB > Hi - 1 ? Hi - 1 : yB);
    xA = xA < 0 ? 0 : (xA > Wi - 1 ? Wi - 1 : xA);
    xB = xB < 0 ? 0 : (xB > Wi - 1 ? Wi - 1 : xB);
    i00 = yA * Wi + xA; i01 = yA * Wi + xB;
    i10 = yB * Wi + xA; i11 = yB * Wi + xB;
}

// ---------------------------------------------------------------------------
// NHWC bf16 upsample(2x) + concat: dst[b][H][W][C1+C2] =
//   cat(bilinear-up(up NHWC [b][H/2][W/2][C1]), skip NHWC [b][H][W][C2]).
// ---------------------------------------------------------------------------
__global__ void upcat_nhwc2(const unsigned short* __restrict__ up,
                            const unsigned short* __restrict__ skip,
                            unsigned short* __restrict__ dst,
                            int C1, int C2, int H, int W)
{
    int C8 = (C1 + C2) >> 3;
    int idx = blockIdx.x * 256 + threadIdx.x;
    int total = 8 * H * W * C8;
    if (idx >= total) return;
    int g = idx % C8;
    int p = idx / C8;
    int x = p % W;
    int y = (p / W) % H;
    int b = p / (W * H);
    u16x8 r;
    if (g < (C1 >> 3)) {
        int Hi = H >> 1, Wi = W >> 1;
        int i00, i01, i10, i11; float wy, wx;
        bilin_setup(y, x, Hi, Wi, i00, i01, i10, i11, wy, wx);
        const unsigned short* sb = up + (size_t)b * Hi * Wi * C1 + g * 8;
        u16x8 v00 = *(const u16x8*)(sb + (size_t)i00 * C1);
        u16x8 v01 = *(const u16x8*)(sb + (size_t)i01 * C1);
        u16x8 v10 = *(const u16x8*)(sb + (size_t)i10 * C1);
        u16x8 v11 = *(const u16x8*)(sb + (size_t)i11 * C1);
        float w00 = (1.f - wy) * (1.f - wx), w01 = (1.f - wy) * wx;
        float w10 = wy * (1.f - wx),         w11 = wy * wx;
#pragma unroll
        for (int j = 0; j < 8; ++j)
            r[j] = f2bf(w00 * bf2f(v00[j]) + w01 * bf2f(v01[j]) +
                        w10 * bf2f(v10[j]) + w11 * bf2f(v11[j]));
    } else {
        r = *(const u16x8*)(skip + ((size_t)(b * H + y) * W + x) * C2 + (g - (C1 >> 3)) * 8);
    }
    *(u16x8*)(dst + (((size_t)(b * H + y) * W + x) * (C1 + C2) + g * 8)) = r;
}

// ---------------------------------------------------------------------------
// img [8][15][256][256] fp32 -> imgT [b][y][x][16] bf16 (ch15 = 0)
// ---------------------------------------------------------------------------
__global__ void imgT_bf16(const float* __restrict__ img, unsigned short* __restrict__ dst)
{
    int idx = blockIdx.x * 256 + threadIdx.x;
    if (idx >= 8 * 256 * 256) return;
    int x = idx & 255, y = (idx >> 8) & 255, b = idx >> 16;
    unsigned short v[16];
#pragma unroll
    for (int c = 0; c < 15; ++c)
        v[c] = f2bf(img[(size_t)(b * 15 + c) * 65536 + y * 256 + x]);
    v[15] = 0;
    uint4 lo = make_uint4(pack2(v[0], v[1]), pack2(v[2], v[3]), pack2(v[4], v[5]), pack2(v[6], v[7]));
    uint4 hi = make_uint4(pack2(v[8], v[9]), pack2(v[10], v[11]), pack2(v[12], v[13]), pack2(v[14], v[15]));
    *(uint4*)(dst + (size_t)idx * 16)     = lo;
    *(uint4*)(dst + (size_t)idx * 16 + 8) = hi;
}

// ---------------------------------------------------------------------------
// Generic weight pack: w [Cout][Cin][3][3] fp32 -> bf16 A-fragments.
// idx = (((s*KST+kst)*MT+mt)*64 + lane)*8 + j
//   oc = mt*32+(lane&31), ci = kst*16+(lane>>5)*8+j, s = dy*3+dx.
// ---------------------------------------------------------------------------
__global__ void wpack(const float* __restrict__ w, unsigned short* __restrict__ dst,
                      int Cin, int Cout)
{
    int KST = Cin >> 4, MT = Cout >> 5;
    int total = 9 * KST * MT * 512;
    int idx = blockIdx.x * 256 + threadIdx.x;
    if (idx >= total) return;
    int j = idx & 7;
    int lane = (idx >> 3) & 63;
    int t = idx >> 9;
    int mt = t % MT; t /= MT;
    int kst = t % KST;
    int s = t / KST;
    int oc = mt * 32 + (lane & 31);
    int ci = kst * 16 + (lane >> 5) * 8 + j;
    dst[idx] = f2bf(w[(oc * Cin + ci) * 9 + s]);
}

// Special packs: w9 (K=48), w8 (K=64), w1 (5x5, Cin15->16), wi (Cin15->16).
__global__ void wprep_all(const float* __restrict__ w9, const float* __restrict__ w8,
                          const float* __restrict__ w1, const float* __restrict__ wi,
                          unsigned short* __restrict__ wpk9, unsigned short* __restrict__ wpk8,
                          unsigned short* __restrict__ wpk1, unsigned short* __restrict__ wpki)
{
    int idx = blockIdx.x * 256 + threadIdx.x;
    if (idx < 27648) {
        int j = idx & 7;
        int t = idx >> 3;
        int lane = t & 63; t >>= 6;
        int mt = t & 1; t >>= 1;
        int kst = t % 3;
        int s = t / 3;
        int oc = mt * 32 + (lane & 31);
        int ci = kst * 16 + (lane >> 5) * 8 + j;
        wpk9[idx] = f2bf(w9[(oc * 48 + ci) * 9 + s]);
    } else if (idx < 46080) {
        int i = idx - 27648;
        int j = i & 7;
        int lane = (i >> 3) & 63;
        int t = i >> 9;
        int kst = t & 3;
        int s = t >> 2;
        int oc = lane & 31;
        int ci = kst * 16 + (lane >> 5) * 8 + j;
        wpk8[i] = f2bf(w8[(oc * 64 + ci) * 9 + s]);
    } else if (idx < 58880) {
        int i = idx - 46080;
        int j = i & 7;
        int lane = (i >> 3) & 63;
        int s = i >> 9;                 // 0..24
        int oc = lane & 31;
        int ci = (lane >> 5) * 8 + j;   // 0..15
        float v = 0.f;
        if (oc < 16 && ci < 15) v = w1[((oc * 15 + ci) * 5 + s / 5) * 5 + s % 5];
        wpk1[i] = f2bf(v);
    } else if (idx < 63488) {
        int i = idx - 58880;
        int j = i & 7;
        int lane = (i >> 3) & 63;
        int s = i >> 9;                 // 0..8
        int oc = lane & 31;
        int ci = (lane >> 5) * 8 + j;
        float v = 0.f;
        if (oc < 16 && ci < 15) v = wi[((oc * 15 + ci) * 3 + s / 3) * 3 + s % 3];
        wpki[i] = f2bf(v);
    }
}

// ---------------------------------------------------------------------------
// Generic NHWC bf16 MFMA conv (3x3, pad 1, relu -> NHWC bf16).
// Block: ROWS x W strip = 128 px (4 waves x 32 px). LDS per-channel-group
// planes padded (+8 el) so staging writes spread across banks; b-frag reads
// are 16 B/lane stride (conflict-free).
// ---------------------------------------------------------------------------
template<int CIN, int COUT, int H, int W, int ROWS>
__global__ __launch_bounds__(256)
void convN_mfma(const unsigned short* __restrict__ in,
                const unsigned short* __restrict__ wpk,
                const float* __restrict__ bias,
                unsigned short* __restrict__ out)
{
    constexpr int G = CIN / 8;
    constexpr int KST = CIN / 16;
    constexpr int MT = COUT / 32;
    constexpr int TR = ROWS + 2;
    constexpr int TWd = W + 2;
    constexpr int PS = TR * TWd * 8 + 8;    // padded plane stride
    __shared__ __align__(16) unsigned short smem[G * PS];

    const int tid  = threadIdx.x;
    const int lane = tid & 63;
    const int wv   = tid >> 6;
    const int q    = lane >> 5;
    const int y0   = blockIdx.x * ROWS;
    const int b    = blockIdx.y;

    for (int i = tid; i < G * TR * TWd; i += 256) {
        int g = i % G;
        int u = (i / G) % TWd;
        int t = i / (G * TWd);
        int yg = y0 + t - 1, xg = u - 1;
        uint4 v = make_uint4(0, 0, 0, 0);
        if (yg >= 0 && yg < H && xg >= 0 && xg < W)
            v = *(const uint4*)(in + (((size_t)(b * H + yg) * W + xg) * CIN + g * 8));
        *(uint4*)(&smem[g * PS + (t * TWd + u) * 8]) = v;
    }
    __syncthreads();

    const int p = wv * 32 + (lane & 31);
    const int r = p / W;
    const int x = p % W;

    f32x16 acc[MT];
#pragma unroll
    for (int mt = 0; mt < MT; ++mt)
#pragma unroll
        for (int i = 0; i < 16; ++i) acc[mt][i] = 0.f;

    const unsigned short* wbase = wpk + lane * 8;

#pragma unroll
    for (int s = 0; s < 9; ++s) {
        const int dy = s / 3, dx = s % 3;
#pragma unroll
        for (int kst = 0; kst < KST; ++kst) {
            const int g = kst * 2 + q;
            bf16x8 bfrag = *(const bf16x8*)(&smem[g * PS + ((r + dy) * TWd + (x + dx)) * 8]);
#pragma unroll
            for (int mt = 0; mt < MT; ++mt) {
                bf16x8 a = *(const bf16x8*)(wbase + ((s * KST + kst) * MT + mt) * 512);
                acc[mt] = __builtin_amdgcn_mfma_f32_32x32x16_bf16(a, bfrag, acc[mt], 0, 0, 0);
            }
        }
    }

    size_t base = ((size_t)(b * H + y0 + r) * W + x) * COUT;
#pragma unroll
    for (int mt = 0; mt < MT; ++mt)
#pragma unroll
        for (int rg = 0; rg < 4; ++rg) {
            int oc = mt * 32 + 8 * rg + 4 * q;
            unsigned short s0 = f2bf(fmaxf(acc[mt][rg * 4 + 0] + bias[oc + 0], 0.f));
            unsigned short s1 = f2bf(fmaxf(acc[mt][rg * 4 + 1] + bias[oc + 1], 0.f));
            unsigned short s2 = f2bf(fmaxf(acc[mt][rg * 4 + 2] + bias[oc + 2], 0.f));
            unsigned short s3 = f2bf(fmaxf(acc[mt][rg * 4 + 3] + bias[oc + 3], 0.f));
            *(uint2*)(out + base + oc) = make_uint2(pack2(s0, s1), pack2(s2, s3));
        }
}

// ---------------------------------------------------------------------------
// Fused conv1 (5x5, relu -> x1t NHWC bf16) + conv_i (3x3 -> xin NCHW fp32).
// ---------------------------------------------------------------------------
__global__ __launch_bounds__(256)
void conv1i_mfma(const unsigned short* __restrict__ imgT,
                 const unsigned short* __restrict__ wpk1,
                 const unsigned short* __restrict__ wpki,
                 const float* __restrict__ b1, const float* __restrict__ bi,
                 unsigned short* __restrict__ x1t, float* __restrict__ xin)
{
    __shared__ __align__(16) unsigned short smem[2 * 5 * 132 * 8];  // 21120 B

    const int tid  = threadIdx.x;
    const int lane = tid & 63;
    const int wv   = tid >> 6;
    const int n    = lane & 31;
    const int q    = lane >> 5;
    const int y    = blockIdx.x >> 1;
    const int x0   = (blockIdx.x & 1) * 128;
    const int b    = blockIdx.y;

    for (int i = tid; i < 5 * 132 * 2; i += 256) {
        int r   = i / 264;
        int rem = i - r * 264;
        int xi  = rem >> 1;
        int g   = rem & 1;
        int yg = y + r - 2;
        int xg = x0 - 2 + xi;
        uint4 v = make_uint4(0, 0, 0, 0);
        if (yg >= 0 && yg < 256 && xg >= 0 && xg < 256)
            v = *(const uint4*)(imgT + (((size_t)(b * 256 + yg) * 256 + xg) * 16 + g * 8));
        *(uint4*)(&smem[((g * 5 + r) * 132 + xi) * 8]) = v;
    }
    __syncthreads();

    f32x16 acc1, acci;
#pragma unroll
    for (int i = 0; i < 16; ++i) { acc1[i] = 0.f; acci[i] = 0.f; }

    const int pxl = wv * 32 + n;
    const unsigned short* wb1 = wpk1 + lane * 8;
    const unsigned short* wbi = wpki + lane * 8;

#pragma unroll
    for (int s = 0; s < 25; ++s) {
        const int dy = s / 5, dx = s % 5;
        bf16x8 bfrag = *(const bf16x8*)(&smem[((q * 5 + dy) * 132 + pxl + dx) * 8]);
        bf16x8 a = *(const bf16x8*)(wb1 + s * 512);
        acc1 = __builtin_amdgcn_mfma_f32_32x32x16_bf16(a, bfrag, acc1, 0, 0, 0);
    }
#pragma unroll
    for (int s = 0; s < 9; ++s) {
        const int dy = s / 3, dx = s % 3;
        bf16x8 bfrag = *(const bf16x8*)(&smem[((q * 5 + dy + 1) * 132 + pxl + dx + 1) * 8]);
        bf16x8 a = *(const bf16x8*)(wbi + s * 512);
        acci = __builtin_amdgcn_mfma_f32_32x32x16_bf16(a, bfrag, acci, 0, 0, 0);
    }

    const int px = x0 + pxl;
    // x1t NHWC bf16: regs 0..3 -> oc 4q+0..3 ; regs 4..7 -> oc 8+4q+0..3
    size_t base1 = ((size_t)(b * 256 + y) * 256 + px) * 16;
#pragma unroll
    for (int rg = 0; rg < 2; ++rg) {
        int oc = 8 * rg + 4 * q;
        unsigned short s0 = f2bf(fmaxf(acc1[rg * 4 + 0] + b1[oc + 0], 0.f));
        unsigned short s1 = f2bf(fmaxf(acc1[rg * 4 + 1] + b1[oc + 1], 0.f));
        unsigned short s2 = f2bf(fmaxf(acc1[rg * 4 + 2] + b1[oc + 2], 0.f));
        unsigned short s3 = f2bf(fmaxf(acc1[rg * 4 + 3] + b1[oc + 3], 0.f));
        *(uint2*)(x1t + base1 + oc) = make_uint2(pack2(s0, s1), pack2(s2, s3));
    }
#pragma unroll
    for (int reg = 0; reg < 8; ++reg) {
        int row = (reg & 3) + 8 * (reg >> 2) + 4 * q;
        xin[((size_t)(b * 16 + row) * 256 + y) * 256 + px] = acci[reg] + bi[row];
    }
}

// ---------------------------------------------------------------------------
// conv8 MFMA: Cin=64, Cout=32, 128x128, relu -> x8t NHWC bf16.
// ---------------------------------------------------------------------------
__global__ __launch_bounds__(256)
void conv8_mfma(const unsigned short* __restrict__ cat8t,
                const unsigned short* __restrict__ wpk8,
                const float* __restrict__ bias,
                unsigned short* __restrict__ x8t)
{
    __shared__ __align__(16) unsigned short smem[8 * 3 * 130 * 8];  // 49920 B

    const int tid  = threadIdx.x;
    const int lane = tid & 63;
    const int wv   = tid >> 6;
    const int n    = lane & 31;
    const int q    = lane >> 5;
    const int y    = blockIdx.x;
    const int b    = blockIdx.y;

    for (int i = tid; i < 3 * 130 * 8; i += 256) {
        int r   = i / 1040;
        int rem = i - r * 1040;
        int xi  = rem >> 3;
        int g   = rem & 7;
        int yg = y + r - 1;
        int xg = xi - 1;
        uint4 v = make_uint4(0, 0, 0, 0);
        if (yg >= 0 && yg < 128 && xg >= 0 && xg < 128)
            v = *(const uint4*)(cat8t + (((size_t)(b * 128 + yg) * 128 + xg) * 64 + g * 8));
        *(uint4*)(&smem[((g * 3 + r) * 130 + xi) * 8]) = v;
    }
    __syncthreads();

    f32x16 acc;
#pragma unroll
    for (int i = 0; i < 16; ++i) acc[i] = 0.f;

    const int pxl = wv * 32 + n;
    const unsigned short* wbase = wpk8 + lane * 8;

#pragma unroll
    for (int s = 0; s < 9; ++s) {
        const int dy = s / 3, dx = s % 3;
        const int xi = pxl + dx;
#pragma unroll
        for (int kst = 0; kst < 4; ++kst) {
            const int g = kst * 2 + q;
            bf16x8 bfrag = *(const bf16x8*)(&smem[((g * 3 + dy) * 130 + xi) * 8]);
            bf16x8 a = *(const bf16x8*)(wbase + (s * 4 + kst) * 512);
            acc = __builtin_amdgcn_mfma_f32_32x32x16_bf16(a, bfrag, acc, 0, 0, 0);
        }
    }

    size_t base = ((size_t)(b * 128 + y) * 128 + pxl) * 32;
#pragma unroll
    for (int rg = 0; rg < 4; ++rg) {
        int oc0 = 8 * rg + 4 * q;
        unsigned short s0 = f2bf(fmaxf(acc[rg * 4 + 0] + bias[oc0 + 0], 0.f));
        unsigned short s1 = f2bf(fmaxf(acc[rg * 4 + 1] + bias[oc0 + 1], 0.f));
        unsigned short s2 = f2bf(fmaxf(acc[rg * 4 + 2] + bias[oc0 + 2], 0.f));
        unsigned short s3 = f2bf(fmaxf(acc[rg * 4 + 3] + bias[oc0 + 3], 0.f));
        *(uint2*)(x8t + base + oc0) = make_uint2(pack2(s0, s1), pack2(s2, s3));
    }
}

// ---------------------------------------------------------------------------
// upcat9 -> xt9 NHWC bf16 [b][256][256][48]; skip from x1t NHWC bf16.
// ---------------------------------------------------------------------------
__global__ void upcat9_nhwc(const unsigned short* __restrict__ x8t,
                            const unsigned short* __restrict__ x1t,
                            unsigned short* __restrict__ dst)
{
    int idx = blockIdx.x * 256 + threadIdx.x;
    if (idx >= 8 * 256 * 256) return;
    int x = idx & 255, y = (idx >> 8) & 255, b = idx >> 16;
    int i00, i01, i10, i11; float wy, wx;
    bilin_setup(y, x, 128, 128, i00, i01, i10, i11, wy, wx);
    const unsigned short* sb = x8t + (size_t)b * 128 * 128 * 32;
    unsigned short* d = dst + (size_t)idx * 48;
    float w00 = (1.f - wy) * (1.f - wx), w01 = (1.f - wy) * wx;
    float w10 = wy * (1.f - wx),         w11 = wy * wx;
#pragma unroll
    for (int g = 0; g < 4; ++g) {
        u16x8 v00 = *(const u16x8*)(sb + (size_t)i00 * 32 + g * 8);
        u16x8 v01 = *(const u16x8*)(sb + (size_t)i01 * 32 + g * 8);
        u16x8 v10 = *(const u16x8*)(sb + (size_t)i10 * 32 + g * 8);
        u16x8 v11 = *(const u16x8*)(sb + (size_t)i11 * 32 + g * 8);
        u16x8 r;
#pragma unroll
        for (int j = 0; j < 8; ++j)
            r[j] = f2bf(w00 * bf2f(v00[j]) + w01 * bf2f(v01[j]) +
                        w10 * bf2f(v10[j]) + w11 * bf2f(v11[j]));
        *(u16x8*)(d + g * 8) = r;
    }
    const unsigned short* x1b = x1t + ((size_t)(b * 256 + y) * 256 + x) * 16;
    *(u16x8*)(d + 32) = *(const u16x8*)(x1b);
    *(u16x8*)(d + 40) = *(const u16x8*)(x1b + 8);
}

// ---------------------------------------------------------------------------
// conv9 MFMA: K=48, 64 oc, 256x256, tanh -> fm NCHW fp32.
// ---------------------------------------------------------------------------
__global__ __launch_bounds__(256)
void conv9_mfma(const unsigned short* __restrict__ xt9,
                const unsigned short* __restrict__ wpk,
                const float* __restrict__ bias,
                float* __restrict__ fm)
{
    __shared__ __align__(16) unsigned short smem[6 * 3 * 130 * 8];  // 37440 B

    const int tid  = threadIdx.x;
    const int lane = tid & 63;
    const int wv   = tid >> 6;
    const int n    = lane & 31;
    const int q    = lane >> 5;
    const int y    = blockIdx.x >> 1;
    const int x0   = (blockIdx.x & 1) * 128;
    const int b    = blockIdx.y;

    for (int i = tid; i < 3 * 130 * 6; i += 256) {
        int r   = i / 780;
        int rem = i - r * 780;
        int xi  = rem / 6;
        int g   = rem - xi * 6;
        int yg = y + r - 1;
        int xg = x0 - 1 + xi;
        uint4 v = make_uint4(0, 0, 0, 0);
        if (yg >= 0 && yg < 256 && xg >= 0 && xg < 256)
            v = *(const uint4*)(xt9 + (((size_t)(b * 256 + yg) * 256 + xg) * 48 + g * 8));
        *(uint4*)(&smem[((g * 3 + r) * 130 + xi) * 8]) = v;
    }
    __syncthreads();

    f32x16 acc0, acc1;
#pragma unroll
    for (int i = 0; i < 16; ++i) { acc0[i] = 0.f; acc1[i] = 0.f; }

    const int pxl = wv * 32 + n;
    const unsigned short* wbase = wpk + lane * 8;

#pragma unroll
    for (int s = 0; s < 9; ++s) {
        const int dy = s / 3, dx = s % 3;
        const int xi = pxl + dx;
#pragma unroll
        for (int kst = 0; kst < 3; ++kst) {
            const int g = kst * 2 + q;
            bf16x8 bfrag = *(const bf16x8*)(&smem[((g * 3 + dy) * 130 + xi) * 8]);
            bf16x8 a0 = *(const bf16x8*)(wbase + ((s * 3 + kst) * 2 + 0) * 512);
            bf16x8 a1 = *(const bf16x8*)(wbase + ((s * 3 + kst) * 2 + 1) * 512);
            acc0 = __builtin_amdgcn_mfma_f32_32x32x16_bf16(a0, bfrag, acc0, 0, 0, 0);
            acc1 = __builtin_amdgcn_mfma_f32_32x32x16_bf16(a1, bfrag, acc1, 0, 0, 0);
        }
    }

    const int px = x0 + pxl;
#pragma unroll
    for (int reg = 0; reg < 16; ++reg) {
        int row = (reg & 3) + 8 * (reg >> 2) + 4 * q;
        int oc0 = row, oc1 = 32 + row;
        fm[(((size_t)b * 64 + oc0) * 256 + y) * 256 + px] = fast_tanh(acc0[reg] + bias[oc0]);
        fm[(((size_t)b * 64 + oc1) * 256 + y) * 256 + px] = fast_tanh(acc1[reg] + bias[oc1]);
    }
}

// ---------------------------------------------------------------------------
// LDS-tiled W-direction LRNN pair (fwd+rev), initializes out (rnn).
// ---------------------------------------------------------------------------
__global__ __launch_bounds__(256)
void lrnn_wt(const float* __restrict__ X, const float* __restrict__ FM,
             float* __restrict__ out)
{
    __shared__ float tiles[2][3][16][130];   // [dir][stream][xi][row] 49920 B

    const int tid = threadIdx.x;
    const int r   = tid & 127;
    const int d   = tid >> 7;
    const int yb  = blockIdx.x & 1;
    const int c   = (blockIdx.x >> 1) & 15;
    const int b   = blockIdx.x >> 5;
    const int y0  = yb * 128;

    const size_t xin_base = ((size_t)(b * 16 + c) * 256 + y0) * 256;
    const size_t p1_base  = ((size_t)(b * 64 + c) * 256 + y0) * 256;
    const size_t p2_base  = ((size_t)(b * 64 + 32 + c) * 256 + y0) * 256;

    float h1 = 0.f, h2 = 0.f;

    for (int k = 0; k < 16; ++k) {
        const int xsf = 16 * k;
        const int xsr = 240 - 16 * k;

        for (int i = tid; i < 3072; i += 256) {
            int f4 = i & 3;
            int rr = (i >> 2) & 127;
            int v  = i >> 9;           // 0..5
            int s  = v % 3;
            int dd = v / 3;
            int xs = dd ? xsr : xsf;
            const float* sp = (s == 0) ? X : FM;
            size_t off = (s == 0 ? xin_base : (s == 1 ? p1_base : p2_base))
                       + (size_t)rr * 256 + xs + f4 * 4;
            float4 vv = *(const float4*)(sp + off);
            tiles[dd][s][f4 * 4 + 0][rr] = vv.x;
            tiles[dd][s][f4 * 4 + 1][rr] = vv.y;
            tiles[dd][s][f4 * 4 + 2][rr] = vv.z;
            tiles[dd][s][f4 * 4 + 3][rr] = vv.w;
        }
        __syncthreads();

        if (d == 0) {
#pragma unroll
            for (int xi = 0; xi < 16; ++xi) {
                float xv = tiles[0][0][xi][r];
                float p1 = tiles[0][1][xi][r];
                float p2 = tiles[0][2][xi][r];
                h1 = fmaf(p1, h1 - xv, xv);
                h2 = fmaf(p2, h2 - xv, xv);
                tiles[0][0][xi][r] = fmaxf(h1, h2);
            }
        } else {
#pragma unroll
            for (int xi = 0; xi < 16; ++xi) {
                float xv = tiles[1][0][15 - xi][r];
                float p1 = tiles[1][1][15 - xi][r];
                float p2 = tiles[1][2][15 - xi][r];
                h1 = fmaf(p1, h1 - xv, xv);
                h2 = fmaf(p2, h2 - xv, xv);
                tiles[1][0][15 - xi][r] = fmaxf(h1, h2);
            }
        }
        __syncthreads();

        for (int i = tid; i < 512; i += 256) {
            int f4 = i & 3;
            int rr = i >> 2;
            float4 m;
            m.x = fmaxf(tiles[0][0][f4 * 4 + 0][rr], tiles[1][0][15 - (f4 * 4 + 0)][rr]);
            m.y = fmaxf(tiles[0][0][f4 * 4 + 1][rr], tiles[1][0][15 - (f4 * 4 + 1)][rr]);
            m.z = fmaxf(tiles[0][0][f4 * 4 + 2][rr], tiles[1][0][15 - (f4 * 4 + 2)][rr]);
            m.w = fmaxf(tiles[0][0][f4 * 4 + 3][rr], tiles[1][0][15 - (f4 * 4 + 3)][rr]);
            *(float4*)(out + xin_base + (size_t)rr * 256 + xsf + f4 * 4) = m;
        }
    }
}

// ---------------------------------------------------------------------------
// Fused H-direction LRNN pair (fwd + rev), max-accumulates into out.
// ---------------------------------------------------------------------------
__global__ void lrnn_hb(const float* __restrict__ X, const float* __restrict__ FM,
                        float* __restrict__ out, int B, int H, int W)
{
    int total = B * 16 * W;
    int idx = blockIdx.x * 256 + threadIdx.x;
    if (idx >= total) return;
    int x = idx % W;
    int c = (idx / W) & 15;
    int b = idx / (W * 16);
    const float* xc  = X  + (size_t)((b * 16 + c) * H) * W + x;
    const float* p1c = FM + (size_t)((b * 64 + 16 + c) * H) * W + x;
    const float* p2c = FM + (size_t)((b * 64 + 48 + c) * H) * W + x;
    float* ocp = out + (size_t)((b * 16 + c) * H) * W + x;
    float hf1 = 0.f, hf2 = 0.f, hr1 = 0.f, hr2 = 0.f;
    float xfa = xc[0], pf1a = p1c[0], pf2a = p2c[0];
    float xra = xc[(H - 1) * W], pr1a = p1c[(H - 1) * W], pr2a = p2c[(H - 1) * W];
    float oa = ocp[0];
    float xfb = xc[W], pf1b = p1c[W], pf2b = p2c[W];
    float xrb = xc[(H - 2) * W], pr1b = p1c[(H - 2) * W], pr2b = p2c[(H - 2) * W];
    float ob = ocp[W];
    for (int i = 0; i < H; ++i) {
        float xfn = 0.f, pf1n = 0.f, pf2n = 0.f, xrn = 0.f, pr1n = 0.f, pr2n = 0.f, on = 0.f;
        if (i + 2 < H) {
            int yf = (i + 2) * W, yr = (H - 3 - i) * W;
            xfn = xc[yf]; pf1n = p1c[yf]; pf2n = p2c[yf];
            xrn = xc[yr]; pr1n = p1c[yr]; pr2n = p2c[yr];
            on = ocp[yf];
        }
        hf1 = fmaf(pf1a, hf1 - xfa, xfa);
        hf2 = fmaf(pf2a, hf2 - xfa, xfa);
        hr1 = fmaf(pr1a, hr1 - xra, xra);
        hr2 = fmaf(pr2a, hr2 - xra, xra);
        ocp[i * W] = fmaxf(fmaxf(oa, fmaxf(hf1, hf2)), fmaxf(hr1, hr2));
        xfa = xfb; pf1a = pf1b; pf2a = pf2b; xra = xrb; pr1a = pr1b; pr2a = pr2b; oa = ob;
        xfb = xfn; pf1b = pf1n; pf2b = pf2n; xrb = xrn; pr1b = pr1n; pr2b = pr2n; ob = on;
    }
}

// ---------------------------------------------------------------------------
extern "C" void kernel_launch(void* const* d_in, const int* in_sizes, int n_in,
                              void* d_out, int out_size, void* d_ws, size_t ws_size,
                              hipStream_t stream)
{
    const float* img = (const float*)d_in[0];
    const float* w1 = (const float*)d_in[1];  const float* b1 = (const float*)d_in[2];
    const float* w2 = (const float*)d_in[3];  const float* b2 = (const float*)d_in[4];
    const float* w3 = (const float*)d_in[5];  const float* b3 = (const float*)d_in[6];
    const float* w4 = (const float*)d_in[7];  const float* b4 = (const float*)d_in[8];
    const float* w5 = (const float*)d_in[9];  const float* b5 = (const float*)d_in[10];
    const float* w6 = (const float*)d_in[11]; const float* b6 = (const float*)d_in[12];
    const float* w7 = (const float*)d_in[13]; const float* b7 = (const float*)d_in[14];
    const float* w8 = (const float*)d_in[15]; const float* b8 = (const float*)d_in[16];
    const float* w9 = (const float*)d_in[17]; const float* b9 = (const float*)d_in[18];
    const float* wi = (const float*)d_in[19]; const float* bi = (const float*)d_in[20];
    const float* wo = (const float*)d_in[21]; const float* bo = (const float*)d_in[22];

    char* wsb = (char*)d_ws;
    const size_t MB = (size_t)(1u << 20);
    // NHWC bf16 pipeline, live-range-checked; peak 209 MiB.
    unsigned short* imgT  = (unsigned short*)(wsb);            // [0,16)
    unsigned short* x1t   = (unsigned short*)(wsb + 16 * MB);  // [16,32)  (until upcat9)
    unsigned short* p1t   = (unsigned short*)(wsb + 32 * MB);  // [32,36)
    unsigned short* x2t   = (unsigned short*)(wsb + 36 * MB);  // [36,44)  (until cat8)
    unsigned short* p2t   = (unsigned short*)(wsb + 44 * MB);  // [44,46)
    unsigned short* x3t   = (unsigned short*)(wsb + 46 * MB);  // [46,48)  (until cat7)
    unsigned short* p3t   = (unsigned short*)(wsb + 48 * MB);  // [48,48.5)
    unsigned short* x4t   = (unsigned short*)(wsb + 49 * MB);  // [49,49.5) (until cat6)
    unsigned short* p4t   = (unsigned short*)(wsb + 50 * MB);  // [50,50.125)
    unsigned short* x5t   = (unsigned short*)(wsb + 51 * MB);  // [51,51.25)
    unsigned short* cat6t = (unsigned short*)(wsb + 52 * MB);  // [52,53.5)
    unsigned short* x6t   = (unsigned short*)(wsb + 54 * MB);  // [54,54.5)
    unsigned short* cat7t = (unsigned short*)(wsb + 55 * MB);  // [55,59)
    unsigned short* x7t   = (unsigned short*)(wsb + 59 * MB);  // [59,61)
    unsigned short* cat8t = (unsigned short*)(wsb + 62 * MB);  // [62,78)
    unsigned short* x8t   = (unsigned short*)(wsb + 78 * MB);  // [78,86)
    unsigned short* xt9   = (unsigned short*)(wsb + 128 * MB); // [128,176)
    float* fm    = (float*)(wsb);                              // [0,128) (encoder dead)
    float* rnn   = (float*)(wsb + 128 * MB);                   // [128,160) (xt9 dead)
    float* xin   = (float*)(wsb + 176 * MB);                   // [176,208)
    unsigned short* wpk9 = (unsigned short*)(wsb + 208 * MB);
    unsigned short* wpk8 = wpk9 + 27648;
    unsigned short* wpk1 = wpk8 + 18432;
    unsigned short* wpki = wpk1 + 12800;
    unsigned short* wpk2 = wpki + 4608;   //  4608
    unsigned short* wpk3 = wpk2 + 4608;   //  9216
    unsigned short* wpk4 = wpk3 + 9216;   //  9216
    unsigned short* wpk5 = wpk4 + 9216;   // 18432
    unsigned short* wpk6 = wpk5 + 18432;  // 27648
    unsigned short* wpk7 = wpk6 + 27648;  // 18432
    float* outp = (float*)d_out;

    // --- weight packs + img transpose ---
    wprep_all<<<248, 256, 0, stream>>>(w9, w8, w1, wi, wpk9, wpk8, wpk1, wpki);
    wpack<<<18, 256, 0, stream>>>(w2, wpk2, 16, 32);
    wpack<<<36, 256, 0, stream>>>(w3, wpk3, 32, 32);
    wpack<<<36, 256, 0, stream>>>(w4, wpk4, 32, 32);
    wpack<<<72, 256, 0, stream>>>(w5, wpk5, 32, 64);
    wpack<<<108, 256, 0, stream>>>(w6, wpk6, 96, 32);
    wpack<<<72, 256, 0, stream>>>(w7, wpk7, 64, 32);
    imgT_bf16<<<2048, 256, 0, stream>>>(img, imgT);

    // --- fused conv1 (relu -> x1t NHWC) + input projection (xin NCHW) ---
    { dim3 grd(512, 8);
      conv1i_mfma<<<grd, 256, 0, stream>>>(imgT, wpk1, wpki, b1, bi, x1t, xin); }

    // --- encoder (NHWC bf16 MFMA) ---
    pool_nhwc<<<1024, 256, 0, stream>>>(x1t, p1t, 128, 128, 2);
    convN_mfma<16, 32, 128, 128, 1><<<dim3(128, 8), 256, 0, stream>>>(p1t, wpk2, b2, x2t);
    pool_nhwc<<<512, 256, 0, stream>>>(x2t, p2t, 64, 64, 4);
    convN_mfma<32, 32, 64, 64, 2><<<dim3(32, 8), 256, 0, stream>>>(p2t, wpk3, b3, x3t);
    pool_nhwc<<<128, 256, 0, stream>>>(x3t, p3t, 32, 32, 4);
    convN_mfma<32, 32, 32, 32, 4><<<dim3(8, 8), 256, 0, stream>>>(p3t, wpk4, b4, x4t);
    pool_nhwc<<<32, 256, 0, stream>>>(x4t, p4t, 16, 16, 4);
    convN_mfma<32, 64, 16, 16, 8><<<dim3(2, 8), 256, 0, stream>>>(p4t, wpk5, b5, x5t);

    // --- decoder (NHWC bf16) ---
    upcat_nhwc2<<<384, 256, 0, stream>>>(x5t, x4t, cat6t, 64, 32, 32, 32);
    convN_mfma<96, 32, 32, 32, 4><<<dim3(8, 8), 256, 0, stream>>>(cat6t, wpk6, b6, x6t);
    upcat_nhwc2<<<1024, 256, 0, stream>>>(x6t, x3t, cat7t, 32, 32, 64, 64);
    convN_mfma<64, 32, 64, 64, 2><<<dim3(32, 8), 256, 0, stream>>>(cat7t, wpk7, b7, x7t);
    upcat_nhwc2<<<4096, 256, 0, stream>>>(x7t, x2t, cat8t, 32, 32, 128, 128);
    { dim3 grd(128, 8);
      conv8_mfma<<<grd, 256, 0, stream>>>(cat8t, wpk8, b8, x8t); }

    // --- stage 9 ---
    { int tot = 8 * 256 * 256;
      upcat9_nhwc<<<(tot + 255) / 256, 256, 0, stream>>>(x8t, x1t, xt9); }
    { dim3 grd(512, 8);
      conv9_mfma<<<grd, 256, 0, stream>>>(xt9, wpk9, b9, fm); }

    // --- spatial RNN: W pair (LDS-tiled) then H pair ---
    lrnn_wt<<<256, 256, 0, stream>>>(xin, fm, rnn);
    { int tot = 8 * 16 * 256; int g = (tot + 255) / 256;
      lrnn_hb<<<g, 256, 0, stream>>>(xin, fm, rnn, 8, 256, 256); }

    // --- output head ---
    conv_rt<3, 3, 4>(rnn, wo, bo, outp, 8, 16, 256, 256, 3, stream);
}

// Round 8
// 465.548 us; speedup vs baseline: 4.9886x; 1.2509x over previous
//
#include <hip/hip_runtime.h>
#include <math.h>

typedef __attribute__((ext_vector_type(8)))  short bf16x8;
typedef __attribute__((ext_vector_type(8)))  unsigned short u16x8;
typedef __attribute__((ext_vector_type(16))) float f32x16;

__device__ __forceinline__ unsigned short f2bf(float f) {
    unsigned u = __float_as_uint(f);
    unsigned r = (u + 0x7FFFu + ((u >> 16) & 1u)) >> 16;
    return (unsigned short)r;
}
__device__ __forceinline__ float bf2f(unsigned short h) {
    return __uint_as_float(((unsigned)h) << 16);
}
__device__ __forceinline__ unsigned pack2(unsigned short a, unsigned short b) {
    return (unsigned)a | ((unsigned)b << 16);
}
__device__ __forceinline__ float fast_tanh(float x) {
    float e = __expf(2.f * x);
    return 1.f - 2.f / (e + 1.f);
}

// ---------------------------------------------------------------------------
// NHWC bf16 2x2 maxpool (stride 2). C8 = C/8 vector groups.
// ---------------------------------------------------------------------------
__global__ void pool_nhwc(const unsigned short* __restrict__ in,
                          unsigned short* __restrict__ out,
                          int Ho, int Wo, int C8)
{
    int idx = blockIdx.x * 256 + threadIdx.x;
    int total = 8 * Ho * Wo * C8;
    if (idx >= total) return;
    int g = idx % C8;
    int p = idx / C8;
    int x = p % Wo;
    int y = (p / Wo) % Ho;
    int b = p / (Wo * Ho);
    int Wi = Wo * 2, C = C8 * 8;
    const unsigned short* q0 = in + (((size_t)(b * Ho * 2 + 2 * y) * Wi + 2 * x) * C + g * 8);
    u16x8 v0 = *(const u16x8*)q0;
    u16x8 v1 = *(const u16x8*)(q0 + C);
    u16x8 v2 = *(const u16x8*)(q0 + (size_t)Wi * C);
    u16x8 v3 = *(const u16x8*)(q0 + (size_t)Wi * C + C);
    u16x8 r;
#pragma unroll
    for (int j = 0; j < 8; ++j)
        r[j] = f2bf(fmaxf(fmaxf(bf2f(v0[j]), bf2f(v1[j])), fmaxf(bf2f(v2[j]), bf2f(v3[j]))));
    *(u16x8*)(out + (size_t)idx * 8) = r;
}

__device__ __forceinline__ void bilin_setup(int y, int x, int Hi, int Wi,
                                            int& i00, int& i01, int& i10, int& i11,
                                            float& wy, float& wx)
{
    float fy = 0.5f * y - 0.25f;
    float fx = 0.5f * x - 0.25f;
    float y0f = floorf(fy), x0f = floorf(fx);
    wy = fy - y0f; wx = fx - x0f;
    int yA = (int)y0f, xA = (int)x0f;
    int yB = yA + 1, xB = xA + 1;
    yA = yA < 0 ? 0 : (yA > Hi - 1 ? Hi - 1 : yA);
    yB = yB < 0 ? 0 : (yB > Hi - 1 ? Hi - 1 : yB);
    xA = xA < 0 ? 0 : (xA > Wi - 1 ? Wi - 1 : xA);
    xB = xB < 0 ? 0 : (xB > Wi - 1 ? Wi - 1 : xB);
    i00 = yA * Wi + xA; i01 = yA * Wi + xB;
    i10 = yB * Wi + xA; i11 = yB * Wi + xB;
}

// ---------------------------------------------------------------------------
// NHWC bf16 upsample(2x) + concat.
// ---------------------------------------------------------------------------
__global__ void upcat_nhwc2(const unsigned short* __restrict__ up,
                            const unsigned short* __restrict__ skip,
                            unsigned short* __restrict__ dst,
                            int C1, int C2, int H, int W)
{
    int C8 = (C1 + C2) >> 3;
    int idx = blockIdx.x * 256 + threadIdx.x;
    int total = 8 * H * W * C8;
    if (idx >= total) return;
    int g = idx % C8;
    int p = idx / C8;
    int x = p % W;
    int y = (p / W) % H;
    int b = p / (W * H);
    u16x8 r;
    if (g < (C1 >> 3)) {
        int Hi = H >> 1, Wi = W >> 1;
        int i00, i01, i10, i11; float wy, wx;
        bilin_setup(y, x, Hi, Wi, i00, i01, i10, i11, wy, wx);
        const unsigned short* sb = up + (size_t)b * Hi * Wi * C1 + g * 8;
        u16x8 v00 = *(const u16x8*)(sb + (size_t)i00 * C1);
        u16x8 v01 = *(const u16x8*)(sb + (size_t)i01 * C1);
        u16x8 v10 = *(const u16x8*)(sb + (size_t)i10 * C1);
        u16x8 v11 = *(const u16x8*)(sb + (size_t)i11 * C1);
        float w00 = (1.f - wy) * (1.f - wx), w01 = (1.f - wy) * wx;
        float w10 = wy * (1.f - wx),         w11 = wy * wx;
#pragma unroll
        for (int j = 0; j < 8; ++j)
            r[j] = f2bf(w00 * bf2f(v00[j]) + w01 * bf2f(v01[j]) +
                        w10 * bf2f(v10[j]) + w11 * bf2f(v11[j]));
    } else {
        r = *(const u16x8*)(skip + ((size_t)(b * H + y) * W + x) * C2 + (g - (C1 >> 3)) * 8);
    }
    *(u16x8*)(dst + (((size_t)(b * H + y) * W + x) * (C1 + C2) + g * 8)) = r;
}

// ---------------------------------------------------------------------------
// img [8][15][256][256] fp32 -> imgT [b][y][x][16] bf16 (ch15 = 0)
// ---------------------------------------------------------------------------
__global__ void imgT_bf16(const float* __restrict__ img, unsigned short* __restrict__ dst)
{
    int idx = blockIdx.x * 256 + threadIdx.x;
    if (idx >= 8 * 256 * 256) return;
    int x = idx & 255, y = (idx >> 8) & 255, b = idx >> 16;
    unsigned short v[16];
#pragma unroll
    for (int c = 0; c < 15; ++c)
        v[c] = f2bf(img[(size_t)(b * 15 + c) * 65536 + y * 256 + x]);
    v[15] = 0;
    uint4 lo = make_uint4(pack2(v[0], v[1]), pack2(v[2], v[3]), pack2(v[4], v[5]), pack2(v[6], v[7]));
    uint4 hi = make_uint4(pack2(v[8], v[9]), pack2(v[10], v[11]), pack2(v[12], v[13]), pack2(v[14], v[15]));
    *(uint4*)(dst + (size_t)idx * 16)     = lo;
    *(uint4*)(dst + (size_t)idx * 16 + 8) = hi;
}

// ---------------------------------------------------------------------------
// Generic weight pack: w [Cout][Cin][3][3] fp32 -> bf16 A-fragments.
// ---------------------------------------------------------------------------
__global__ void wpack(const float* __restrict__ w, unsigned short* __restrict__ dst,
                      int Cin, int Cout)
{
    int KST = Cin >> 4, MT = Cout >> 5;
    int total = 9 * KST * MT * 512;
    int idx = blockIdx.x * 256 + threadIdx.x;
    if (idx >= total) return;
    int j = idx & 7;
    int lane = (idx >> 3) & 63;
    int t = idx >> 9;
    int mt = t % MT; t /= MT;
    int kst = t % KST;
    int s = t / KST;
    int oc = mt * 32 + (lane & 31);
    int ci = kst * 16 + (lane >> 5) * 8 + j;
    dst[idx] = f2bf(w[(oc * Cin + ci) * 9 + s]);
}

// Special packs: w9 (K=48), w8 (K=64), w1 (5x5, Cin15->16), wi, wo (3 oc -> 32).
__global__ void wprep_all(const float* __restrict__ w9, const float* __restrict__ w8,
                          const float* __restrict__ w1, const float* __restrict__ wi,
                          const float* __restrict__ wo,
                          unsigned short* __restrict__ wpk9, unsigned short* __restrict__ wpk8,
                          unsigned short* __restrict__ wpk1, unsigned short* __restrict__ wpki,
                          unsigned short* __restrict__ wpko)
{
    int idx = blockIdx.x * 256 + threadIdx.x;
    if (idx < 27648) {
        int j = idx & 7;
        int t = idx >> 3;
        int lane = t & 63; t >>= 6;
        int mt = t & 1; t >>= 1;
        int kst = t % 3;
        int s = t / 3;
        int oc = mt * 32 + (lane & 31);
        int ci = kst * 16 + (lane >> 5) * 8 + j;
        wpk9[idx] = f2bf(w9[(oc * 48 + ci) * 9 + s]);
    } else if (idx < 46080) {
        int i = idx - 27648;
        int j = i & 7;
        int lane = (i >> 3) & 63;
        int t = i >> 9;
        int kst = t & 3;
        int s = t >> 2;
        int oc = lane & 31;
        int ci = kst * 16 + (lane >> 5) * 8 + j;
        wpk8[i] = f2bf(w8[(oc * 64 + ci) * 9 + s]);
    } else if (idx < 58880) {
        int i = idx - 46080;
        int j = i & 7;
        int lane = (i >> 3) & 63;
        int s = i >> 9;                 // 0..24
        int oc = lane & 31;
        int ci = (lane >> 5) * 8 + j;   // 0..15
        float v = 0.f;
        if (oc < 16 && ci < 15) v = w1[((oc * 15 + ci) * 5 + s / 5) * 5 + s % 5];
        wpk1[i] = f2bf(v);
    } else if (idx < 63488) {
        int i = idx - 58880;
        int j = i & 7;
        int lane = (i >> 3) & 63;
        int s = i >> 9;                 // 0..8
        int oc = lane & 31;
        int ci = (lane >> 5) * 8 + j;
        float v = 0.f;
        if (oc < 16 && ci < 15) v = wi[((oc * 15 + ci) * 3 + s / 3) * 3 + s % 3];
        wpki[i] = f2bf(v);
    } else if (idx < 68096) {
        int i = idx - 63488;
        int j = i & 7;
        int lane = (i >> 3) & 63;
        int s = i >> 9;                 // 0..8
        int oc = lane & 31;
        int ci = (lane >> 5) * 8 + j;   // 0..15
        float v = 0.f;
        if (oc < 3) v = wo[((oc * 16 + ci) * 3 + s / 3) * 3 + s % 3];
        wpko[i] = f2bf(v);
    }
}

// ---------------------------------------------------------------------------
// Generic NHWC bf16 MFMA conv (3x3, pad 1, relu -> NHWC bf16).
// ---------------------------------------------------------------------------
template<int CIN, int COUT, int H, int W, int ROWS>
__global__ __launch_bounds__(256)
void convN_mfma(const unsigned short* __restrict__ in,
                const unsigned short* __restrict__ wpk,
                const float* __restrict__ bias,
                unsigned short* __restrict__ out)
{
    constexpr int G = CIN / 8;
    constexpr int KST = CIN / 16;
    constexpr int MT = COUT / 32;
    constexpr int TR = ROWS + 2;
    constexpr int TWd = W + 2;
    constexpr int PS = TR * TWd * 8 + 8;
    __shared__ __align__(16) unsigned short smem[G * PS];

    const int tid  = threadIdx.x;
    const int lane = tid & 63;
    const int wv   = tid >> 6;
    const int q    = lane >> 5;
    const int y0   = blockIdx.x * ROWS;
    const int b    = blockIdx.y;

    for (int i = tid; i < G * TR * TWd; i += 256) {
        int g = i % G;
        int u = (i / G) % TWd;
        int t = i / (G * TWd);
        int yg = y0 + t - 1, xg = u - 1;
        uint4 v = make_uint4(0, 0, 0, 0);
        if (yg >= 0 && yg < H && xg >= 0 && xg < W)
            v = *(const uint4*)(in + (((size_t)(b * H + yg) * W + xg) * CIN + g * 8));
        *(uint4*)(&smem[g * PS + (t * TWd + u) * 8]) = v;
    }
    __syncthreads();

    const int p = wv * 32 + (lane & 31);
    const int r = p / W;
    const int x = p % W;

    f32x16 acc[MT];
#pragma unroll
    for (int mt = 0; mt < MT; ++mt)
#pragma unroll
        for (int i = 0; i < 16; ++i) acc[mt][i] = 0.f;

    const unsigned short* wbase = wpk + lane * 8;

#pragma unroll
    for (int s = 0; s < 9; ++s) {
        const int dy = s / 3, dx = s % 3;
#pragma unroll
        for (int kst = 0; kst < KST; ++kst) {
            const int g = kst * 2 + q;
            bf16x8 bfrag = *(const bf16x8*)(&smem[g * PS + ((r + dy) * TWd + (x + dx)) * 8]);
#pragma unroll
            for (int mt = 0; mt < MT; ++mt) {
                bf16x8 a = *(const bf16x8*)(wbase + ((s * KST + kst) * MT + mt) * 512);
                acc[mt] = __builtin_amdgcn_mfma_f32_32x32x16_bf16(a, bfrag, acc[mt], 0, 0, 0);
            }
        }
    }

    size_t base = ((size_t)(b * H + y0 + r) * W + x) * COUT;
#pragma unroll
    for (int mt = 0; mt < MT; ++mt)
#pragma unroll
        for (int rg = 0; rg < 4; ++rg) {
            int oc = mt * 32 + 8 * rg + 4 * q;
            unsigned short s0 = f2bf(fmaxf(acc[mt][rg * 4 + 0] + bias[oc + 0], 0.f));
            unsigned short s1 = f2bf(fmaxf(acc[mt][rg * 4 + 1] + bias[oc + 1], 0.f));
            unsigned short s2 = f2bf(fmaxf(acc[mt][rg * 4 + 2] + bias[oc + 2], 0.f));
            unsigned short s3 = f2bf(fmaxf(acc[mt][rg * 4 + 3] + bias[oc + 3], 0.f));
            *(uint2*)(out + base + oc) = make_uint2(pack2(s0, s1), pack2(s2, s3));
        }
}

// ---------------------------------------------------------------------------
// Fused conv1 (5x5, relu -> x1t NHWC bf16) + conv_i (3x3 -> xin NCHW fp32).
// ---------------------------------------------------------------------------
__global__ __launch_bounds__(256)
void conv1i_mfma(const unsigned short* __restrict__ imgT,
                 const unsigned short* __restrict__ wpk1,
                 const unsigned short* __restrict__ wpki,
                 const float* __restrict__ b1, const float* __restrict__ bi,
                 unsigned short* __restrict__ x1t, float* __restrict__ xin)
{
    __shared__ __align__(16) unsigned short smem[2 * 5 * 132 * 8];

    const int tid  = threadIdx.x;
    const int lane = tid & 63;
    const int wv   = tid >> 6;
    const int n    = lane & 31;
    const int q    = lane >> 5;
    const int y    = blockIdx.x >> 1;
    const int x0   = (blockIdx.x & 1) * 128;
    const int b    = blockIdx.y;

    for (int i = tid; i < 5 * 132 * 2; i += 256) {
        int r   = i / 264;
        int rem = i - r * 264;
        int xi  = rem >> 1;
        int g   = rem & 1;
        int yg = y + r - 2;
        int xg = x0 - 2 + xi;
        uint4 v = make_uint4(0, 0, 0, 0);
        if (yg >= 0 && yg < 256 && xg >= 0 && xg < 256)
            v = *(const uint4*)(imgT + (((size_t)(b * 256 + yg) * 256 + xg) * 16 + g * 8));
        *(uint4*)(&smem[((g * 5 + r) * 132 + xi) * 8]) = v;
    }
    __syncthreads();

    f32x16 acc1, acci;
#pragma unroll
    for (int i = 0; i < 16; ++i) { acc1[i] = 0.f; acci[i] = 0.f; }

    const int pxl = wv * 32 + n;
    const unsigned short* wb1 = wpk1 + lane * 8;
    const unsigned short* wbi = wpki + lane * 8;

#pragma unroll
    for (int s = 0; s < 25; ++s) {
        const int dy = s / 5, dx = s % 5;
        bf16x8 bfrag = *(const bf16x8*)(&smem[((q * 5 + dy) * 132 + pxl + dx) * 8]);
        bf16x8 a = *(const bf16x8*)(wb1 + s * 512);
        acc1 = __builtin_amdgcn_mfma_f32_32x32x16_bf16(a, bfrag, acc1, 0, 0, 0);
    }
#pragma unroll
    for (int s = 0; s < 9; ++s) {
        const int dy = s / 3, dx = s % 3;
        bf16x8 bfrag = *(const bf16x8*)(&smem[((q * 5 + dy + 1) * 132 + pxl + dx + 1) * 8]);
        bf16x8 a = *(const bf16x8*)(wbi + s * 512);
        acci = __builtin_amdgcn_mfma_f32_32x32x16_bf16(a, bfrag, acci, 0, 0, 0);
    }

    const int px = x0 + pxl;
    size_t base1 = ((size_t)(b * 256 + y) * 256 + px) * 16;
#pragma unroll
    for (int rg = 0; rg < 2; ++rg) {
        int oc = 8 * rg + 4 * q;
        unsigned short s0 = f2bf(fmaxf(acc1[rg * 4 + 0] + b1[oc + 0], 0.f));
        unsigned short s1 = f2bf(fmaxf(acc1[rg * 4 + 1] + b1[oc + 1], 0.f));
        unsigned short s2 = f2bf(fmaxf(acc1[rg * 4 + 2] + b1[oc + 2], 0.f));
        unsigned short s3 = f2bf(fmaxf(acc1[rg * 4 + 3] + b1[oc + 3], 0.f));
        *(uint2*)(x1t + base1 + oc) = make_uint2(pack2(s0, s1), pack2(s2, s3));
    }
#pragma unroll
    for (int reg = 0; reg < 8; ++reg) {
        int row = (reg & 3) + 8 * (reg >> 2) + 4 * q;
        xin[((size_t)(b * 16 + row) * 256 + y) * 256 + px] = acci[reg] + bi[row];
    }
}

// ---------------------------------------------------------------------------
// conv8 MFMA: Cin=64, Cout=32, 128x128, relu -> x8t NHWC bf16.
// ---------------------------------------------------------------------------
__global__ __launch_bounds__(256)
void conv8_mfma(const unsigned short* __restrict__ cat8t,
                const unsigned short* __restrict__ wpk8,
                const float* __restrict__ bias,
                unsigned short* __restrict__ x8t)
{
    __shared__ __align__(16) unsigned short smem[8 * 3 * 130 * 8];

    const int tid  = threadIdx.x;
    const int lane = tid & 63;
    const int wv   = tid >> 6;
    const int n    = lane & 31;
    const int q    = lane >> 5;
    const int y    = blockIdx.x;
    const int b    = blockIdx.y;

    for (int i = tid; i < 3 * 130 * 8; i += 256) {
        int r   = i / 1040;
        int rem = i - r * 1040;
        int xi  = rem >> 3;
        int g   = rem & 7;
        int yg = y + r - 1;
        int xg = xi - 1;
        uint4 v = make_uint4(0, 0, 0, 0);
        if (yg >= 0 && yg < 128 && xg >= 0 && xg < 128)
            v = *(const uint4*)(cat8t + (((size_t)(b * 128 + yg) * 128 + xg) * 64 + g * 8));
        *(uint4*)(&smem[((g * 3 + r) * 130 + xi) * 8]) = v;
    }
    __syncthreads();

    f32x16 acc;
#pragma unroll
    for (int i = 0; i < 16; ++i) acc[i] = 0.f;

    const int pxl = wv * 32 + n;
    const unsigned short* wbase = wpk8 + lane * 8;

#pragma unroll
    for (int s = 0; s < 9; ++s) {
        const int dy = s / 3, dx = s % 3;
        const int xi = pxl + dx;
#pragma unroll
        for (int kst = 0; kst < 4; ++kst) {
            const int g = kst * 2 + q;
            bf16x8 bfrag = *(const bf16x8*)(&smem[((g * 3 + dy) * 130 + xi) * 8]);
            bf16x8 a = *(const bf16x8*)(wbase + (s * 4 + kst) * 512);
            acc = __builtin_amdgcn_mfma_f32_32x32x16_bf16(a, bfrag, acc, 0, 0, 0);
        }
    }

    size_t base = ((size_t)(b * 128 + y) * 128 + pxl) * 32;
#pragma unroll
    for (int rg = 0; rg < 4; ++rg) {
        int oc0 = 8 * rg + 4 * q;
        unsigned short s0 = f2bf(fmaxf(acc[rg * 4 + 0] + bias[oc0 + 0], 0.f));
        unsigned short s1 = f2bf(fmaxf(acc[rg * 4 + 1] + bias[oc0 + 1], 0.f));
        unsigned short s2 = f2bf(fmaxf(acc[rg * 4 + 2] + bias[oc0 + 2], 0.f));
        unsigned short s3 = f2bf(fmaxf(acc[rg * 4 + 3] + bias[oc0 + 3], 0.f));
        *(uint2*)(x8t + base + oc0) = make_uint2(pack2(s0, s1), pack2(s2, s3));
    }
}

// ---------------------------------------------------------------------------
// upcat9 -> xt9 NHWC bf16 [b][256][256][48]; skip from x1t NHWC bf16.
// ---------------------------------------------------------------------------
__global__ void upcat9_nhwc(const unsigned short* __restrict__ x8t,
                            const unsigned short* __restrict__ x1t,
                            unsigned short* __restrict__ dst)
{
    int idx = blockIdx.x * 256 + threadIdx.x;
    if (idx >= 8 * 256 * 256) return;
    int x = idx & 255, y = (idx >> 8) & 255, b = idx >> 16;
    int i00, i01, i10, i11; float wy, wx;
    bilin_setup(y, x, 128, 128, i00, i01, i10, i11, wy, wx);
    const unsigned short* sb = x8t + (size_t)b * 128 * 128 * 32;
    unsigned short* d = dst + (size_t)idx * 48;
    float w00 = (1.f - wy) * (1.f - wx), w01 = (1.f - wy) * wx;
    float w10 = wy * (1.f - wx),         w11 = wy * wx;
#pragma unroll
    for (int g = 0; g < 4; ++g) {
        u16x8 v00 = *(const u16x8*)(sb + (size_t)i00 * 32 + g * 8);
        u16x8 v01 = *(const u16x8*)(sb + (size_t)i01 * 32 + g * 8);
        u16x8 v10 = *(const u16x8*)(sb + (size_t)i10 * 32 + g * 8);
        u16x8 v11 = *(const u16x8*)(sb + (size_t)i11 * 32 + g * 8);
        u16x8 r;
#pragma unroll
        for (int j = 0; j < 8; ++j)
            r[j] = f2bf(w00 * bf2f(v00[j]) + w01 * bf2f(v01[j]) +
                        w10 * bf2f(v10[j]) + w11 * bf2f(v11[j]));
        *(u16x8*)(d + g * 8) = r;
    }
    const unsigned short* x1b = x1t + ((size_t)(b * 256 + y) * 256 + x) * 16;
    *(u16x8*)(d + 32) = *(const u16x8*)(x1b);
    *(u16x8*)(d + 40) = *(const u16x8*)(x1b + 8);
}

// ---------------------------------------------------------------------------
// conv9 MFMA: K=48, 64 oc, 256x256, tanh -> fm NCHW fp32.
// ---------------------------------------------------------------------------
__global__ __launch_bounds__(256)
void conv9_mfma(const unsigned short* __restrict__ xt9,
                const unsigned short* __restrict__ wpk,
                const float* __restrict__ bias,
                float* __restrict__ fm)
{
    __shared__ __align__(16) unsigned short smem[6 * 3 * 130 * 8];

    const int tid  = threadIdx.x;
    const int lane = tid & 63;
    const int wv   = tid >> 6;
    const int n    = lane & 31;
    const int q    = lane >> 5;
    const int y    = blockIdx.x >> 1;
    const int x0   = (blockIdx.x & 1) * 128;
    const int b    = blockIdx.y;

    for (int i = tid; i < 3 * 130 * 6; i += 256) {
        int r   = i / 780;
        int rem = i - r * 780;
        int xi  = rem / 6;
        int g   = rem - xi * 6;
        int yg = y + r - 1;
        int xg = x0 - 1 + xi;
        uint4 v = make_uint4(0, 0, 0, 0);
        if (yg >= 0 && yg < 256 && xg >= 0 && xg < 256)
            v = *(const uint4*)(xt9 + (((size_t)(b * 256 + yg) * 256 + xg) * 48 + g * 8));
        *(uint4*)(&smem[((g * 3 + r) * 130 + xi) * 8]) = v;
    }
    __syncthreads();

    f32x16 acc0, acc1;
#pragma unroll
    for (int i = 0; i < 16; ++i) { acc0[i] = 0.f; acc1[i] = 0.f; }

    const int pxl = wv * 32 + n;
    const unsigned short* wbase = wpk + lane * 8;

#pragma unroll
    for (int s = 0; s < 9; ++s) {
        const int dy = s / 3, dx = s % 3;
        const int xi = pxl + dx;
#pragma unroll
        for (int kst = 0; kst < 3; ++kst) {
            const int g = kst * 2 + q;
            bf16x8 bfrag = *(const bf16x8*)(&smem[((g * 3 + dy) * 130 + xi) * 8]);
            bf16x8 a0 = *(const bf16x8*)(wbase + ((s * 3 + kst) * 2 + 0) * 512);
            bf16x8 a1 = *(const bf16x8*)(wbase + ((s * 3 + kst) * 2 + 1) * 512);
            acc0 = __builtin_amdgcn_mfma_f32_32x32x16_bf16(a0, bfrag, acc0, 0, 0, 0);
            acc1 = __builtin_amdgcn_mfma_f32_32x32x16_bf16(a1, bfrag, acc1, 0, 0, 0);
        }
    }

    const int px = x0 + pxl;
#pragma unroll
    for (int reg = 0; reg < 16; ++reg) {
        int row = (reg & 3) + 8 * (reg >> 2) + 4 * q;
        int oc0 = row, oc1 = 32 + row;
        fm[(((size_t)b * 64 + oc0) * 256 + y) * 256 + px] = fast_tanh(acc0[reg] + bias[oc0]);
        fm[(((size_t)b * 64 + oc1) * 256 + y) * 256 + px] = fast_tanh(acc1[reg] + bias[oc1]);
    }
}

// ---------------------------------------------------------------------------
// Segmented W-direction LRNN pair (fwd+rev) -> rnnW NHWC bf16.
// Block: (b, c, 16-row tile). Two-pass affine scan: pass1 computes per-32-seg
// gate products + zero-init partials; 32-thread serial combine gives exact
// h_in per segment; pass2 rescans and emits max(h1,h2). Rev outputs stay
// spatially flipped (step-order). Gates: fm channels {c, 32+c}.
// ---------------------------------------------------------------------------
__global__ __launch_bounds__(256)
void lrnn_w_seg(const float* __restrict__ X, const float* __restrict__ FM,
                unsigned short* __restrict__ rnnW)
{
    __shared__ float tx[3][16][258];                 // 49536 B
    __shared__ unsigned short outm[2][16][256];      // 16384 B
    __shared__ float segres[2][16][8][4];
    __shared__ float hin[2][16][8][2];

    const int tid = threadIdx.x;
    const int bid = blockIdx.x;
    const int yt = bid & 15;
    const int c  = (bid >> 4) & 15;
    const int b  = bid >> 8;
    const int y0 = yt * 16;

    const size_t xb  = ((size_t)(b * 16 + c) * 256 + y0) * 256;
    const size_t p1b = ((size_t)(b * 64 + c) * 256 + y0) * 256;
    const size_t p2b = ((size_t)(b * 64 + 32 + c) * 256 + y0) * 256;

    for (int i = tid; i < 3072; i += 256) {
        int s = i >> 10;
        int r = i & 1023;
        int y = r >> 6;
        int f4 = r & 63;
        size_t base = (s == 0 ? xb : (s == 1 ? p1b : p2b));
        const float* sp = (s == 0) ? X : FM;
        float4 v = *(const float4*)(sp + base + (size_t)y * 256 + f4 * 4);
        tx[s][y][f4 * 4 + 0] = v.x; tx[s][y][f4 * 4 + 1] = v.y;
        tx[s][y][f4 * 4 + 2] = v.z; tx[s][y][f4 * 4 + 3] = v.w;
    }
    __syncthreads();

    const int y  = tid & 15;
    const int sg = (tid >> 4) & 7;
    const int d  = tid >> 7;

    {   // pass 1
        float h1 = 0.f, h2 = 0.f, A1 = 1.f, A2 = 1.f;
        if (d == 0) {
            int xs = sg * 32;
#pragma unroll
            for (int i = 0; i < 32; ++i) {
                float xv = tx[0][y][xs + i], p1 = tx[1][y][xs + i], p2 = tx[2][y][xs + i];
                h1 = fmaf(p1, h1 - xv, xv); A1 *= p1;
                h2 = fmaf(p2, h2 - xv, xv); A2 *= p2;
            }
        } else {
            int xs = 255 - sg * 32;
#pragma unroll
            for (int i = 0; i < 32; ++i) {
                float xv = tx[0][y][xs - i], p1 = tx[1][y][xs - i], p2 = tx[2][y][xs - i];
                h1 = fmaf(p1, h1 - xv, xv); A1 *= p1;
                h2 = fmaf(p2, h2 - xv, xv); A2 *= p2;
            }
        }
        segres[d][y][sg][0] = h1; segres[d][y][sg][1] = A1;
        segres[d][y][sg][2] = h2; segres[d][y][sg][3] = A2;
    }
    __syncthreads();

    if (tid < 32) {
        int yy = tid & 15, dd = tid >> 4;
        float c1 = 0.f, c2 = 0.f;
        for (int s = 0; s < 8; ++s) {
            hin[dd][yy][s][0] = c1;
            hin[dd][yy][s][1] = c2;
            c1 = segres[dd][yy][s][0] + segres[dd][yy][s][1] * c1;
            c2 = segres[dd][yy][s][2] + segres[dd][yy][s][3] * c2;
        }
    }
    __syncthreads();

    {   // pass 2
        float h1 = hin[d][y][sg][0], h2 = hin[d][y][sg][1];
        if (d == 0) {
            int xs = sg * 32;
#pragma unroll
            for (int i = 0; i < 32; ++i) {
                float xv = tx[0][y][xs + i], p1 = tx[1][y][xs + i], p2 = tx[2][y][xs + i];
                h1 = fmaf(p1, h1 - xv, xv);
                h2 = fmaf(p2, h2 - xv, xv);
                outm[0][y][xs + i] = f2bf(fmaxf(h1, h2));
            }
        } else {
#pragma unroll
            for (int i = 0; i < 32; ++i) {
                int t = sg * 32 + i;
                float xv = tx[0][y][255 - t], p1 = tx[1][y][255 - t], p2 = tx[2][y][255 - t];
                h1 = fmaf(p1, h1 - xv, xv);
                h2 = fmaf(p2, h2 - xv, xv);
                outm[1][y][t] = f2bf(fmaxf(h1, h2));
            }
        }
    }
    __syncthreads();

    for (int i = tid; i < 4096; i += 256) {
        int x = i & 255, yy = i >> 8;
        float m = fmaxf(bf2f(outm[0][yy][x]), bf2f(outm[1][yy][x]));
        rnnW[((size_t)(b * 256 + y0 + yy) * 256 + x) * 16 + c] = f2bf(m);
    }
}

// ---------------------------------------------------------------------------
// Segmented H-direction LRNN pair (fwd+rev) -> rnnH NHWC bf16.
// Block: (b, c, 16-column tile). Gates: fm channels {16+c, 48+c}.
// ---------------------------------------------------------------------------
__global__ __launch_bounds__(256)
void lrnn_h_seg(const float* __restrict__ X, const float* __restrict__ FM,
                unsigned short* __restrict__ rnnH)
{
    __shared__ float tx[3][256][17];                 // 52224 B
    __shared__ unsigned short outm[2][256][16];      // 16384 B
    __shared__ float segres[2][16][8][4];
    __shared__ float hin[2][16][8][2];

    const int tid = threadIdx.x;
    const int bid = blockIdx.x;
    const int xt = bid & 15;
    const int c  = (bid >> 4) & 15;
    const int b  = bid >> 8;
    const int x0 = xt * 16;

    const size_t xb  = (size_t)(b * 16 + c) * 65536 + x0;
    const size_t p1b = (size_t)(b * 64 + 16 + c) * 65536 + x0;
    const size_t p2b = (size_t)(b * 64 + 48 + c) * 65536 + x0;

    for (int i = tid; i < 3072; i += 256) {
        int s = i >> 10;
        int r = i & 1023;
        int y = r >> 2;
        int f4 = r & 3;
        size_t base = (s == 0 ? xb : (s == 1 ? p1b : p2b));
        const float* sp = (s == 0) ? X : FM;
        float4 v = *(const float4*)(sp + base + (size_t)y * 256 + f4 * 4);
        tx[s][y][f4 * 4 + 0] = v.x; tx[s][y][f4 * 4 + 1] = v.y;
        tx[s][y][f4 * 4 + 2] = v.z; tx[s][y][f4 * 4 + 3] = v.w;
    }
    __syncthreads();

    const int x  = tid & 15;
    const int sg = (tid >> 4) & 7;
    const int d  = tid >> 7;

    {   // pass 1
        float h1 = 0.f, h2 = 0.f, A1 = 1.f, A2 = 1.f;
        if (d == 0) {
            int ys = sg * 32;
#pragma unroll
            for (int i = 0; i < 32; ++i) {
                float xv = tx[0][ys + i][x], p1 = tx[1][ys + i][x], p2 = tx[2][ys + i][x];
                h1 = fmaf(p1, h1 - xv, xv); A1 *= p1;
                h2 = fmaf(p2, h2 - xv, xv); A2 *= p2;
            }
        } else {
            int ys = 255 - sg * 32;
#pragma unroll
            for (int i = 0; i < 32; ++i) {
                float xv = tx[0][ys - i][x], p1 = tx[1][ys - i][x], p2 = tx[2][ys - i][x];
                h1 = fmaf(p1, h1 - xv, xv); A1 *= p1;
                h2 = fmaf(p2, h2 - xv, xv); A2 *= p2;
            }
        }
        segres[d][x][sg][0] = h1; segres[d][x][sg][1] = A1;
        segres[d][x][sg][2] = h2; segres[d][x][sg][3] = A2;
    }
    __syncthreads();

    if (tid < 32) {
        int xx = tid & 15, dd = tid >> 4;
        float c1 = 0.f, c2 = 0.f;
        for (int s = 0; s < 8; ++s) {
            hin[dd][xx][s][0] = c1;
            hin[dd][xx][s][1] = c2;
            c1 = segres[dd][xx][s][0] + segres[dd][xx][s][1] * c1;
            c2 = segres[dd][xx][s][2] + segres[dd][xx][s][3] * c2;
        }
    }
    __syncthreads();

    {   // pass 2
        float h1 = hin[d][x][sg][0], h2 = hin[d][x][sg][1];
        if (d == 0) {
            int ys = sg * 32;
#pragma unroll
            for (int i = 0; i < 32; ++i) {
                float xv = tx[0][ys + i][x], p1 = tx[1][ys + i][x], p2 = tx[2][ys + i][x];
                h1 = fmaf(p1, h1 - xv, xv);
                h2 = fmaf(p2, h2 - xv, xv);
                outm[0][ys + i][x] = f2bf(fmaxf(h1, h2));
            }
        } else {
#pragma unroll
            for (int i = 0; i < 32; ++i) {
                int t = sg * 32 + i;
                float xv = tx[0][255 - t][x], p1 = tx[1][255 - t][x], p2 = tx[2][255 - t][x];
                h1 = fmaf(p1, h1 - xv, xv);
                h2 = fmaf(p2, h2 - xv, xv);
                outm[1][t][x] = f2bf(fmaxf(h1, h2));
            }
        }
    }
    __syncthreads();

    for (int i = tid; i < 4096; i += 256) {
        int xx = i & 15, yy = i >> 4;
        float m = fmaxf(bf2f(outm[0][yy][xx]), bf2f(outm[1][yy][xx]));
        rnnH[((size_t)(b * 256 + yy) * 256 + x0 + xx) * 16 + c] = f2bf(m);
    }
}

// ---------------------------------------------------------------------------
// Output head MFMA: max(rnnW, rnnH) staged -> 3x3 conv (Cin16, Cout3),
// sigmoid -> d_out NCHW fp32.
// ---------------------------------------------------------------------------
__global__ __launch_bounds__(256)
void convo_mfma(const unsigned short* __restrict__ rnnW,
                const unsigned short* __restrict__ rnnH,
                const unsigned short* __restrict__ wpko,
                const float* __restrict__ bo,
                float* __restrict__ outp)
{
    __shared__ __align__(16) unsigned short smem[2 * 3 * 130 * 8];

    const int tid  = threadIdx.x;
    const int lane = tid & 63;
    const int wv   = tid >> 6;
    const int n    = lane & 31;
    const int q    = lane >> 5;
    const int y    = blockIdx.x >> 1;
    const int x0   = (blockIdx.x & 1) * 128;
    const int b    = blockIdx.y;

    for (int i = tid; i < 3 * 130 * 2; i += 256) {
        int r   = i / 260;
        int rem = i - r * 260;
        int xi  = rem >> 1;
        int g   = rem & 1;
        int yg = y + r - 1;
        int xg = x0 - 1 + xi;
        u16x8 m = {0, 0, 0, 0, 0, 0, 0, 0};
        if (yg >= 0 && yg < 256 && xg >= 0 && xg < 256) {
            size_t off = (((size_t)(b * 256 + yg) * 256 + xg) * 16 + g * 8);
            u16x8 a = *(const u16x8*)(rnnW + off);
            u16x8 bb = *(const u16x8*)(rnnH + off);
#pragma unroll
            for (int j = 0; j < 8; ++j)
                m[j] = f2bf(fmaxf(bf2f(a[j]), bf2f(bb[j])));
        }
        *(u16x8*)(&smem[((g * 3 + r) * 130 + xi) * 8]) = m;
    }
    __syncthreads();

    f32x16 acc;
#pragma unroll
    for (int i = 0; i < 16; ++i) acc[i] = 0.f;

    const int pxl = wv * 32 + n;
    const unsigned short* wbase = wpko + lane * 8;

#pragma unroll
    for (int s = 0; s < 9; ++s) {
        const int dy = s / 3, dx = s % 3;
        bf16x8 bfrag = *(const bf16x8*)(&smem[((q * 3 + dy) * 130 + pxl + dx) * 8]);
        bf16x8 a = *(const bf16x8*)(wbase + s * 512);
        acc = __builtin_amdgcn_mfma_f32_32x32x16_bf16(a, bfrag, acc, 0, 0, 0);
    }

    const int px = x0 + pxl;
    if (q == 0) {
#pragma unroll
        for (int oc = 0; oc < 3; ++oc) {
            float r = acc[oc] + bo[oc];      // row = reg for reg 0..2, q=0
            outp[((size_t)(b * 3 + oc) * 256 + y) * 256 + px] = 1.f / (1.f + __expf(-r));
        }
    }
}

// ---------------------------------------------------------------------------
extern "C" void kernel_launch(void* const* d_in, const int* in_sizes, int n_in,
                              void* d_out, int out_size, void* d_ws, size_t ws_size,
                              hipStream_t stream)
{
    const float* img = (const float*)d_in[0];
    const float* w1 = (const float*)d_in[1];  const float* b1 = (const float*)d_in[2];
    const float* w2 = (const float*)d_in[3];  const float* b2 = (const float*)d_in[4];
    const float* w3 = (const float*)d_in[5];  const float* b3 = (const float*)d_in[6];
    const float* w4 = (const float*)d_in[7];  const float* b4 = (const float*)d_in[8];
    const float* w5 = (const float*)d_in[9];  const float* b5 = (const float*)d_in[10];
    const float* w6 = (const float*)d_in[11]; const float* b6 = (const float*)d_in[12];
    const float* w7 = (const float*)d_in[13]; const float* b7 = (const float*)d_in[14];
    const float* w8 = (const float*)d_in[15]; const float* b8 = (const float*)d_in[16];
    const float* w9 = (const float*)d_in[17]; const float* b9 = (const float*)d_in[18];
    const float* wi = (const float*)d_in[19]; const float* bi = (const float*)d_in[20];
    const float* wo = (const float*)d_in[21]; const float* bo = (const float*)d_in[22];

    char* wsb = (char*)d_ws;
    const size_t MB = (size_t)(1u << 20);
    unsigned short* imgT  = (unsigned short*)(wsb);            // [0,16)
    unsigned short* x1t   = (unsigned short*)(wsb + 16 * MB);  // [16,32)
    unsigned short* p1t   = (unsigned short*)(wsb + 32 * MB);  // [32,36)
    unsigned short* x2t   = (unsigned short*)(wsb + 36 * MB);  // [36,44)
    unsigned short* p2t   = (unsigned short*)(wsb + 44 * MB);  // [44,46)
    unsigned short* x3t   = (unsigned short*)(wsb + 46 * MB);  // [46,48)
    unsigned short* p3t   = (unsigned short*)(wsb + 48 * MB);  // [48,48.5)
    unsigned short* x4t   = (unsigned short*)(wsb + 49 * MB);  // [49,49.5)
    unsigned short* p4t   = (unsigned short*)(wsb + 50 * MB);  // [50,50.125)
    unsigned short* x5t   = (unsigned short*)(wsb + 51 * MB);  // [51,51.25)
    unsigned short* cat6t = (unsigned short*)(wsb + 52 * MB);  // [52,53.5)
    unsigned short* x6t   = (unsigned short*)(wsb + 54 * MB);  // [54,54.5)
    unsigned short* cat7t = (unsigned short*)(wsb + 55 * MB);  // [55,59)
    unsigned short* x7t   = (unsigned short*)(wsb + 59 * MB);  // [59,61)
    unsigned short* cat8t = (unsigned short*)(wsb + 62 * MB);  // [62,78)
    unsigned short* x8t   = (unsigned short*)(wsb + 78 * MB);  // [78,86)
    unsigned short* xt9   = (unsigned short*)(wsb + 128 * MB); // [128,176)
    float* fm    = (float*)(wsb);                              // [0,128)
    unsigned short* rnnW = (unsigned short*)(wsb + 128 * MB);  // [128,144) (xt9 dead)
    unsigned short* rnnH = (unsigned short*)(wsb + 144 * MB);  // [144,160)
    float* xin   = (float*)(wsb + 176 * MB);                   // [176,208)
    unsigned short* wpk9 = (unsigned short*)(wsb + 208 * MB);
    unsigned short* wpk8 = wpk9 + 27648;
    unsigned short* wpk1 = wpk8 + 18432;
    unsigned short* wpki = wpk1 + 12800;
    unsigned short* wpko = wpki + 4608;
    unsigned short* wpk2 = wpko + 4608;
    unsigned short* wpk3 = wpk2 + 4608;
    unsigned short* wpk4 = wpk3 + 9216;
    unsigned short* wpk5 = wpk4 + 9216;
    unsigned short* wpk6 = wpk5 + 18432;
    unsigned short* wpk7 = wpk6 + 27648;
    float* outp = (float*)d_out;

    // --- weight packs + img transpose ---
    wprep_all<<<266, 256, 0, stream>>>(w9, w8, w1, wi, wo, wpk9, wpk8, wpk1, wpki, wpko);
    wpack<<<18, 256, 0, stream>>>(w2, wpk2, 16, 32);
    wpack<<<36, 256, 0, stream>>>(w3, wpk3, 32, 32);
    wpack<<<36, 256, 0, stream>>>(w4, wpk4, 32, 32);
    wpack<<<72, 256, 0, stream>>>(w5, wpk5, 32, 64);
    wpack<<<108, 256, 0, stream>>>(w6, wpk6, 96, 32);
    wpack<<<72, 256, 0, stream>>>(w7, wpk7, 64, 32);
    imgT_bf16<<<2048, 256, 0, stream>>>(img, imgT);

    // --- fused conv1 (relu -> x1t NHWC) + input projection (xin NCHW) ---
    { dim3 grd(512, 8);
      conv1i_mfma<<<grd, 256, 0, stream>>>(imgT, wpk1, wpki, b1, bi, x1t, xin); }

    // --- encoder (NHWC bf16 MFMA) ---
    pool_nhwc<<<1024, 256, 0, stream>>>(x1t, p1t, 128, 128, 2);
    convN_mfma<16, 32, 128, 128, 1><<<dim3(128, 8), 256, 0, stream>>>(p1t, wpk2, b2, x2t);
    pool_nhwc<<<512, 256, 0, stream>>>(x2t, p2t, 64, 64, 4);
    convN_mfma<32, 32, 64, 64, 2><<<dim3(32, 8), 256, 0, stream>>>(p2t, wpk3, b3, x3t);
    pool_nhwc<<<128, 256, 0, stream>>>(x3t, p3t, 32, 32, 4);
    convN_mfma<32, 32, 32, 32, 4><<<dim3(8, 8), 256, 0, stream>>>(p3t, wpk4, b4, x4t);
    pool_nhwc<<<32, 256, 0, stream>>>(x4t, p4t, 16, 16, 4);
    convN_mfma<32, 64, 16, 16, 8><<<dim3(2, 8), 256, 0, stream>>>(p4t, wpk5, b5, x5t);

    // --- decoder (NHWC bf16) ---
    upcat_nhwc2<<<384, 256, 0, stream>>>(x5t, x4t, cat6t, 64, 32, 32, 32);
    convN_mfma<96, 32, 32, 32, 4><<<dim3(8, 8), 256, 0, stream>>>(cat6t, wpk6, b6, x6t);
    upcat_nhwc2<<<1024, 256, 0, stream>>>(x6t, x3t, cat7t, 32, 32, 64, 64);
    convN_mfma<64, 32, 64, 64, 2><<<dim3(32, 8), 256, 0, stream>>>(cat7t, wpk7, b7, x7t);
    upcat_nhwc2<<<4096, 256, 0, stream>>>(x7t, x2t, cat8t, 32, 32, 128, 128);
    { dim3 grd(128, 8);
      conv8_mfma<<<grd, 256, 0, stream>>>(cat8t, wpk8, b8, x8t); }

    // --- stage 9 ---
    { int tot = 8 * 256 * 256;
      upcat9_nhwc<<<(tot + 255) / 256, 256, 0, stream>>>(x8t, x1t, xt9); }
    { dim3 grd(512, 8);
      conv9_mfma<<<grd, 256, 0, stream>>>(xt9, wpk9, b9, fm); }

    // --- spatial RNN: segmented two-pass scans, independent W/H outputs ---
    lrnn_w_seg<<<2048, 256, 0, stream>>>(xin, fm, rnnW);
    lrnn_h_seg<<<2048, 256, 0, stream>>>(xin, fm, rnnH);

    // --- output head: max(rnnW,rnnH) -> conv -> sigmoid ---
    { dim3 grd(512, 8);
      convo_mfma<<<grd, 256, 0, stream>>>(rnnW, rnnH, wpko, bo, outp); }
}

// Round 9
// 445.849 us; speedup vs baseline: 5.2090x; 1.0442x over previous
//
#include <hip/hip_runtime.h>
#include <math.h>

typedef __attribute__((ext_vector_type(8)))  short bf16x8;
typedef __attribute__((ext_vector_type(8)))  unsigned short u16x8;
typedef __attribute__((ext_vector_type(16))) float f32x16;

__device__ __forceinline__ unsigned short f2bf(float f) {
    unsigned u = __float_as_uint(f);
    unsigned r = (u + 0x7FFFu + ((u >> 16) & 1u)) >> 16;
    return (unsigned short)r;
}
__device__ __forceinline__ float bf2f(unsigned short h) {
    return __uint_as_float(((unsigned)h) << 16);
}
__device__ __forceinline__ unsigned pack2(unsigned short a, unsigned short b) {
    return (unsigned)a | ((unsigned)b << 16);
}
__device__ __forceinline__ float fast_tanh(float x) {
    float e = __expf(2.f * x);
    return 1.f - 2.f / (e + 1.f);
}

// ---------------------------------------------------------------------------
// NHWC bf16 2x2 maxpool (stride 2). C8 = C/8 vector groups.
// ---------------------------------------------------------------------------
__global__ void pool_nhwc(const unsigned short* __restrict__ in,
                          unsigned short* __restrict__ out,
                          int Ho, int Wo, int C8)
{
    int idx = blockIdx.x * 256 + threadIdx.x;
    int total = 8 * Ho * Wo * C8;
    if (idx >= total) return;
    int g = idx % C8;
    int p = idx / C8;
    int x = p % Wo;
    int y = (p / Wo) % Ho;
    int b = p / (Wo * Ho);
    int Wi = Wo * 2, C = C8 * 8;
    const unsigned short* q0 = in + (((size_t)(b * Ho * 2 + 2 * y) * Wi + 2 * x) * C + g * 8);
    u16x8 v0 = *(const u16x8*)q0;
    u16x8 v1 = *(const u16x8*)(q0 + C);
    u16x8 v2 = *(const u16x8*)(q0 + (size_t)Wi * C);
    u16x8 v3 = *(const u16x8*)(q0 + (size_t)Wi * C + C);
    u16x8 r;
#pragma unroll
    for (int j = 0; j < 8; ++j)
        r[j] = f2bf(fmaxf(fmaxf(bf2f(v0[j]), bf2f(v1[j])), fmaxf(bf2f(v2[j]), bf2f(v3[j]))));
    *(u16x8*)(out + (size_t)idx * 8) = r;
}

__device__ __forceinline__ void bilin_setup(int y, int x, int Hi, int Wi,
                                            int& i00, int& i01, int& i10, int& i11,
                                            float& wy, float& wx)
{
    float fy = 0.5f * y - 0.25f;
    float fx = 0.5f * x - 0.25f;
    float y0f = floorf(fy), x0f = floorf(fx);
    wy = fy - y0f; wx = fx - x0f;
    int yA = (int)y0f, xA = (int)x0f;
    int yB = yA + 1, xB = xA + 1;
    yA = yA < 0 ? 0 : (yA > Hi - 1 ? Hi - 1 : yA);
    yB = yB < 0 ? 0 : (yB > Hi - 1 ? Hi - 1 : yB);
    xA = xA < 0 ? 0 : (xA > Wi - 1 ? Wi - 1 : xA);
    xB = xB < 0 ? 0 : (xB > Wi - 1 ? Wi - 1 : xB);
    i00 = yA * Wi + xA; i01 = yA * Wi + xB;
    i10 = yB * Wi + xA; i11 = yB * Wi + xB;
}

// ---------------------------------------------------------------------------
// NHWC bf16 upsample(2x) + concat (stages 6,7,8).
// ---------------------------------------------------------------------------
__global__ void upcat_nhwc2(const unsigned short* __restrict__ up,
                            const unsigned short* __restrict__ skip,
                            unsigned short* __restrict__ dst,
                            int C1, int C2, int H, int W)
{
    int C8 = (C1 + C2) >> 3;
    int idx = blockIdx.x * 256 + threadIdx.x;
    int total = 8 * H * W * C8;
    if (idx >= total) return;
    int g = idx % C8;
    int p = idx / C8;
    int x = p % W;
    int y = (p / W) % H;
    int b = p / (W * H);
    u16x8 r;
    if (g < (C1 >> 3)) {
        int Hi = H >> 1, Wi = W >> 1;
        int i00, i01, i10, i11; float wy, wx;
        bilin_setup(y, x, Hi, Wi, i00, i01, i10, i11, wy, wx);
        const unsigned short* sb = up + (size_t)b * Hi * Wi * C1 + g * 8;
        u16x8 v00 = *(const u16x8*)(sb + (size_t)i00 * C1);
        u16x8 v01 = *(const u16x8*)(sb + (size_t)i01 * C1);
        u16x8 v10 = *(const u16x8*)(sb + (size_t)i10 * C1);
        u16x8 v11 = *(const u16x8*)(sb + (size_t)i11 * C1);
        float w00 = (1.f - wy) * (1.f - wx), w01 = (1.f - wy) * wx;
        float w10 = wy * (1.f - wx),         w11 = wy * wx;
#pragma unroll
        for (int j = 0; j < 8; ++j)
            r[j] = f2bf(w00 * bf2f(v00[j]) + w01 * bf2f(v01[j]) +
                        w10 * bf2f(v10[j]) + w11 * bf2f(v11[j]));
    } else {
        r = *(const u16x8*)(skip + ((size_t)(b * H + y) * W + x) * C2 + (g - (C1 >> 3)) * 8);
    }
    *(u16x8*)(dst + (((size_t)(b * H + y) * W + x) * (C1 + C2) + g * 8)) = r;
}

// ---------------------------------------------------------------------------
// img [8][15][256][256] fp32 -> imgT [b][y][x][16] bf16 (ch15 = 0)
// ---------------------------------------------------------------------------
__global__ void imgT_bf16(const float* __restrict__ img, unsigned short* __restrict__ dst)
{
    int idx = blockIdx.x * 256 + threadIdx.x;
    if (idx >= 8 * 256 * 256) return;
    int x = idx & 255, y = (idx >> 8) & 255, b = idx >> 16;
    unsigned short v[16];
#pragma unroll
    for (int c = 0; c < 15; ++c)
        v[c] = f2bf(img[(size_t)(b * 15 + c) * 65536 + y * 256 + x]);
    v[15] = 0;
    uint4 lo = make_uint4(pack2(v[0], v[1]), pack2(v[2], v[3]), pack2(v[4], v[5]), pack2(v[6], v[7]));
    uint4 hi = make_uint4(pack2(v[8], v[9]), pack2(v[10], v[11]), pack2(v[12], v[13]), pack2(v[14], v[15]));
    *(uint4*)(dst + (size_t)idx * 16)     = lo;
    *(uint4*)(dst + (size_t)idx * 16 + 8) = hi;
}

// ---------------------------------------------------------------------------
// Generic weight pack: w [Cout][Cin][3][3] fp32 -> bf16 A-fragments.
// ---------------------------------------------------------------------------
__global__ void wpack(const float* __restrict__ w, unsigned short* __restrict__ dst,
                      int Cin, int Cout)
{
    int KST = Cin >> 4, MT = Cout >> 5;
    int total = 9 * KST * MT * 512;
    int idx = blockIdx.x * 256 + threadIdx.x;
    if (idx >= total) return;
    int j = idx & 7;
    int lane = (idx >> 3) & 63;
    int t = idx >> 9;
    int mt = t % MT; t /= MT;
    int kst = t % KST;
    int s = t / KST;
    int oc = mt * 32 + (lane & 31);
    int ci = kst * 16 + (lane >> 5) * 8 + j;
    dst[idx] = f2bf(w[(oc * Cin + ci) * 9 + s]);
}

// Special packs: w9 (K=48), w8 (K=64), w1 (5x5, Cin15->16), wi, wo (3 oc -> 32).
__global__ void wprep_all(const float* __restrict__ w9, const float* __restrict__ w8,
                          const float* __restrict__ w1, const float* __restrict__ wi,
                          const float* __restrict__ wo,
                          unsigned short* __restrict__ wpk9, unsigned short* __restrict__ wpk8,
                          unsigned short* __restrict__ wpk1, unsigned short* __restrict__ wpki,
                          unsigned short* __restrict__ wpko)
{
    int idx = blockIdx.x * 256 + threadIdx.x;
    if (idx < 27648) {
        int j = idx & 7;
        int t = idx >> 3;
        int lane = t & 63; t >>= 6;
        int mt = t & 1; t >>= 1;
        int kst = t % 3;
        int s = t / 3;
        int oc = mt * 32 + (lane & 31);
        int ci = kst * 16 + (lane >> 5) * 8 + j;
        wpk9[idx] = f2bf(w9[(oc * 48 + ci) * 9 + s]);
    } else if (idx < 46080) {
        int i = idx - 27648;
        int j = i & 7;
        int lane = (i >> 3) & 63;
        int t = i >> 9;
        int kst = t & 3;
        int s = t >> 2;
        int oc = lane & 31;
        int ci = kst * 16 + (lane >> 5) * 8 + j;
        wpk8[i] = f2bf(w8[(oc * 64 + ci) * 9 + s]);
    } else if (idx < 58880) {
        int i = idx - 46080;
        int j = i & 7;
        int lane = (i >> 3) & 63;
        int s = i >> 9;                 // 0..24
        int oc = lane & 31;
        int ci = (lane >> 5) * 8 + j;   // 0..15
        float v = 0.f;
        if (oc < 16 && ci < 15) v = w1[((oc * 15 + ci) * 5 + s / 5) * 5 + s % 5];
        wpk1[i] = f2bf(v);
    } else if (idx < 63488) {
        int i = idx - 58880;
        int j = i & 7;
        int lane = (i >> 3) & 63;
        int s = i >> 9;                 // 0..8
        int oc = lane & 31;
        int ci = (lane >> 5) * 8 + j;
        float v = 0.f;
        if (oc < 16 && ci < 15) v = wi[((oc * 15 + ci) * 3 + s / 3) * 3 + s % 3];
        wpki[i] = f2bf(v);
    } else if (idx < 68096) {
        int i = idx - 63488;
        int j = i & 7;
        int lane = (i >> 3) & 63;
        int s = i >> 9;                 // 0..8
        int oc = lane & 31;
        int ci = (lane >> 5) * 8 + j;   // 0..15
        float v = 0.f;
        if (oc < 3) v = wo[((oc * 16 + ci) * 3 + s / 3) * 3 + s % 3];
        wpko[i] = f2bf(v);
    }
}

// ---------------------------------------------------------------------------
// Generic NHWC bf16 MFMA conv (3x3, pad 1, relu -> NHWC bf16).
// ---------------------------------------------------------------------------
template<int CIN, int COUT, int H, int W, int ROWS>
__global__ __launch_bounds__(256)
void convN_mfma(const unsigned short* __restrict__ in,
                const unsigned short* __restrict__ wpk,
                const float* __restrict__ bias,
                unsigned short* __restrict__ out)
{
    constexpr int G = CIN / 8;
    constexpr int KST = CIN / 16;
    constexpr int MT = COUT / 32;
    constexpr int TR = ROWS + 2;
    constexpr int TWd = W + 2;
    constexpr int PS = TR * TWd * 8 + 8;
    __shared__ __align__(16) unsigned short smem[G * PS];

    const int tid  = threadIdx.x;
    const int lane = tid & 63;
    const int wv   = tid >> 6;
    const int q    = lane >> 5;
    const int y0   = blockIdx.x * ROWS;
    const int b    = blockIdx.y;

    for (int i = tid; i < G * TR * TWd; i += 256) {
        int g = i % G;
        int u = (i / G) % TWd;
        int t = i / (G * TWd);
        int yg = y0 + t - 1, xg = u - 1;
        uint4 v = make_uint4(0, 0, 0, 0);
        if (yg >= 0 && yg < H && xg >= 0 && xg < W)
            v = *(const uint4*)(in + (((size_t)(b * H + yg) * W + xg) * CIN + g * 8));
        *(uint4*)(&smem[g * PS + (t * TWd + u) * 8]) = v;
    }
    __syncthreads();

    const int p = wv * 32 + (lane & 31);
    const int r = p / W;
    const int x = p % W;

    f32x16 acc[MT];
#pragma unroll
    for (int mt = 0; mt < MT; ++mt)
#pragma unroll
        for (int i = 0; i < 16; ++i) acc[mt][i] = 0.f;

    const unsigned short* wbase = wpk + lane * 8;

#pragma unroll
    for (int s = 0; s < 9; ++s) {
        const int dy = s / 3, dx = s % 3;
#pragma unroll
        for (int kst = 0; kst < KST; ++kst) {
            const int g = kst * 2 + q;
            bf16x8 bfrag = *(const bf16x8*)(&smem[g * PS + ((r + dy) * TWd + (x + dx)) * 8]);
#pragma unroll
            for (int mt = 0; mt < MT; ++mt) {
                bf16x8 a = *(const bf16x8*)(wbase + ((s * KST + kst) * MT + mt) * 512);
                acc[mt] = __builtin_amdgcn_mfma_f32_32x32x16_bf16(a, bfrag, acc[mt], 0, 0, 0);
            }
        }
    }

    size_t base = ((size_t)(b * H + y0 + r) * W + x) * COUT;
#pragma unroll
    for (int mt = 0; mt < MT; ++mt)
#pragma unroll
        for (int rg = 0; rg < 4; ++rg) {
            int oc = mt * 32 + 8 * rg + 4 * q;
            unsigned short s0 = f2bf(fmaxf(acc[mt][rg * 4 + 0] + bias[oc + 0], 0.f));
            unsigned short s1 = f2bf(fmaxf(acc[mt][rg * 4 + 1] + bias[oc + 1], 0.f));
            unsigned short s2 = f2bf(fmaxf(acc[mt][rg * 4 + 2] + bias[oc + 2], 0.f));
            unsigned short s3 = f2bf(fmaxf(acc[mt][rg * 4 + 3] + bias[oc + 3], 0.f));
            *(uint2*)(out + base + oc) = make_uint2(pack2(s0, s1), pack2(s2, s3));
        }
}

// ---------------------------------------------------------------------------
// Fused conv1 (5x5, relu -> x1t NHWC bf16) + conv_i (3x3 -> xin NCHW bf16).
// ---------------------------------------------------------------------------
__global__ __launch_bounds__(256)
void conv1i_mfma(const unsigned short* __restrict__ imgT,
                 const unsigned short* __restrict__ wpk1,
                 const unsigned short* __restrict__ wpki,
                 const float* __restrict__ b1, const float* __restrict__ bi,
                 unsigned short* __restrict__ x1t, unsigned short* __restrict__ xin)
{
    __shared__ __align__(16) unsigned short smem[2 * 5 * 132 * 8];

    const int tid  = threadIdx.x;
    const int lane = tid & 63;
    const int wv   = tid >> 6;
    const int n    = lane & 31;
    const int q    = lane >> 5;
    const int y    = blockIdx.x >> 1;
    const int x0   = (blockIdx.x & 1) * 128;
    const int b    = blockIdx.y;

    for (int i = tid; i < 5 * 132 * 2; i += 256) {
        int r   = i / 264;
        int rem = i - r * 264;
        int xi  = rem >> 1;
        int g   = rem & 1;
        int yg = y + r - 2;
        int xg = x0 - 2 + xi;
        uint4 v = make_uint4(0, 0, 0, 0);
        if (yg >= 0 && yg < 256 && xg >= 0 && xg < 256)
            v = *(const uint4*)(imgT + (((size_t)(b * 256 + yg) * 256 + xg) * 16 + g * 8));
        *(uint4*)(&smem[((g * 5 + r) * 132 + xi) * 8]) = v;
    }
    __syncthreads();

    f32x16 acc1, acci;
#pragma unroll
    for (int i = 0; i < 16; ++i) { acc1[i] = 0.f; acci[i] = 0.f; }

    const int pxl = wv * 32 + n;
    const unsigned short* wb1 = wpk1 + lane * 8;
    const unsigned short* wbi = wpki + lane * 8;

#pragma unroll
    for (int s = 0; s < 25; ++s) {
        const int dy = s / 5, dx = s % 5;
        bf16x8 bfrag = *(const bf16x8*)(&smem[((q * 5 + dy) * 132 + pxl + dx) * 8]);
        bf16x8 a = *(const bf16x8*)(wb1 + s * 512);
        acc1 = __builtin_amdgcn_mfma_f32_32x32x16_bf16(a, bfrag, acc1, 0, 0, 0);
    }
#pragma unroll
    for (int s = 0; s < 9; ++s) {
        const int dy = s / 3, dx = s % 3;
        bf16x8 bfrag = *(const bf16x8*)(&smem[((q * 5 + dy + 1) * 132 + pxl + dx + 1) * 8]);
        bf16x8 a = *(const bf16x8*)(wbi + s * 512);
        acci = __builtin_amdgcn_mfma_f32_32x32x16_bf16(a, bfrag, acci, 0, 0, 0);
    }

    const int px = x0 + pxl;
    size_t base1 = ((size_t)(b * 256 + y) * 256 + px) * 16;
#pragma unroll
    for (int rg = 0; rg < 2; ++rg) {
        int oc = 8 * rg + 4 * q;
        unsigned short s0 = f2bf(fmaxf(acc1[rg * 4 + 0] + b1[oc + 0], 0.f));
        unsigned short s1 = f2bf(fmaxf(acc1[rg * 4 + 1] + b1[oc + 1], 0.f));
        unsigned short s2 = f2bf(fmaxf(acc1[rg * 4 + 2] + b1[oc + 2], 0.f));
        unsigned short s3 = f2bf(fmaxf(acc1[rg * 4 + 3] + b1[oc + 3], 0.f));
        *(uint2*)(x1t + base1 + oc) = make_uint2(pack2(s0, s1), pack2(s2, s3));
    }
#pragma unroll
    for (int reg = 0; reg < 8; ++reg) {
        int row = (reg & 3) + 8 * (reg >> 2) + 4 * q;
        xin[((size_t)(b * 16 + row) * 256 + y) * 256 + px] = f2bf(acci[reg] + bi[row]);
    }
}

// ---------------------------------------------------------------------------
// conv8 MFMA: Cin=64, Cout=32, 128x128, relu -> x8t NHWC bf16.
// ---------------------------------------------------------------------------
__global__ __launch_bounds__(256)
void conv8_mfma(const unsigned short* __restrict__ cat8t,
                const unsigned short* __restrict__ wpk8,
                const float* __restrict__ bias,
                unsigned short* __restrict__ x8t)
{
    __shared__ __align__(16) unsigned short smem[8 * 3 * 130 * 8];

    const int tid  = threadIdx.x;
    const int lane = tid & 63;
    const int wv   = tid >> 6;
    const int n    = lane & 31;
    const int q    = lane >> 5;
    const int y    = blockIdx.x;
    const int b    = blockIdx.y;

    for (int i = tid; i < 3 * 130 * 8; i += 256) {
        int r   = i / 1040;
        int rem = i - r * 1040;
        int xi  = rem >> 3;
        int g   = rem & 7;
        int yg = y + r - 1;
        int xg = xi - 1;
        uint4 v = make_uint4(0, 0, 0, 0);
        if (yg >= 0 && yg < 128 && xg >= 0 && xg < 128)
            v = *(const uint4*)(cat8t + (((size_t)(b * 128 + yg) * 128 + xg) * 64 + g * 8));
        *(uint4*)(&smem[((g * 3 + r) * 130 + xi) * 8]) = v;
    }
    __syncthreads();

    f32x16 acc;
#pragma unroll
    for (int i = 0; i < 16; ++i) acc[i] = 0.f;

    const int pxl = wv * 32 + n;
    const unsigned short* wbase = wpk8 + lane * 8;

#pragma unroll
    for (int s = 0; s < 9; ++s) {
        const int dy = s / 3, dx = s % 3;
        const int xi = pxl + dx;
#pragma unroll
        for (int kst = 0; kst < 4; ++kst) {
            const int g = kst * 2 + q;
            bf16x8 bfrag = *(const bf16x8*)(&smem[((g * 3 + dy) * 130 + xi) * 8]);
            bf16x8 a = *(const bf16x8*)(wbase + (s * 4 + kst) * 512);
            acc = __builtin_amdgcn_mfma_f32_32x32x16_bf16(a, bfrag, acc, 0, 0, 0);
        }
    }

    size_t base = ((size_t)(b * 128 + y) * 128 + pxl) * 32;
#pragma unroll
    for (int rg = 0; rg < 4; ++rg) {
        int oc0 = 8 * rg + 4 * q;
        unsigned short s0 = f2bf(fmaxf(acc[rg * 4 + 0] + bias[oc0 + 0], 0.f));
        unsigned short s1 = f2bf(fmaxf(acc[rg * 4 + 1] + bias[oc0 + 1], 0.f));
        unsigned short s2 = f2bf(fmaxf(acc[rg * 4 + 2] + bias[oc0 + 2], 0.f));
        unsigned short s3 = f2bf(fmaxf(acc[rg * 4 + 3] + bias[oc0 + 3], 0.f));
        *(uint2*)(x8t + base + oc0) = make_uint2(pack2(s0, s1), pack2(s2, s3));
    }
}

// ---------------------------------------------------------------------------
// conv9 MFMA, fused upsample staging: stages its 3x130x48 window directly
// from x8t (bilinear 2x, NHWC bf16) + x1t (skip, NHWC bf16) — xt9 never
// materialized. K=48, 64 oc, tanh -> fm NCHW **bf16**.
// ---------------------------------------------------------------------------
__global__ __launch_bounds__(256)
void conv9f_mfma(const unsigned short* __restrict__ x8t,
                 const unsigned short* __restrict__ x1t,
                 const unsigned short* __restrict__ wpk,
                 const float* __restrict__ bias,
                 unsigned short* __restrict__ fm)
{
    __shared__ __align__(16) unsigned short smem[6 * 3 * 130 * 8];  // 37440 B

    const int tid  = threadIdx.x;
    const int lane = tid & 63;
    const int wv   = tid >> 6;
    const int n    = lane & 31;
    const int q    = lane >> 5;
    const int y    = blockIdx.x >> 1;
    const int x0   = (blockIdx.x & 1) * 128;
    const int b    = blockIdx.y;

    const unsigned short* x8b = x8t + (size_t)b * 128 * 128 * 32;

    for (int i = tid; i < 3 * 130 * 6; i += 256) {
        int r   = i / 780;
        int rem = i - r * 780;
        int xi  = rem / 6;
        int g   = rem - xi * 6;
        int yg = y + r - 1;
        int xg = x0 - 1 + xi;
        u16x8 v = {0, 0, 0, 0, 0, 0, 0, 0};
        if (yg >= 0 && yg < 256 && xg >= 0 && xg < 256) {
            if (g < 4) {
                int i00, i01, i10, i11; float wy, wx;
                bilin_setup(yg, xg, 128, 128, i00, i01, i10, i11, wy, wx);
                const unsigned short* sb = x8b + g * 8;
                u16x8 v00 = *(const u16x8*)(sb + (size_t)i00 * 32);
                u16x8 v01 = *(const u16x8*)(sb + (size_t)i01 * 32);
                u16x8 v10 = *(const u16x8*)(sb + (size_t)i10 * 32);
                u16x8 v11 = *(const u16x8*)(sb + (size_t)i11 * 32);
                float w00 = (1.f - wy) * (1.f - wx), w01 = (1.f - wy) * wx;
                float w10 = wy * (1.f - wx),         w11 = wy * wx;
#pragma unroll
                for (int j = 0; j < 8; ++j)
                    v[j] = f2bf(w00 * bf2f(v00[j]) + w01 * bf2f(v01[j]) +
                                w10 * bf2f(v10[j]) + w11 * bf2f(v11[j]));
            } else {
                v = *(const u16x8*)(x1t + (((size_t)(b * 256 + yg) * 256 + xg) * 16 + (g - 4) * 8));
            }
        }
        *(u16x8*)(&smem[((g * 3 + r) * 130 + xi) * 8]) = v;
    }
    __syncthreads();

    f32x16 acc0, acc1;
#pragma unroll
    for (int i = 0; i < 16; ++i) { acc0[i] = 0.f; acc1[i] = 0.f; }

    const int pxl = wv * 32 + n;
    const unsigned short* wbase = wpk + lane * 8;

#pragma unroll
    for (int s = 0; s < 9; ++s) {
        const int dy = s / 3, dx = s % 3;
        const int xi = pxl + dx;
#pragma unroll
        for (int kst = 0; kst < 3; ++kst) {
            const int g = kst * 2 + q;
            bf16x8 bfrag = *(const bf16x8*)(&smem[((g * 3 + dy) * 130 + xi) * 8]);
            bf16x8 a0 = *(const bf16x8*)(wbase + ((s * 3 + kst) * 2 + 0) * 512);
            bf16x8 a1 = *(const bf16x8*)(wbase + ((s * 3 + kst) * 2 + 1) * 512);
            acc0 = __builtin_amdgcn_mfma_f32_32x32x16_bf16(a0, bfrag, acc0, 0, 0, 0);
            acc1 = __builtin_amdgcn_mfma_f32_32x32x16_bf16(a1, bfrag, acc1, 0, 0, 0);
        }
    }

    const int px = x0 + pxl;
#pragma unroll
    for (int reg = 0; reg < 16; ++reg) {
        int row = (reg & 3) + 8 * (reg >> 2) + 4 * q;
        int oc0 = row, oc1 = 32 + row;
        fm[(((size_t)b * 64 + oc0) * 256 + y) * 256 + px] = f2bf(fast_tanh(acc0[reg] + bias[oc0]));
        fm[(((size_t)b * 64 + oc1) * 256 + y) * 256 + px] = f2bf(fast_tanh(acc1[reg] + bias[oc1]));
    }
}

// ---------------------------------------------------------------------------
// Segmented W-direction LRNN pair (fwd+rev) -> rnnW NHWC bf16.
// Inputs X (xin) and FM now NCHW bf16; recurrence stays fp32 in LDS/regs.
// ---------------------------------------------------------------------------
__global__ __launch_bounds__(256)
void lrnn_w_seg(const unsigned short* __restrict__ X, const unsigned short* __restrict__ FM,
                unsigned short* __restrict__ rnnW)
{
    __shared__ float tx[3][16][258];
    __shared__ unsigned short outm[2][16][256];
    __shared__ float segres[2][16][8][4];
    __shared__ float hin[2][16][8][2];

    const int tid = threadIdx.x;
    const int bid = blockIdx.x;
    const int yt = bid & 15;
    const int c  = (bid >> 4) & 15;
    const int b  = bid >> 8;
    const int y0 = yt * 16;

    const size_t xb  = ((size_t)(b * 16 + c) * 256 + y0) * 256;
    const size_t p1b = ((size_t)(b * 64 + c) * 256 + y0) * 256;
    const size_t p2b = ((size_t)(b * 64 + 32 + c) * 256 + y0) * 256;

    for (int i = tid; i < 1536; i += 256) {
        int s = i >> 9;          // 0..2
        int r = i & 511;
        int y = r >> 5;          // 0..15
        int g = r & 31;          // 0..31
        const unsigned short* sp = (s == 0) ? (X + xb) : (s == 1 ? FM + p1b : FM + p2b);
        u16x8 v = *(const u16x8*)(sp + (size_t)y * 256 + g * 8);
#pragma unroll
        for (int j = 0; j < 8; ++j) tx[s][y][g * 8 + j] = bf2f(v[j]);
    }
    __syncthreads();

    const int y  = tid & 15;
    const int sg = (tid >> 4) & 7;
    const int d  = tid >> 7;

    {   // pass 1
        float h1 = 0.f, h2 = 0.f, A1 = 1.f, A2 = 1.f;
        if (d == 0) {
            int xs = sg * 32;
#pragma unroll
            for (int i = 0; i < 32; ++i) {
                float xv = tx[0][y][xs + i], p1 = tx[1][y][xs + i], p2 = tx[2][y][xs + i];
                h1 = fmaf(p1, h1 - xv, xv); A1 *= p1;
                h2 = fmaf(p2, h2 - xv, xv); A2 *= p2;
            }
        } else {
            int xs = 255 - sg * 32;
#pragma unroll
            for (int i = 0; i < 32; ++i) {
                float xv = tx[0][y][xs - i], p1 = tx[1][y][xs - i], p2 = tx[2][y][xs - i];
                h1 = fmaf(p1, h1 - xv, xv); A1 *= p1;
                h2 = fmaf(p2, h2 - xv, xv); A2 *= p2;
            }
        }
        segres[d][y][sg][0] = h1; segres[d][y][sg][1] = A1;
        segres[d][y][sg][2] = h2; segres[d][y][sg][3] = A2;
    }
    __syncthreads();

    if (tid < 32) {
        int yy = tid & 15, dd = tid >> 4;
        float c1 = 0.f, c2 = 0.f;
        for (int s = 0; s < 8; ++s) {
            hin[dd][yy][s][0] = c1;
            hin[dd][yy][s][1] = c2;
            c1 = segres[dd][yy][s][0] + segres[dd][yy][s][1] * c1;
            c2 = segres[dd][yy][s][2] + segres[dd][yy][s][3] * c2;
        }
    }
    __syncthreads();

    {   // pass 2
        float h1 = hin[d][y][sg][0], h2 = hin[d][y][sg][1];
        if (d == 0) {
            int xs = sg * 32;
#pragma unroll
            for (int i = 0; i < 32; ++i) {
                float xv = tx[0][y][xs + i], p1 = tx[1][y][xs + i], p2 = tx[2][y][xs + i];
                h1 = fmaf(p1, h1 - xv, xv);
                h2 = fmaf(p2, h2 - xv, xv);
                outm[0][y][xs + i] = f2bf(fmaxf(h1, h2));
            }
        } else {
#pragma unroll
            for (int i = 0; i < 32; ++i) {
                int t = sg * 32 + i;
                float xv = tx[0][y][255 - t], p1 = tx[1][y][255 - t], p2 = tx[2][y][255 - t];
                h1 = fmaf(p1, h1 - xv, xv);
                h2 = fmaf(p2, h2 - xv, xv);
                outm[1][y][t] = f2bf(fmaxf(h1, h2));
            }
        }
    }
    __syncthreads();

    for (int i = tid; i < 4096; i += 256) {
        int x = i & 255, yy = i >> 8;
        float m = fmaxf(bf2f(outm[0][yy][x]), bf2f(outm[1][yy][x]));
        rnnW[((size_t)(b * 256 + y0 + yy) * 256 + x) * 16 + c] = f2bf(m);
    }
}

// ---------------------------------------------------------------------------
// Segmented H-direction LRNN pair (fwd+rev) -> rnnH NHWC bf16. bf16 inputs.
// ---------------------------------------------------------------------------
__global__ __launch_bounds__(256)
void lrnn_h_seg(const unsigned short* __restrict__ X, const unsigned short* __restrict__ FM,
                unsigned short* __restrict__ rnnH)
{
    __shared__ float tx[3][256][17];
    __shared__ unsigned short outm[2][256][16];
    __shared__ float segres[2][16][8][4];
    __shared__ float hin[2][16][8][2];

    const int tid = threadIdx.x;
    const int bid = blockIdx.x;
    const int xt = bid & 15;
    const int c  = (bid >> 4) & 15;
    const int b  = bid >> 8;
    const int x0 = xt * 16;

    const size_t xb  = (size_t)(b * 16 + c) * 65536 + x0;
    const size_t p1b = (size_t)(b * 64 + 16 + c) * 65536 + x0;
    const size_t p2b = (size_t)(b * 64 + 48 + c) * 65536 + x0;

    for (int i = tid; i < 1536; i += 256) {
        int s = i >> 9;
        int r = i & 511;
        int y = r >> 1;
        int g = r & 1;
        const unsigned short* sp = (s == 0) ? (X + xb) : (s == 1 ? FM + p1b : FM + p2b);
        u16x8 v = *(const u16x8*)(sp + (size_t)y * 256 + g * 8);
#pragma unroll
        for (int j = 0; j < 8; ++j) tx[s][y][g * 8 + j] = bf2f(v[j]);
    }
    __syncthreads();

    const int x  = tid & 15;
    const int sg = (tid >> 4) & 7;
    const int d  = tid >> 7;

    {   // pass 1
        float h1 = 0.f, h2 = 0.f, A1 = 1.f, A2 = 1.f;
        if (d == 0) {
            int ys = sg * 32;
#pragma unroll
            for (int i = 0; i < 32; ++i) {
                float xv = tx[0][ys + i][x], p1 = tx[1][ys + i][x], p2 = tx[2][ys + i][x];
                h1 = fmaf(p1, h1 - xv, xv); A1 *= p1;
                h2 = fmaf(p2, h2 - xv, xv); A2 *= p2;
            }
        } else {
            int ys = 255 - sg * 32;
#pragma unroll
            for (int i = 0; i < 32; ++i) {
                float xv = tx[0][ys - i][x], p1 = tx[1][ys - i][x], p2 = tx[2][ys - i][x];
                h1 = fmaf(p1, h1 - xv, xv); A1 *= p1;
                h2 = fmaf(p2, h2 - xv, xv); A2 *= p2;
            }
        }
        segres[d][x][sg][0] = h1; segres[d][x][sg][1] = A1;
        segres[d][x][sg][2] = h2; segres[d][x][sg][3] = A2;
    }
    __syncthreads();

    if (tid < 32) {
        int xx = tid & 15, dd = tid >> 4;
        float c1 = 0.f, c2 = 0.f;
        for (int s = 0; s < 8; ++s) {
            hin[dd][xx][s][0] = c1;
            hin[dd][xx][s][1] = c2;
            c1 = segres[dd][xx][s][0] + segres[dd][xx][s][1] * c1;
            c2 = segres[dd][xx][s][2] + segres[dd][xx][s][3] * c2;
        }
    }
    __syncthreads();

    {   // pass 2
        float h1 = hin[d][x][sg][0], h2 = hin[d][x][sg][1];
        if (d == 0) {
            int ys = sg * 32;
#pragma unroll
            for (int i = 0; i < 32; ++i) {
                float xv = tx[0][ys + i][x], p1 = tx[1][ys + i][x], p2 = tx[2][ys + i][x];
                h1 = fmaf(p1, h1 - xv, xv);
                h2 = fmaf(p2, h2 - xv, xv);
                outm[0][ys + i][x] = f2bf(fmaxf(h1, h2));
            }
        } else {
#pragma unroll
            for (int i = 0; i < 32; ++i) {
                int t = sg * 32 + i;
                float xv = tx[0][255 - t][x], p1 = tx[1][255 - t][x], p2 = tx[2][255 - t][x];
                h1 = fmaf(p1, h1 - xv, xv);
                h2 = fmaf(p2, h2 - xv, xv);
                outm[1][t][x] = f2bf(fmaxf(h1, h2));
            }
        }
    }
    __syncthreads();

    for (int i = tid; i < 4096; i += 256) {
        int xx = i & 15, yy = i >> 4;
        float m = fmaxf(bf2f(outm[0][yy][xx]), bf2f(outm[1][yy][xx]));
        rnnH[((size_t)(b * 256 + yy) * 256 + x0 + xx) * 16 + c] = f2bf(m);
    }
}

// ---------------------------------------------------------------------------
// Output head MFMA: max(rnnW, rnnH) staged -> 3x3 conv (Cin16, Cout3),
// sigmoid -> d_out NCHW fp32.
// ---------------------------------------------------------------------------
__global__ __launch_bounds__(256)
void convo_mfma(const unsigned short* __restrict__ rnnW,
                const unsigned short* __restrict__ rnnH,
                const unsigned short* __restrict__ wpko,
                const float* __restrict__ bo,
                float* __restrict__ outp)
{
    __shared__ __align__(16) unsigned short smem[2 * 3 * 130 * 8];

    const int tid  = threadIdx.x;
    const int lane = tid & 63;
    const int wv   = tid >> 6;
    const int n    = lane & 31;
    const int q    = lane >> 5;
    const int y    = blockIdx.x >> 1;
    const int x0   = (blockIdx.x & 1) * 128;
    const int b    = blockIdx.y;

    for (int i = tid; i < 3 * 130 * 2; i += 256) {
        int r   = i / 260;
        int rem = i - r * 260;
        int xi  = rem >> 1;
        int g   = rem & 1;
        int yg = y + r - 1;
        int xg = x0 - 1 + xi;
        u16x8 m = {0, 0, 0, 0, 0, 0, 0, 0};
        if (yg >= 0 && yg < 256 && xg >= 0 && xg < 256) {
            size_t off = (((size_t)(b * 256 + yg) * 256 + xg) * 16 + g * 8);
            u16x8 a = *(const u16x8*)(rnnW + off);
            u16x8 bb = *(const u16x8*)(rnnH + off);
#pragma unroll
            for (int j = 0; j < 8; ++j)
                m[j] = f2bf(fmaxf(bf2f(a[j]), bf2f(bb[j])));
        }
        *(u16x8*)(&smem[((g * 3 + r) * 130 + xi) * 8]) = m;
    }
    __syncthreads();

    f32x16 acc;
#pragma unroll
    for (int i = 0; i < 16; ++i) acc[i] = 0.f;

    const int pxl = wv * 32 + n;
    const unsigned short* wbase = wpko + lane * 8;

#pragma unroll
    for (int s = 0; s < 9; ++s) {
        const int dy = s / 3, dx = s % 3;
        bf16x8 bfrag = *(const bf16x8*)(&smem[((q * 3 + dy) * 130 + pxl + dx) * 8]);
        bf16x8 a = *(const bf16x8*)(wbase + s * 512);
        acc = __builtin_amdgcn_mfma_f32_32x32x16_bf16(a, bfrag, acc, 0, 0, 0);
    }

    const int px = x0 + pxl;
    if (q == 0) {
#pragma unroll
        for (int oc = 0; oc < 3; ++oc) {
            float r = acc[oc] + bo[oc];
            outp[((size_t)(b * 3 + oc) * 256 + y) * 256 + px] = 1.f / (1.f + __expf(-r));
        }
    }
}

// ---------------------------------------------------------------------------
extern "C" void kernel_launch(void* const* d_in, const int* in_sizes, int n_in,
                              void* d_out, int out_size, void* d_ws, size_t ws_size,
                              hipStream_t stream)
{
    const float* img = (const float*)d_in[0];
    const float* w1 = (const float*)d_in[1];  const float* b1 = (const float*)d_in[2];
    const float* w2 = (const float*)d_in[3];  const float* b2 = (const float*)d_in[4];
    const float* w3 = (const float*)d_in[5];  const float* b3 = (const float*)d_in[6];
    const float* w4 = (const float*)d_in[7];  const float* b4 = (const float*)d_in[8];
    const float* w5 = (const float*)d_in[9];  const float* b5 = (const float*)d_in[10];
    const float* w6 = (const float*)d_in[11]; const float* b6 = (const float*)d_in[12];
    const float* w7 = (const float*)d_in[13]; const float* b7 = (const float*)d_in[14];
    const float* w8 = (const float*)d_in[15]; const float* b8 = (const float*)d_in[16];
    const float* w9 = (const float*)d_in[17]; const float* b9 = (const float*)d_in[18];
    const float* wi = (const float*)d_in[19]; const float* bi = (const float*)d_in[20];
    const float* wo = (const float*)d_in[21]; const float* bo = (const float*)d_in[22];

    char* wsb = (char*)d_ws;
    const size_t MB = (size_t)(1u << 20);
    // Layout (live-range-checked):
    unsigned short* imgT  = (unsigned short*)(wsb);            // [0,16)  dead after conv1i
    unsigned short* x1t   = (unsigned short*)(wsb + 16 * MB);  // [16,32) live until conv9f
    unsigned short* p1t   = (unsigned short*)(wsb + 32 * MB);
    unsigned short* x2t   = (unsigned short*)(wsb + 36 * MB);
    unsigned short* p2t   = (unsigned short*)(wsb + 44 * MB);
    unsigned short* x3t   = (unsigned short*)(wsb + 46 * MB);
    unsigned short* p3t   = (unsigned short*)(wsb + 48 * MB);
    unsigned short* x4t   = (unsigned short*)(wsb + 49 * MB);
    unsigned short* p4t   = (unsigned short*)(wsb + 50 * MB);
    unsigned short* x5t   = (unsigned short*)(wsb + 51 * MB);
    unsigned short* cat6t = (unsigned short*)(wsb + 52 * MB);
    unsigned short* x6t   = (unsigned short*)(wsb + 54 * MB);
    unsigned short* cat7t = (unsigned short*)(wsb + 55 * MB);
    unsigned short* x7t   = (unsigned short*)(wsb + 59 * MB);
    unsigned short* cat8t = (unsigned short*)(wsb + 62 * MB);  // [62,78)
    unsigned short* x8t   = (unsigned short*)(wsb + 78 * MB);  // [78,86) live until conv9f
    unsigned short* fm16  = (unsigned short*)(wsb + 96 * MB);  // [96,160) NCHW bf16 64MB
    unsigned short* xin16 = (unsigned short*)(wsb + 176 * MB); // [176,192) NCHW bf16 16MB
    unsigned short* rnnW  = (unsigned short*)(wsb);            // [0,16)  (imgT dead)
    unsigned short* rnnH  = (unsigned short*)(wsb + 16 * MB);  // [16,32) (x1t dead after conv9f)
    unsigned short* wpk9 = (unsigned short*)(wsb + 208 * MB);
    unsigned short* wpk8 = wpk9 + 27648;
    unsigned short* wpk1 = wpk8 + 18432;
    unsigned short* wpki = wpk1 + 12800;
    unsigned short* wpko = wpki + 4608;
    unsigned short* wpk2 = wpko + 4608;
    unsigned short* wpk3 = wpk2 + 4608;
    unsigned short* wpk4 = wpk3 + 9216;
    unsigned short* wpk5 = wpk4 + 9216;
    unsigned short* wpk6 = wpk5 + 18432;
    unsigned short* wpk7 = wpk6 + 27648;
    float* outp = (float*)d_out;

    // --- weight packs + img transpose ---
    wprep_all<<<266, 256, 0, stream>>>(w9, w8, w1, wi, wo, wpk9, wpk8, wpk1, wpki, wpko);
    wpack<<<18, 256, 0, stream>>>(w2, wpk2, 16, 32);
    wpack<<<36, 256, 0, stream>>>(w3, wpk3, 32, 32);
    wpack<<<36, 256, 0, stream>>>(w4, wpk4, 32, 32);
    wpack<<<72, 256, 0, stream>>>(w5, wpk5, 32, 64);
    wpack<<<108, 256, 0, stream>>>(w6, wpk6, 96, 32);
    wpack<<<72, 256, 0, stream>>>(w7, wpk7, 64, 32);
    imgT_bf16<<<2048, 256, 0, stream>>>(img, imgT);

    // --- fused conv1 (relu -> x1t NHWC) + input projection (xin16 NCHW bf16) ---
    { dim3 grd(512, 8);
      conv1i_mfma<<<grd, 256, 0, stream>>>(imgT, wpk1, wpki, b1, bi, x1t, xin16); }

    // --- encoder (NHWC bf16 MFMA) ---
    pool_nhwc<<<1024, 256, 0, stream>>>(x1t, p1t, 128, 128, 2);
    convN_mfma<16, 32, 128, 128, 1><<<dim3(128, 8), 256, 0, stream>>>(p1t, wpk2, b2, x2t);
    pool_nhwc<<<512, 256, 0, stream>>>(x2t, p2t, 64, 64, 4);
    convN_mfma<32, 32, 64, 64, 2><<<dim3(32, 8), 256, 0, stream>>>(p2t, wpk3, b3, x3t);
    pool_nhwc<<<128, 256, 0, stream>>>(x3t, p3t, 32, 32, 4);
    convN_mfma<32, 32, 32, 32, 4><<<dim3(8, 8), 256, 0, stream>>>(p3t, wpk4, b4, x4t);
    pool_nhwc<<<32, 256, 0, stream>>>(x4t, p4t, 16, 16, 4);
    convN_mfma<32, 64, 16, 16, 8><<<dim3(2, 8), 256, 0, stream>>>(p4t, wpk5, b5, x5t);

    // --- decoder (NHWC bf16) ---
    upcat_nhwc2<<<384, 256, 0, stream>>>(x5t, x4t, cat6t, 64, 32, 32, 32);
    convN_mfma<96, 32, 32, 32, 4><<<dim3(8, 8), 256, 0, stream>>>(cat6t, wpk6, b6, x6t);
    upcat_nhwc2<<<1024, 256, 0, stream>>>(x6t, x3t, cat7t, 32, 32, 64, 64);
    convN_mfma<64, 32, 64, 64, 2><<<dim3(32, 8), 256, 0, stream>>>(cat7t, wpk7, b7, x7t);
    upcat_nhwc2<<<4096, 256, 0, stream>>>(x7t, x2t, cat8t, 32, 32, 128, 128);
    { dim3 grd(128, 8);
      conv8_mfma<<<grd, 256, 0, stream>>>(cat8t, wpk8, b8, x8t); }

    // --- stage 9: fused upsample + conv9, fm NCHW bf16 ---
    { dim3 grd(512, 8);
      conv9f_mfma<<<grd, 256, 0, stream>>>(x8t, x1t, wpk9, b9, fm16); }

    // --- spatial RNN: segmented two-pass scans (bf16 in, fp32 recurrence) ---
    lrnn_w_seg<<<2048, 256, 0, stream>>>(xin16, fm16, rnnW);
    lrnn_h_seg<<<2048, 256, 0, stream>>>(xin16, fm16, rnnH);

    // --- output head: max(rnnW,rnnH) -> conv -> sigmoid ---
    { dim3 grd(512, 8);
      convo_mfma<<<grd, 256, 0, stream>>>(rnnW, rnnH, wpko, bo, outp); }
}

// Round 10
// 418.071 us; speedup vs baseline: 5.5551x; 1.0664x over previous
//
#include <hip/hip_runtime.h>
#include <math.h>

typedef __attribute__((ext_vector_type(8)))  short bf16x8;
typedef __attribute__((ext_vector_type(8)))  unsigned short u16x8;
typedef __attribute__((ext_vector_type(16))) float f32x16;

__device__ __forceinline__ unsigned short f2bf(float f) {
    unsigned u = __float_as_uint(f);
    unsigned r = (u + 0x7FFFu + ((u >> 16) & 1u)) >> 16;
    return (unsigned short)r;
}
__device__ __forceinline__ float bf2f(unsigned short h) {
    return __uint_as_float(((unsigned)h) << 16);
}
__device__ __forceinline__ unsigned pack2(unsigned short a, unsigned short b) {
    return (unsigned)a | ((unsigned)b << 16);
}
__device__ __forceinline__ float fast_tanh(float x) {
    float e = __expf(2.f * x);
    return 1.f - 2.f / (e + 1.f);
}

__device__ __forceinline__ void bilin_setup(int y, int x, int Hi, int Wi,
                                            int& i00, int& i01, int& i10, int& i11,
                                            float& wy, float& wx)
{
    float fy = 0.5f * y - 0.25f;
    float fx = 0.5f * x - 0.25f;
    float y0f = floorf(fy), x0f = floorf(fx);
    wy = fy - y0f; wx = fx - x0f;
    int yA = (int)y0f, xA = (int)x0f;
    int yB = yA + 1, xB = xA + 1;
    yA = yA < 0 ? 0 : (yA > Hi - 1 ? Hi - 1 : yA);
    yB = yB < 0 ? 0 : (yB > Hi - 1 ? Hi - 1 : yB);
    xA = xA < 0 ? 0 : (xA > Wi - 1 ? Wi - 1 : xA);
    xB = xB < 0 ? 0 : (xB > Wi - 1 ? Wi - 1 : xB);
    i00 = yA * Wi + xA; i01 = yA * Wi + xB;
    i10 = yB * Wi + xA; i11 = yB * Wi + xB;
}

// ---------------------------------------------------------------------------
// NHWC bf16 upsample(2x) + concat (stages 6,7,8).
// ---------------------------------------------------------------------------
__global__ void upcat_nhwc2(const unsigned short* __restrict__ up,
                            const unsigned short* __restrict__ skip,
                            unsigned short* __restrict__ dst,
                            int C1, int C2, int H, int W)
{
    int C8 = (C1 + C2) >> 3;
    int idx = blockIdx.x * 256 + threadIdx.x;
    int total = 8 * H * W * C8;
    if (idx >= total) return;
    int g = idx % C8;
    int p = idx / C8;
    int x = p % W;
    int y = (p / W) % H;
    int b = p / (W * H);
    u16x8 r;
    if (g < (C1 >> 3)) {
        int Hi = H >> 1, Wi = W >> 1;
        int i00, i01, i10, i11; float wy, wx;
        bilin_setup(y, x, Hi, Wi, i00, i01, i10, i11, wy, wx);
        const unsigned short* sb = up + (size_t)b * Hi * Wi * C1 + g * 8;
        u16x8 v00 = *(const u16x8*)(sb + (size_t)i00 * C1);
        u16x8 v01 = *(const u16x8*)(sb + (size_t)i01 * C1);
        u16x8 v10 = *(const u16x8*)(sb + (size_t)i10 * C1);
        u16x8 v11 = *(const u16x8*)(sb + (size_t)i11 * C1);
        float w00 = (1.f - wy) * (1.f - wx), w01 = (1.f - wy) * wx;
        float w10 = wy * (1.f - wx),         w11 = wy * wx;
#pragma unroll
        for (int j = 0; j < 8; ++j)
            r[j] = f2bf(w00 * bf2f(v00[j]) + w01 * bf2f(v01[j]) +
                        w10 * bf2f(v10[j]) + w11 * bf2f(v11[j]));
    } else {
        r = *(const u16x8*)(skip + ((size_t)(b * H + y) * W + x) * C2 + (g - (C1 >> 3)) * 8);
    }
    *(u16x8*)(dst + (((size_t)(b * H + y) * W + x) * (C1 + C2) + g * 8)) = r;
}

// ---------------------------------------------------------------------------
// upx8: bilinear 2x upsample of x8t -> x8u NHWC bf16 [8,256,256,32].
// Computed ONCE per pixel (conv9 staging then only copies).
// ---------------------------------------------------------------------------
__global__ void upx8_kernel(const unsigned short* __restrict__ x8t,
                            unsigned short* __restrict__ x8u)
{
    int idx = blockIdx.x * 256 + threadIdx.x;
    if (idx >= 8 * 256 * 256 * 4) return;
    int g = idx & 3;
    int p = idx >> 2;
    int x = p & 255, y = (p >> 8) & 255, b = p >> 16;
    int i00, i01, i10, i11; float wy, wx;
    bilin_setup(y, x, 128, 128, i00, i01, i10, i11, wy, wx);
    const unsigned short* sb = x8t + (size_t)b * 128 * 128 * 32 + g * 8;
    u16x8 v00 = *(const u16x8*)(sb + (size_t)i00 * 32);
    u16x8 v01 = *(const u16x8*)(sb + (size_t)i01 * 32);
    u16x8 v10 = *(const u16x8*)(sb + (size_t)i10 * 32);
    u16x8 v11 = *(const u16x8*)(sb + (size_t)i11 * 32);
    float w00 = (1.f - wy) * (1.f - wx), w01 = (1.f - wy) * wx;
    float w10 = wy * (1.f - wx),         w11 = wy * wx;
    u16x8 r;
#pragma unroll
    for (int j = 0; j < 8; ++j)
        r[j] = f2bf(w00 * bf2f(v00[j]) + w01 * bf2f(v01[j]) +
                    w10 * bf2f(v10[j]) + w11 * bf2f(v11[j]));
    *(u16x8*)(x8u + (size_t)idx * 8) = r;
}

// ---------------------------------------------------------------------------
// img [8][15][256][256] fp32 -> imgT [b][y][x][16] bf16 (ch15 = 0)
// ---------------------------------------------------------------------------
__global__ void imgT_bf16(const float* __restrict__ img, unsigned short* __restrict__ dst)
{
    int idx = blockIdx.x * 256 + threadIdx.x;
    if (idx >= 8 * 256 * 256) return;
    int x = idx & 255, y = (idx >> 8) & 255, b = idx >> 16;
    unsigned short v[16];
#pragma unroll
    for (int c = 0; c < 15; ++c)
        v[c] = f2bf(img[(size_t)(b * 15 + c) * 65536 + y * 256 + x]);
    v[15] = 0;
    uint4 lo = make_uint4(pack2(v[0], v[1]), pack2(v[2], v[3]), pack2(v[4], v[5]), pack2(v[6], v[7]));
    uint4 hi = make_uint4(pack2(v[8], v[9]), pack2(v[10], v[11]), pack2(v[12], v[13]), pack2(v[14], v[15]));
    *(uint4*)(dst + (size_t)idx * 16)     = lo;
    *(uint4*)(dst + (size_t)idx * 16 + 8) = hi;
}

// ---------------------------------------------------------------------------
// One mega weight-pack kernel: all 11 packs in a single dispatch.
// Generic 3x3 layout: idx = (((s*KST+kst)*MT+mt)*64+lane)*8+j,
//   oc = mt*32+(lane&31), ci = kst*16+(lane>>5)*8+j.
// ---------------------------------------------------------------------------
__device__ __forceinline__ void pack33(const float* __restrict__ w,
                                       unsigned short* __restrict__ dst,
                                       int i, int Cin, int Cout)
{
    int KST = Cin >> 4, MT = Cout >> 5;
    int j = i & 7;
    int lane = (i >> 3) & 63;
    int t = i >> 9;
    int mt = t % MT; t /= MT;
    int kst = t % KST;
    int s = t / KST;
    int oc = mt * 32 + (lane & 31);
    int ci = kst * 16 + (lane >> 5) * 8 + j;
    dst[i] = f2bf(w[(oc * Cin + ci) * 9 + s]);
}

__global__ void wprep_mega(const float* __restrict__ w9, const float* __restrict__ w8,
                           const float* __restrict__ w1, const float* __restrict__ wi,
                           const float* __restrict__ wo, const float* __restrict__ w2,
                           const float* __restrict__ w3, const float* __restrict__ w4,
                           const float* __restrict__ w5, const float* __restrict__ w6,
                           const float* __restrict__ w7,
                           unsigned short* __restrict__ wpk9, unsigned short* __restrict__ wpk8,
                           unsigned short* __restrict__ wpk1, unsigned short* __restrict__ wpki,
                           unsigned short* __restrict__ wpko, unsigned short* __restrict__ wpk2,
                           unsigned short* __restrict__ wpk3, unsigned short* __restrict__ wpk4,
                           unsigned short* __restrict__ wpk5, unsigned short* __restrict__ wpk6,
                           unsigned short* __restrict__ wpk7)
{
    int idx = blockIdx.x * 256 + threadIdx.x;
    if (idx < 27648)       pack33(w9, wpk9, idx, 48, 64);
    else if (idx < 46080)  pack33(w8, wpk8, idx - 27648, 64, 32);
    else if (idx < 58880) {
        int i = idx - 46080;
        int j = i & 7;
        int lane = (i >> 3) & 63;
        int s = i >> 9;                 // 0..24
        int oc = lane & 31;
        int ci = (lane >> 5) * 8 + j;   // 0..15
        float v = 0.f;
        if (oc < 16 && ci < 15) v = w1[((oc * 15 + ci) * 5 + s / 5) * 5 + s % 5];
        wpk1[i] = f2bf(v);
    } else if (idx < 63488) {
        int i = idx - 58880;
        int j = i & 7;
        int lane = (i >> 3) & 63;
        int s = i >> 9;                 // 0..8
        int oc = lane & 31;
        int ci = (lane >> 5) * 8 + j;
        float v = 0.f;
        if (oc < 16 && ci < 15) v = wi[((oc * 15 + ci) * 3 + s / 3) * 3 + s % 3];
        wpki[i] = f2bf(v);
    } else if (idx < 68096) {
        int i = idx - 63488;
        int j = i & 7;
        int lane = (i >> 3) & 63;
        int s = i >> 9;
        int oc = lane & 31;
        int ci = (lane >> 5) * 8 + j;
        float v = 0.f;
        if (oc < 3) v = wo[((oc * 16 + ci) * 3 + s / 3) * 3 + s % 3];
        wpko[i] = f2bf(v);
    }
    else if (idx < 72704)  pack33(w2, wpk2, idx - 68096, 16, 32);
    else if (idx < 81920)  pack33(w3, wpk3, idx - 72704, 32, 32);
    else if (idx < 91136)  pack33(w4, wpk4, idx - 81920, 32, 32);
    else if (idx < 109568) pack33(w5, wpk5, idx - 91136, 32, 64);
    else if (idx < 137216) pack33(w6, wpk6, idx - 109568, 96, 32);
    else if (idx < 155648) pack33(w7, wpk7, idx - 137216, 64, 32);
}

// ---------------------------------------------------------------------------
// Generic NHWC bf16 MFMA conv (3x3, pad 1, relu -> NHWC bf16).
// POOL=1: input is [8, 2H, 2W, CIN]; staging applies 2x2 maxpool on the fly
// (fuses the pool kernel, removing a dispatch + tensor round-trip).
// ---------------------------------------------------------------------------
template<int CIN, int COUT, int H, int W, int ROWS, int POOL>
__global__ __launch_bounds__(256)
void convN_mfma(const unsigned short* __restrict__ in,
                const unsigned short* __restrict__ wpk,
                const float* __restrict__ bias,
                unsigned short* __restrict__ out)
{
    constexpr int G = CIN / 8;
    constexpr int KST = CIN / 16;
    constexpr int MT = COUT / 32;
    constexpr int TR = ROWS + 2;
    constexpr int TWd = W + 2;
    constexpr int PS = TR * TWd * 8 + 8;
    __shared__ __align__(16) unsigned short smem[G * PS];

    const int tid  = threadIdx.x;
    const int lane = tid & 63;
    const int wv   = tid >> 6;
    const int q    = lane >> 5;
    const int y0   = blockIdx.x * ROWS;
    const int b    = blockIdx.y;

    for (int i = tid; i < G * TR * TWd; i += 256) {
        int g = i % G;
        int u = (i / G) % TWd;
        int t = i / (G * TWd);
        int yg = y0 + t - 1, xg = u - 1;
        u16x8 v = {0, 0, 0, 0, 0, 0, 0, 0};
        if (yg >= 0 && yg < H && xg >= 0 && xg < W) {
            if (POOL) {
                const unsigned short* q0 =
                    in + (((size_t)(b * 2 * H + 2 * yg) * 2 * W + 2 * xg) * CIN + g * 8);
                u16x8 a0 = *(const u16x8*)q0;
                u16x8 a1 = *(const u16x8*)(q0 + CIN);
                u16x8 a2 = *(const u16x8*)(q0 + (size_t)2 * W * CIN);
                u16x8 a3 = *(const u16x8*)(q0 + (size_t)2 * W * CIN + CIN);
#pragma unroll
                for (int j = 0; j < 8; ++j)
                    v[j] = f2bf(fmaxf(fmaxf(bf2f(a0[j]), bf2f(a1[j])),
                                      fmaxf(bf2f(a2[j]), bf2f(a3[j]))));
            } else {
                v = *(const u16x8*)(in + (((size_t)(b * H + yg) * W + xg) * CIN + g * 8));
            }
        }
        *(u16x8*)(&smem[g * PS + (t * TWd + u) * 8]) = v;
    }
    __syncthreads();

    const int p = wv * 32 + (lane & 31);
    const int r = p / W;
    const int x = p % W;

    f32x16 acc[MT];
#pragma unroll
    for (int mt = 0; mt < MT; ++mt)
#pragma unroll
        for (int i = 0; i < 16; ++i) acc[mt][i] = 0.f;

    const unsigned short* wbase = wpk + lane * 8;

#pragma unroll
    for (int s = 0; s < 9; ++s) {
        const int dy = s / 3, dx = s % 3;
#pragma unroll
        for (int kst = 0; kst < KST; ++kst) {
            const int g = kst * 2 + q;
            bf16x8 bfrag = *(const bf16x8*)(&smem[g * PS + ((r + dy) * TWd + (x + dx)) * 8]);
#pragma unroll
            for (int mt = 0; mt < MT; ++mt) {
                bf16x8 a = *(const bf16x8*)(wbase + ((s * KST + kst) * MT + mt) * 512);
                acc[mt] = __builtin_amdgcn_mfma_f32_32x32x16_bf16(a, bfrag, acc[mt], 0, 0, 0);
            }
        }
    }

    size_t base = ((size_t)(b * H + y0 + r) * W + x) * COUT;
#pragma unroll
    for (int mt = 0; mt < MT; ++mt)
#pragma unroll
        for (int rg = 0; rg < 4; ++rg) {
            int oc = mt * 32 + 8 * rg + 4 * q;
            unsigned short s0 = f2bf(fmaxf(acc[mt][rg * 4 + 0] + bias[oc + 0], 0.f));
            unsigned short s1 = f2bf(fmaxf(acc[mt][rg * 4 + 1] + bias[oc + 1], 0.f));
            unsigned short s2 = f2bf(fmaxf(acc[mt][rg * 4 + 2] + bias[oc + 2], 0.f));
            unsigned short s3 = f2bf(fmaxf(acc[mt][rg * 4 + 3] + bias[oc + 3], 0.f));
            *(uint2*)(out + base + oc) = make_uint2(pack2(s0, s1), pack2(s2, s3));
        }
}

// ---------------------------------------------------------------------------
// Fused conv1 (5x5, relu -> x1t NHWC bf16) + conv_i (3x3 -> xin NCHW bf16).
// ---------------------------------------------------------------------------
__global__ __launch_bounds__(256)
void conv1i_mfma(const unsigned short* __restrict__ imgT,
                 const unsigned short* __restrict__ wpk1,
                 const unsigned short* __restrict__ wpki,
                 const float* __restrict__ b1, const float* __restrict__ bi,
                 unsigned short* __restrict__ x1t, unsigned short* __restrict__ xin)
{
    __shared__ __align__(16) unsigned short smem[2 * 5 * 132 * 8];

    const int tid  = threadIdx.x;
    const int lane = tid & 63;
    const int wv   = tid >> 6;
    const int n    = lane & 31;
    const int q    = lane >> 5;
    const int y    = blockIdx.x >> 1;
    const int x0   = (blockIdx.x & 1) * 128;
    const int b    = blockIdx.y;

    for (int i = tid; i < 5 * 132 * 2; i += 256) {
        int r   = i / 264;
        int rem = i - r * 264;
        int xi  = rem >> 1;
        int g   = rem & 1;
        int yg = y + r - 2;
        int xg = x0 - 2 + xi;
        uint4 v = make_uint4(0, 0, 0, 0);
        if (yg >= 0 && yg < 256 && xg >= 0 && xg < 256)
            v = *(const uint4*)(imgT + (((size_t)(b * 256 + yg) * 256 + xg) * 16 + g * 8));
        *(uint4*)(&smem[((g * 5 + r) * 132 + xi) * 8]) = v;
    }
    __syncthreads();

    f32x16 acc1, acci;
#pragma unroll
    for (int i = 0; i < 16; ++i) { acc1[i] = 0.f; acci[i] = 0.f; }

    const int pxl = wv * 32 + n;
    const unsigned short* wb1 = wpk1 + lane * 8;
    const unsigned short* wbi = wpki + lane * 8;

#pragma unroll
    for (int s = 0; s < 25; ++s) {
        const int dy = s / 5, dx = s % 5;
        bf16x8 bfrag = *(const bf16x8*)(&smem[((q * 5 + dy) * 132 + pxl + dx) * 8]);
        bf16x8 a = *(const bf16x8*)(wb1 + s * 512);
        acc1 = __builtin_amdgcn_mfma_f32_32x32x16_bf16(a, bfrag, acc1, 0, 0, 0);
    }
#pragma unroll
    for (int s = 0; s < 9; ++s) {
        const int dy = s / 3, dx = s % 3;
        bf16x8 bfrag = *(const bf16x8*)(&smem[((q * 5 + dy + 1) * 132 + pxl + dx + 1) * 8]);
        bf16x8 a = *(const bf16x8*)(wbi + s * 512);
        acci = __builtin_amdgcn_mfma_f32_32x32x16_bf16(a, bfrag, acci, 0, 0, 0);
    }

    const int px = x0 + pxl;
    size_t base1 = ((size_t)(b * 256 + y) * 256 + px) * 16;
#pragma unroll
    for (int rg = 0; rg < 2; ++rg) {
        int oc = 8 * rg + 4 * q;
        unsigned short s0 = f2bf(fmaxf(acc1[rg * 4 + 0] + b1[oc + 0], 0.f));
        unsigned short s1 = f2bf(fmaxf(acc1[rg * 4 + 1] + b1[oc + 1], 0.f));
        unsigned short s2 = f2bf(fmaxf(acc1[rg * 4 + 2] + b1[oc + 2], 0.f));
        unsigned short s3 = f2bf(fmaxf(acc1[rg * 4 + 3] + b1[oc + 3], 0.f));
        *(uint2*)(x1t + base1 + oc) = make_uint2(pack2(s0, s1), pack2(s2, s3));
    }
#pragma unroll
    for (int reg = 0; reg < 8; ++reg) {
        int row = (reg & 3) + 8 * (reg >> 2) + 4 * q;
        xin[((size_t)(b * 16 + row) * 256 + y) * 256 + px] = f2bf(acci[reg] + bi[row]);
    }
}

// ---------------------------------------------------------------------------
// conv8 MFMA: Cin=64, Cout=32, 128x128, relu -> x8t NHWC bf16.
// ---------------------------------------------------------------------------
__global__ __launch_bounds__(256)
void conv8_mfma(const unsigned short* __restrict__ cat8t,
                const unsigned short* __restrict__ wpk8,
                const float* __restrict__ bias,
                unsigned short* __restrict__ x8t)
{
    __shared__ __align__(16) unsigned short smem[8 * 3 * 130 * 8];

    const int tid  = threadIdx.x;
    const int lane = tid & 63;
    const int wv   = tid >> 6;
    const int n    = lane & 31;
    const int q    = lane >> 5;
    const int y    = blockIdx.x;
    const int b    = blockIdx.y;

    for (int i = tid; i < 3 * 130 * 8; i += 256) {
        int r   = i / 1040;
        int rem = i - r * 1040;
        int xi  = rem >> 3;
        int g   = rem & 7;
        int yg = y + r - 1;
        int xg = xi - 1;
        uint4 v = make_uint4(0, 0, 0, 0);
        if (yg >= 0 && yg < 128 && xg >= 0 && xg < 128)
            v = *(const uint4*)(cat8t + (((size_t)(b * 128 + yg) * 128 + xg) * 64 + g * 8));
        *(uint4*)(&smem[((g * 3 + r) * 130 + xi) * 8]) = v;
    }
    __syncthreads();

    f32x16 acc;
#pragma unroll
    for (int i = 0; i < 16; ++i) acc[i] = 0.f;

    const int pxl = wv * 32 + n;
    const unsigned short* wbase = wpk8 + lane * 8;

#pragma unroll
    for (int s = 0; s < 9; ++s) {
        const int dy = s / 3, dx = s % 3;
        const int xi = pxl + dx;
#pragma unroll
        for (int kst = 0; kst < 4; ++kst) {
            const int g = kst * 2 + q;
            bf16x8 bfrag = *(const bf16x8*)(&smem[((g * 3 + dy) * 130 + xi) * 8]);
            bf16x8 a = *(const bf16x8*)(wbase + (s * 4 + kst) * 512);
            acc = __builtin_amdgcn_mfma_f32_32x32x16_bf16(a, bfrag, acc, 0, 0, 0);
        }
    }

    size_t base = ((size_t)(b * 128 + y) * 128 + pxl) * 32;
#pragma unroll
    for (int rg = 0; rg < 4; ++rg) {
        int oc0 = 8 * rg + 4 * q;
        unsigned short s0 = f2bf(fmaxf(acc[rg * 4 + 0] + bias[oc0 + 0], 0.f));
        unsigned short s1 = f2bf(fmaxf(acc[rg * 4 + 1] + bias[oc0 + 1], 0.f));
        unsigned short s2 = f2bf(fmaxf(acc[rg * 4 + 2] + bias[oc0 + 2], 0.f));
        unsigned short s3 = f2bf(fmaxf(acc[rg * 4 + 3] + bias[oc0 + 3], 0.f));
        *(uint2*)(x8t + base + oc0) = make_uint2(pack2(s0, s1), pack2(s2, s3));
    }
}

// ---------------------------------------------------------------------------
// conv9 MFMA: staging is pure COPY from x8u (pre-upsampled) + x1t (skip).
// K=48, 64 oc, tanh -> fm NCHW bf16.
// ---------------------------------------------------------------------------
__global__ __launch_bounds__(256)
void conv9f_mfma(const unsigned short* __restrict__ x8u,
                 const unsigned short* __restrict__ x1t,
                 const unsigned short* __restrict__ wpk,
                 const float* __restrict__ bias,
                 unsigned short* __restrict__ fm)
{
    __shared__ __align__(16) unsigned short smem[6 * 3 * 130 * 8];

    const int tid  = threadIdx.x;
    const int lane = tid & 63;
    const int wv   = tid >> 6;
    const int n    = lane & 31;
    const int q    = lane >> 5;
    const int y    = blockIdx.x >> 1;
    const int x0   = (blockIdx.x & 1) * 128;
    const int b    = blockIdx.y;

    for (int i = tid; i < 3 * 130 * 6; i += 256) {
        int r   = i / 780;
        int rem = i - r * 780;
        int xi  = rem / 6;
        int g   = rem - xi * 6;
        int yg = y + r - 1;
        int xg = x0 - 1 + xi;
        uint4 v = make_uint4(0, 0, 0, 0);
        if (yg >= 0 && yg < 256 && xg >= 0 && xg < 256) {
            if (g < 4)
                v = *(const uint4*)(x8u + (((size_t)(b * 256 + yg) * 256 + xg) * 32 + g * 8));
            else
                v = *(const uint4*)(x1t + (((size_t)(b * 256 + yg) * 256 + xg) * 16 + (g - 4) * 8));
        }
        *(uint4*)(&smem[((g * 3 + r) * 130 + xi) * 8]) = v;
    }
    __syncthreads();

    f32x16 acc0, acc1;
#pragma unroll
    for (int i = 0; i < 16; ++i) { acc0[i] = 0.f; acc1[i] = 0.f; }

    const int pxl = wv * 32 + n;
    const unsigned short* wbase = wpk + lane * 8;

#pragma unroll
    for (int s = 0; s < 9; ++s) {
        const int dy = s / 3, dx = s % 3;
        const int xi = pxl + dx;
#pragma unroll
        for (int kst = 0; kst < 3; ++kst) {
            const int g = kst * 2 + q;
            bf16x8 bfrag = *(const bf16x8*)(&smem[((g * 3 + dy) * 130 + xi) * 8]);
            bf16x8 a0 = *(const bf16x8*)(wbase + ((s * 3 + kst) * 2 + 0) * 512);
            bf16x8 a1 = *(const bf16x8*)(wbase + ((s * 3 + kst) * 2 + 1) * 512);
            acc0 = __builtin_amdgcn_mfma_f32_32x32x16_bf16(a0, bfrag, acc0, 0, 0, 0);
            acc1 = __builtin_amdgcn_mfma_f32_32x32x16_bf16(a1, bfrag, acc1, 0, 0, 0);
        }
    }

    const int px = x0 + pxl;
#pragma unroll
    for (int reg = 0; reg < 16; ++reg) {
        int row = (reg & 3) + 8 * (reg >> 2) + 4 * q;
        int oc0 = row, oc1 = 32 + row;
        fm[(((size_t)b * 64 + oc0) * 256 + y) * 256 + px] = f2bf(fast_tanh(acc0[reg] + bias[oc0]));
        fm[(((size_t)b * 64 + oc1) * 256 + y) * 256 + px] = f2bf(fast_tanh(acc1[reg] + bias[oc1]));
    }
}

// ---------------------------------------------------------------------------
// Segmented W-direction LRNN pair -> rnnW NCHW bf16.
// Bank-conflict fix: logical col x stored at x + (x>>5) -> banks differ
// by segment group. Output NCHW (coalesced 2B stores).
// ---------------------------------------------------------------------------
__device__ __forceinline__ int X2C(int x) { return x + (x >> 5); }

__global__ __launch_bounds__(256)
void lrnn_w_seg(const unsigned short* __restrict__ X, const unsigned short* __restrict__ FM,
                unsigned short* __restrict__ rnnW)
{
    __shared__ float tx[3][16][264];                 // 50688 B
    __shared__ unsigned short outm[2][16][256];      // 16384 B
    __shared__ float segres[2][16][8][4];
    __shared__ float hin[2][16][8][2];

    const int tid = threadIdx.x;
    const int bid = blockIdx.x;
    const int yt = bid & 15;
    const int c  = (bid >> 4) & 15;
    const int b  = bid >> 8;
    const int y0 = yt * 16;

    const size_t xb  = ((size_t)(b * 16 + c) * 256 + y0) * 256;
    const size_t p1b = ((size_t)(b * 64 + c) * 256 + y0) * 256;
    const size_t p2b = ((size_t)(b * 64 + 32 + c) * 256 + y0) * 256;

    for (int i = tid; i < 1536; i += 256) {
        int s = i >> 9;
        int r = i & 511;
        int y = r >> 5;
        int g = r & 31;
        const unsigned short* sp = (s == 0) ? (X + xb) : (s == 1 ? FM + p1b : FM + p2b);
        u16x8 v = *(const u16x8*)(sp + (size_t)y * 256 + g * 8);
        int c0 = X2C(g * 8);
#pragma unroll
        for (int j = 0; j < 8; ++j) tx[s][y][c0 + j] = bf2f(v[j]);
    }
    __syncthreads();

    const int y  = tid & 15;
    const int sg = (tid >> 4) & 7;
    const int d  = tid >> 7;

    {   // pass 1
        float h1 = 0.f, h2 = 0.f, A1 = 1.f, A2 = 1.f;
        if (d == 0) {
            int cs = X2C(sg * 32);
#pragma unroll
            for (int i = 0; i < 32; ++i) {
                float xv = tx[0][y][cs + i], p1 = tx[1][y][cs + i], p2 = tx[2][y][cs + i];
                h1 = fmaf(p1, h1 - xv, xv); A1 *= p1;
                h2 = fmaf(p2, h2 - xv, xv); A2 *= p2;
            }
        } else {
            int cs = X2C(255 - sg * 32);
#pragma unroll
            for (int i = 0; i < 32; ++i) {
                float xv = tx[0][y][cs - i], p1 = tx[1][y][cs - i], p2 = tx[2][y][cs - i];
                h1 = fmaf(p1, h1 - xv, xv); A1 *= p1;
                h2 = fmaf(p2, h2 - xv, xv); A2 *= p2;
            }
        }
        segres[d][y][sg][0] = h1; segres[d][y][sg][1] = A1;
        segres[d][y][sg][2] = h2; segres[d][y][sg][3] = A2;
    }
    __syncthreads();

    if (tid < 32) {
        int yy = tid & 15, dd = tid >> 4;
        float c1 = 0.f, c2 = 0.f;
        for (int s = 0; s < 8; ++s) {
            hin[dd][yy][s][0] = c1;
            hin[dd][yy][s][1] = c2;
            c1 = segres[dd][yy][s][0] + segres[dd][yy][s][1] * c1;
            c2 = segres[dd][yy][s][2] + segres[dd][yy][s][3] * c2;
        }
    }
    __syncthreads();

    {   // pass 2
        float h1 = hin[d][y][sg][0], h2 = hin[d][y][sg][1];
        if (d == 0) {
            int cs = X2C(sg * 32);
            int xs = sg * 32;
#pragma unroll
            for (int i = 0; i < 32; ++i) {
                float xv = tx[0][y][cs + i], p1 = tx[1][y][cs + i], p2 = tx[2][y][cs + i];
                h1 = fmaf(p1, h1 - xv, xv);
                h2 = fmaf(p2, h2 - xv, xv);
                outm[0][y][xs + i] = f2bf(fmaxf(h1, h2));
            }
        } else {
            int cs = X2C(255 - sg * 32);
#pragma unroll
            for (int i = 0; i < 32; ++i) {
                int t = sg * 32 + i;
                float xv = tx[0][y][cs - i], p1 = tx[1][y][cs - i], p2 = tx[2][y][cs - i];
                h1 = fmaf(p1, h1 - xv, xv);
                h2 = fmaf(p2, h2 - xv, xv);
                outm[1][y][t] = f2bf(fmaxf(h1, h2));
            }
        }
    }
    __syncthreads();

    // coalesced NCHW bf16 write
    for (int i = tid; i < 4096; i += 256) {
        int x = i & 255, yy = i >> 8;
        float m = fmaxf(bf2f(outm[0][yy][x]), bf2f(outm[1][yy][x]));
        rnnW[xb + (size_t)yy * 256 + x] = f2bf(m);
    }
}

// ---------------------------------------------------------------------------
// Segmented H-direction LRNN pair -> rnnH NCHW bf16.
// Bank-conflict fix: logical row y stored at y + (y>>5).
// ---------------------------------------------------------------------------
__global__ __launch_bounds__(256)
void lrnn_h_seg(const unsigned short* __restrict__ X, const unsigned short* __restrict__ FM,
                unsigned short* __restrict__ rnnH)
{
    __shared__ float tx[3][264][17];                 // 53856 B
    __shared__ unsigned short outm[2][256][16];      // 16384 B
    __shared__ float segres[2][16][8][4];
    __shared__ float hin[2][16][8][2];

    const int tid = threadIdx.x;
    const int bid = blockIdx.x;
    const int xt = bid & 15;
    const int c  = (bid >> 4) & 15;
    const int b  = bid >> 8;
    const int x0 = xt * 16;

    const size_t xb  = (size_t)(b * 16 + c) * 65536 + x0;
    const size_t p1b = (size_t)(b * 64 + 16 + c) * 65536 + x0;
    const size_t p2b = (size_t)(b * 64 + 48 + c) * 65536 + x0;

    for (int i = tid; i < 1536; i += 256) {
        int s = i >> 9;
        int r = i & 511;
        int y = r >> 1;
        int g = r & 1;
        const unsigned short* sp = (s == 0) ? (X + xb) : (s == 1 ? FM + p1b : FM + p2b);
        u16x8 v = *(const u16x8*)(sp + (size_t)y * 256 + g * 8);
        int pr = y + (y >> 5);
#pragma unroll
        for (int j = 0; j < 8; ++j) tx[s][pr][g * 8 + j] = bf2f(v[j]);
    }
    __syncthreads();

    const int x  = tid & 15;
    const int sg = (tid >> 4) & 7;
    const int d  = tid >> 7;

    {   // pass 1
        float h1 = 0.f, h2 = 0.f, A1 = 1.f, A2 = 1.f;
        if (d == 0) {
            int rs = X2C(sg * 32);
#pragma unroll
            for (int i = 0; i < 32; ++i) {
                float xv = tx[0][rs + i][x], p1 = tx[1][rs + i][x], p2 = tx[2][rs + i][x];
                h1 = fmaf(p1, h1 - xv, xv); A1 *= p1;
                h2 = fmaf(p2, h2 - xv, xv); A2 *= p2;
            }
        } else {
            int rs = X2C(255 - sg * 32);
#pragma unroll
            for (int i = 0; i < 32; ++i) {
                float xv = tx[0][rs - i][x], p1 = tx[1][rs - i][x], p2 = tx[2][rs - i][x];
                h1 = fmaf(p1, h1 - xv, xv); A1 *= p1;
                h2 = fmaf(p2, h2 - xv, xv); A2 *= p2;
            }
        }
        segres[d][x][sg][0] = h1; segres[d][x][sg][1] = A1;
        segres[d][x][sg][2] = h2; segres[d][x][sg][3] = A2;
    }
    __syncthreads();

    if (tid < 32) {
        int xx = tid & 15, dd = tid >> 4;
        float c1 = 0.f, c2 = 0.f;
        for (int s = 0; s < 8; ++s) {
            hin[dd][xx][s][0] = c1;
            hin[dd][xx][s][1] = c2;
            c1 = segres[dd][xx][s][0] + segres[dd][xx][s][1] * c1;
            c2 = segres[dd][xx][s][2] + segres[dd][xx][s][3] * c2;
        }
    }
    __syncthreads();

    {   // pass 2
        float h1 = hin[d][x][sg][0], h2 = hin[d][x][sg][1];
        if (d == 0) {
            int rs = X2C(sg * 32);
            int ys = sg * 32;
#pragma unroll
            for (int i = 0; i < 32; ++i) {
                float xv = tx[0][rs + i][x], p1 = tx[1][rs + i][x], p2 = tx[2][rs + i][x];
                h1 = fmaf(p1, h1 - xv, xv);
                h2 = fmaf(p2, h2 - xv, xv);
                outm[0][ys + i][x] = f2bf(fmaxf(h1, h2));
            }
        } else {
            int rs = X2C(255 - sg * 32);
#pragma unroll
            for (int i = 0; i < 32; ++i) {
                int t = sg * 32 + i;
                float xv = tx[0][rs - i][x], p1 = tx[1][rs - i][x], p2 = tx[2][rs - i][x];
                h1 = fmaf(p1, h1 - xv, xv);
                h2 = fmaf(p2, h2 - xv, xv);
                outm[1][t][x] = f2bf(fmaxf(h1, h2));
            }
        }
    }
    __syncthreads();

    // NCHW bf16 write (16-px contiguous chunks per row)
    for (int i = tid; i < 4096; i += 256) {
        int xx = i & 15, yy = i >> 4;
        float m = fmaxf(bf2f(outm[0][yy][xx]), bf2f(outm[1][yy][xx]));
        rnnH[xb + (size_t)yy * 256 + xx] = f2bf(m);
    }
}

// ---------------------------------------------------------------------------
// Output head MFMA: max(rnnW, rnnH) from NCHW bf16 -> 3x3 conv (Cin16,
// Cout3), sigmoid -> d_out NCHW fp32.
// ---------------------------------------------------------------------------
__global__ __launch_bounds__(256)
void convo_mfma(const unsigned short* __restrict__ rnnW,
                const unsigned short* __restrict__ rnnH,
                const unsigned short* __restrict__ wpko,
                const float* __restrict__ bo,
                float* __restrict__ outp)
{
    __shared__ __align__(16) unsigned short smem[2 * 3 * 130 * 8];

    const int tid  = threadIdx.x;
    const int lane = tid & 63;
    const int wv   = tid >> 6;
    const int n    = lane & 31;
    const int q    = lane >> 5;
    const int y    = blockIdx.x >> 1;
    const int x0   = (blockIdx.x & 1) * 128;
    const int b    = blockIdx.y;

    // stage from NCHW: i = ((r*16 + ch)*130 + xi), xi fastest -> coalesced 2B
    for (int i = tid; i < 3 * 16 * 130; i += 256) {
        int xi = i % 130;
        int t  = i / 130;
        int ch = t & 15;
        int r  = t >> 4;
        int yg = y + r - 1;
        int xg = x0 - 1 + xi;
        unsigned short m = 0;
        if (yg >= 0 && yg < 256 && xg >= 0 && xg < 256) {
            size_t off = (size_t)(b * 16 + ch) * 65536 + yg * 256 + xg;
            m = f2bf(fmaxf(bf2f(rnnW[off]), bf2f(rnnH[off])));
        }
        int g = ch >> 3, j = ch & 7;
        smem[((g * 3 + r) * 130 + xi) * 8 + j] = m;
    }
    __syncthreads();

    f32x16 acc;
#pragma unroll
    for (int i = 0; i < 16; ++i) acc[i] = 0.f;

    const int pxl = wv * 32 + n;
    const unsigned short* wbase = wpko + lane * 8;

#pragma unroll
    for (int s = 0; s < 9; ++s) {
        const int dy = s / 3, dx = s % 3;
        bf16x8 bfrag = *(const bf16x8*)(&smem[((q * 3 + dy) * 130 + pxl + dx) * 8]);
        bf16x8 a = *(const bf16x8*)(wbase + s * 512);
        acc = __builtin_amdgcn_mfma_f32_32x32x16_bf16(a, bfrag, acc, 0, 0, 0);
    }

    const int px = x0 + pxl;
    if (q == 0) {
#pragma unroll
        for (int oc = 0; oc < 3; ++oc) {
            float r = acc[oc] + bo[oc];
            outp[((size_t)(b * 3 + oc) * 256 + y) * 256 + px] = 1.f / (1.f + __expf(-r));
        }
    }
}

// ---------------------------------------------------------------------------
extern "C" void kernel_launch(void* const* d_in, const int* in_sizes, int n_in,
                              void* d_out, int out_size, void* d_ws, size_t ws_size,
                              hipStream_t stream)
{
    const float* img = (const float*)d_in[0];
    const float* w1 = (const float*)d_in[1];  const float* b1 = (const float*)d_in[2];
    const float* w2 = (const float*)d_in[3];  const float* b2 = (const float*)d_in[4];
    const float* w3 = (const float*)d_in[5];  const float* b3 = (const float*)d_in[6];
    const float* w4 = (const float*)d_in[7];  const float* b4 = (const float*)d_in[8];
    const float* w5 = (const float*)d_in[9];  const float* b5 = (const float*)d_in[10];
    const float* w6 = (const float*)d_in[11]; const float* b6 = (const float*)d_in[12];
    const float* w7 = (const float*)d_in[13]; const float* b7 = (const float*)d_in[14];
    const float* w8 = (const float*)d_in[15]; const float* b8 = (const float*)d_in[16];
    const float* w9 = (const float*)d_in[17]; const float* b9 = (const float*)d_in[18];
    const float* wi = (const float*)d_in[19]; const float* bi = (const float*)d_in[20];
    const float* wo = (const float*)d_in[21]; const float* bo = (const float*)d_in[22];

    char* wsb = (char*)d_ws;
    const size_t MB = (size_t)(1u << 20);
    // Layout (live-range-checked), peak 193 MiB:
    unsigned short* imgT  = (unsigned short*)(wsb);             // [0,16) dead after conv1i
    unsigned short* x1t   = (unsigned short*)(wsb + 16 * MB);   // [16,32) live till conv9f
    unsigned short* x2t   = (unsigned short*)(wsb + 32 * MB);   // [32,40) till cat8
    unsigned short* x3t   = (unsigned short*)(wsb + 40 * MB);   // [40,42) till cat7
    unsigned short* x4t   = (unsigned short*)(wsb + 42 * MB);   // [42,42.5) till cat6
    unsigned short* x5t   = (unsigned short*)(wsb + 43 * MB);   // [43,43.25)
    unsigned short* cat6t = (unsigned short*)(wsb + 44 * MB);   // [44,45.5)
    unsigned short* x6t   = (unsigned short*)(wsb + 46 * MB);   // [46,46.5)
    unsigned short* cat7t = (unsigned short*)(wsb + 47 * MB);   // [47,51)
    unsigned short* x7t   = (unsigned short*)(wsb + 51 * MB);   // [51,53)
    unsigned short* cat8t = (unsigned short*)(wsb + 54 * MB);   // [54,70)
    unsigned short* x8t   = (unsigned short*)(wsb + 70 * MB);   // [70,78)
    unsigned short* x8u   = (unsigned short*)(wsb + 78 * MB);   // [78,110) 32MB
    unsigned short* fm16  = (unsigned short*)(wsb + 112 * MB);  // [112,176) NCHW bf16
    unsigned short* xin16 = (unsigned short*)(wsb + 176 * MB);  // [176,192) NCHW bf16
    unsigned short* rnnW  = (unsigned short*)(wsb);             // [0,16)  (imgT dead)
    unsigned short* rnnH  = (unsigned short*)(wsb + 16 * MB);   // [16,32) (x1t dead)
    unsigned short* wpk9 = (unsigned short*)(wsb + 192 * MB);   // packs ~304 KB
    unsigned short* wpk8 = wpk9 + 27648;
    unsigned short* wpk1 = wpk8 + 18432;
    unsigned short* wpki = wpk1 + 12800;
    unsigned short* wpko = wpki + 4608;
    unsigned short* wpk2 = wpko + 4608;
    unsigned short* wpk3 = wpk2 + 4608;
    unsigned short* wpk4 = wpk3 + 9216;
    unsigned short* wpk5 = wpk4 + 9216;
    unsigned short* wpk6 = wpk5 + 18432;
    unsigned short* wpk7 = wpk6 + 27648;
    float* outp = (float*)d_out;

    // --- single weight-pack dispatch + img transpose ---
    wprep_mega<<<608, 256, 0, stream>>>(w9, w8, w1, wi, wo, w2, w3, w4, w5, w6, w7,
                                        wpk9, wpk8, wpk1, wpki, wpko,
                                        wpk2, wpk3, wpk4, wpk5, wpk6, wpk7);
    imgT_bf16<<<2048, 256, 0, stream>>>(img, imgT);

    // --- fused conv1 (relu -> x1t NHWC) + input projection (xin16 NCHW bf16) ---
    { dim3 grd(512, 8);
      conv1i_mfma<<<grd, 256, 0, stream>>>(imgT, wpk1, wpki, b1, bi, x1t, xin16); }

    // --- encoder: pools fused into conv staging ---
    convN_mfma<16, 32, 128, 128, 1, 1><<<dim3(128, 8), 256, 0, stream>>>(x1t, wpk2, b2, x2t);
    convN_mfma<32, 32, 64, 64, 2, 1><<<dim3(32, 8), 256, 0, stream>>>(x2t, wpk3, b3, x3t);
    convN_mfma<32, 32, 32, 32, 4, 1><<<dim3(8, 8), 256, 0, stream>>>(x3t, wpk4, b4, x4t);
    convN_mfma<32, 64, 16, 16, 8, 1><<<dim3(2, 8), 256, 0, stream>>>(x4t, wpk5, b5, x5t);

    // --- decoder (NHWC bf16) ---
    upcat_nhwc2<<<384, 256, 0, stream>>>(x5t, x4t, cat6t, 64, 32, 32, 32);
    convN_mfma<96, 32, 32, 32, 4, 0><<<dim3(8, 8), 256, 0, stream>>>(cat6t, wpk6, b6, x6t);
    upcat_nhwc2<<<1024, 256, 0, stream>>>(x6t, x3t, cat7t, 32, 32, 64, 64);
    convN_mfma<64, 32, 64, 64, 2, 0><<<dim3(32, 8), 256, 0, stream>>>(cat7t, wpk7, b7, x7t);
    upcat_nhwc2<<<4096, 256, 0, stream>>>(x7t, x2t, cat8t, 32, 32, 128, 128);
    { dim3 grd(128, 8);
      conv8_mfma<<<grd, 256, 0, stream>>>(cat8t, wpk8, b8, x8t); }

    // --- stage 9: upsample once, then copy-staged conv9 (fm NCHW bf16) ---
    upx8_kernel<<<8192, 256, 0, stream>>>(x8t, x8u);
    { dim3 grd(512, 8);
      conv9f_mfma<<<grd, 256, 0, stream>>>(x8u, x1t, wpk9, b9, fm16); }

    // --- spatial RNN: segmented scans (conflict-free LDS, NCHW outputs) ---
    lrnn_w_seg<<<2048, 256, 0, stream>>>(xin16, fm16, rnnW);
    lrnn_h_seg<<<2048, 256, 0, stream>>>(xin16, fm16, rnnH);

    // --- output head ---
    { dim3 grd(512, 8);
      convo_mfma<<<grd, 256, 0, stream>>>(rnnW, rnnH, wpko, bo, outp); }
}

// Round 12
// 407.245 us; speedup vs baseline: 5.7028x; 1.0266x over previous
//
#include <hip/hip_runtime.h>
#include <math.h>

typedef __attribute__((ext_vector_type(8)))  short bf16x8;
typedef __attribute__((ext_vector_type(8)))  unsigned short u16x8;
typedef __attribute__((ext_vector_type(16))) float f32x16;

__device__ __forceinline__ unsigned short f2bf(float f) {
    unsigned u = __float_as_uint(f);
    unsigned r = (u + 0x7FFFu + ((u >> 16) & 1u)) >> 16;
    return (unsigned short)r;
}
__device__ __forceinline__ float bf2f(unsigned short h) {
    return __uint_as_float(((unsigned)h) << 16);
}
__device__ __forceinline__ unsigned pack2(unsigned short a, unsigned short b) {
    return (unsigned)a | ((unsigned)b << 16);
}
__device__ __forceinline__ float fast_tanh(float x) {
    float e = __expf(2.f * x);
    return 1.f - 2.f / (e + 1.f);
}

__device__ __forceinline__ void bilin_setup(int y, int x, int Hi, int Wi,
                                            int& i00, int& i01, int& i10, int& i11,
                                            float& wy, float& wx)
{
    float fy = 0.5f * y - 0.25f;
    float fx = 0.5f * x - 0.25f;
    float y0f = floorf(fy), x0f = floorf(fx);
    wy = fy - y0f; wx = fx - x0f;
    int yA = (int)y0f, xA = (int)x0f;
    int yB = yA + 1, xB = xA + 1;
    yA = yA < 0 ? 0 : (yA > Hi - 1 ? Hi - 1 : yA);
    yB = yB < 0 ? 0 : (yB > Hi - 1 ? Hi - 1 : yB);
    xA = xA < 0 ? 0 : (xA > Wi - 1 ? Wi - 1 : xA);
    xB = xB < 0 ? 0 : (xB > Wi - 1 ? Wi - 1 : xB);
    i00 = yA * Wi + xA; i01 = yA * Wi + xB;
    i10 = yB * Wi + xA; i11 = yB * Wi + xB;
}

__device__ __forceinline__ u16x8 bilin8(const unsigned short* __restrict__ sb,
                                        int i00, int i01, int i10, int i11,
                                        float wy, float wx, int stride)
{
    u16x8 v00 = *(const u16x8*)(sb + (size_t)i00 * stride);
    u16x8 v01 = *(const u16x8*)(sb + (size_t)i01 * stride);
    u16x8 v10 = *(const u16x8*)(sb + (size_t)i10 * stride);
    u16x8 v11 = *(const u16x8*)(sb + (size_t)i11 * stride);
    float w00 = (1.f - wy) * (1.f - wx), w01 = (1.f - wy) * wx;
    float w10 = wy * (1.f - wx),         w11 = wy * wx;
    u16x8 r;
#pragma unroll
    for (int j = 0; j < 8; ++j)
        r[j] = f2bf(w00 * bf2f(v00[j]) + w01 * bf2f(v01[j]) +
                    w10 * bf2f(v10[j]) + w11 * bf2f(v11[j]));
    return r;
}

// ---------------------------------------------------------------------------
// NHWC bf16 upsample(2x) + concat (stage 8 only).
// ---------------------------------------------------------------------------
__global__ void upcat_nhwc2(const unsigned short* __restrict__ up,
                            const unsigned short* __restrict__ skip,
                            unsigned short* __restrict__ dst,
                            int C1, int C2, int H, int W)
{
    int C8 = (C1 + C2) >> 3;
    int idx = blockIdx.x * 256 + threadIdx.x;
    int total = 8 * H * W * C8;
    if (idx >= total) return;
    int g = idx % C8;
    int p = idx / C8;
    int x = p % W;
    int y = (p / W) % H;
    int b = p / (W * H);
    u16x8 r;
    if (g < (C1 >> 3)) {
        int Hi = H >> 1, Wi = W >> 1;
        int i00, i01, i10, i11; float wy, wx;
        bilin_setup(y, x, Hi, Wi, i00, i01, i10, i11, wy, wx);
        r = bilin8(up + (size_t)b * Hi * Wi * C1 + g * 8, i00, i01, i10, i11, wy, wx, C1);
    } else {
        r = *(const u16x8*)(skip + ((size_t)(b * H + y) * W + x) * C2 + (g - (C1 >> 3)) * 8);
    }
    *(u16x8*)(dst + (((size_t)(b * H + y) * W + x) * (C1 + C2) + g * 8)) = r;
}

// ---------------------------------------------------------------------------
// upx8: bilinear 2x upsample of x8t -> x8u NHWC bf16 [8,256,256,32].
// ---------------------------------------------------------------------------
__global__ void upx8_kernel(const unsigned short* __restrict__ x8t,
                            unsigned short* __restrict__ x8u)
{
    int idx = blockIdx.x * 256 + threadIdx.x;
    if (idx >= 8 * 256 * 256 * 4) return;
    int g = idx & 3;
    int p = idx >> 2;
    int x = p & 255, y = (p >> 8) & 255, b = p >> 16;
    int i00, i01, i10, i11; float wy, wx;
    bilin_setup(y, x, 128, 128, i00, i01, i10, i11, wy, wx);
    u16x8 r = bilin8(x8t + (size_t)b * 128 * 128 * 32 + g * 8, i00, i01, i10, i11, wy, wx, 32);
    *(u16x8*)(x8u + (size_t)idx * 8) = r;
}

// ---------------------------------------------------------------------------
// img [8][15][256][256] fp32 -> imgT [b][y][x][16] bf16 (ch15 = 0)
// ---------------------------------------------------------------------------
__global__ void imgT_bf16(const float* __restrict__ img, unsigned short* __restrict__ dst)
{
    int idx = blockIdx.x * 256 + threadIdx.x;
    if (idx >= 8 * 256 * 256) return;
    int x = idx & 255, y = (idx >> 8) & 255, b = idx >> 16;
    unsigned short v[16];
#pragma unroll
    for (int c = 0; c < 15; ++c)
        v[c] = f2bf(img[(size_t)(b * 15 + c) * 65536 + y * 256 + x]);
    v[15] = 0;
    uint4 lo = make_uint4(pack2(v[0], v[1]), pack2(v[2], v[3]), pack2(v[4], v[5]), pack2(v[6], v[7]));
    uint4 hi = make_uint4(pack2(v[8], v[9]), pack2(v[10], v[11]), pack2(v[12], v[13]), pack2(v[14], v[15]));
    *(uint4*)(dst + (size_t)idx * 16)     = lo;
    *(uint4*)(dst + (size_t)idx * 16 + 8) = hi;
}

// ---------------------------------------------------------------------------
// Mega weight-pack: all packs in one dispatch.
// ---------------------------------------------------------------------------
__device__ __forceinline__ void pack33(const float* __restrict__ w,
                                       unsigned short* __restrict__ dst,
                                       int i, int Cin, int Cout)
{
    int KST = Cin >> 4, MT = Cout >> 5;
    int j = i & 7;
    int lane = (i >> 3) & 63;
    int t = i >> 9;
    int mt = t % MT; t /= MT;
    int kst = t % KST;
    int s = t / KST;
    int oc = mt * 32 + (lane & 31);
    int ci = kst * 16 + (lane >> 5) * 8 + j;
    dst[i] = f2bf(w[(oc * Cin + ci) * 9 + s]);
}

__global__ void wprep_mega(const float* __restrict__ w9, const float* __restrict__ w8,
                           const float* __restrict__ w1, const float* __restrict__ wi,
                           const float* __restrict__ wo, const float* __restrict__ w2,
                           const float* __restrict__ w3, const float* __restrict__ w4,
                           const float* __restrict__ w5, const float* __restrict__ w6,
                           const float* __restrict__ w7,
                           unsigned short* __restrict__ wpk9, unsigned short* __restrict__ wpk8,
                           unsigned short* __restrict__ wpk1, unsigned short* __restrict__ wpki,
                           unsigned short* __restrict__ wpko, unsigned short* __restrict__ wpk2,
                           unsigned short* __restrict__ wpk3, unsigned short* __restrict__ wpk4,
                           unsigned short* __restrict__ wpk5, unsigned short* __restrict__ wpk6,
                           unsigned short* __restrict__ wpk7)
{
    int idx = blockIdx.x * 256 + threadIdx.x;
    if (idx < 27648)       pack33(w9, wpk9, idx, 48, 64);
    else if (idx < 46080)  pack33(w8, wpk8, idx - 27648, 64, 32);
    else if (idx < 58880) {
        int i = idx - 46080;
        int j = i & 7;
        int lane = (i >> 3) & 63;
        int s = i >> 9;                 // 0..24
        int oc = lane & 31;
        int ci = (lane >> 5) * 8 + j;   // 0..15
        float v = 0.f;
        if (oc < 16 && ci < 15) v = w1[((oc * 15 + ci) * 5 + s / 5) * 5 + s % 5];
        wpk1[i] = f2bf(v);
    } else if (idx < 63488) {
        int i = idx - 58880;
        int j = i & 7;
        int lane = (i >> 3) & 63;
        int s = i >> 9;                 // 0..8
        int oc = lane & 31;
        int ci = (lane >> 5) * 8 + j;
        float v = 0.f;
        if (oc < 16 && ci < 15) v = wi[((oc * 15 + ci) * 3 + s / 3) * 3 + s % 3];
        wpki[i] = f2bf(v);
    } else if (idx < 68096) {
        int i = idx - 63488;
        int j = i & 7;
        int lane = (i >> 3) & 63;
        int s = i >> 9;
        int oc = lane & 31;
        int ci = (lane >> 5) * 8 + j;
        float v = 0.f;
        if (oc < 3) v = wo[((oc * 16 + ci) * 3 + s / 3) * 3 + s % 3];
        wpko[i] = f2bf(v);
    }
    else if (idx < 72704)  pack33(w2, wpk2, idx - 68096, 16, 32);
    else if (idx < 81920)  pack33(w3, wpk3, idx - 72704, 32, 32);
    else if (idx < 91136)  pack33(w4, wpk4, idx - 81920, 32, 32);
    else if (idx < 109568) pack33(w5, wpk5, idx - 91136, 32, 64);
    else if (idx < 137216) pack33(w6, wpk6, idx - 109568, 96, 32);
    else if (idx < 155648) pack33(w7, wpk7, idx - 137216, 64, 32);
}

// ---------------------------------------------------------------------------
// Generic NHWC bf16 MFMA conv (3x3, pad 1, relu -> NHWC bf16).
// POOL=1: input is [8, 2H, 2W, CIN]; staging applies 2x2 maxpool on the fly.
// ---------------------------------------------------------------------------
template<int CIN, int COUT, int H, int W, int ROWS, int POOL>
__global__ __launch_bounds__(256)
void convN_mfma(const unsigned short* __restrict__ in,
                const unsigned short* __restrict__ wpk,
                const float* __restrict__ bias,
                unsigned short* __restrict__ out)
{
    constexpr int G = CIN / 8;
    constexpr int KST = CIN / 16;
    constexpr int MT = COUT / 32;
    constexpr int TR = ROWS + 2;
    constexpr int TWd = W + 2;
    constexpr int PS = TR * TWd * 8 + 8;
    __shared__ __align__(16) unsigned short smem[G * PS];

    const int tid  = threadIdx.x;
    const int lane = tid & 63;
    const int wv   = tid >> 6;
    const int q    = lane >> 5;
    const int y0   = blockIdx.x * ROWS;
    const int b    = blockIdx.y;

    for (int i = tid; i < G * TR * TWd; i += 256) {
        int g = i % G;
        int u = (i / G) % TWd;
        int t = i / (G * TWd);
        int yg = y0 + t - 1, xg = u - 1;
        u16x8 v = {0, 0, 0, 0, 0, 0, 0, 0};
        if (yg >= 0 && yg < H && xg >= 0 && xg < W) {
            if (POOL) {
                const unsigned short* q0 =
                    in + (((size_t)(b * 2 * H + 2 * yg) * 2 * W + 2 * xg) * CIN + g * 8);
                u16x8 a0 = *(const u16x8*)q0;
                u16x8 a1 = *(const u16x8*)(q0 + CIN);
                u16x8 a2 = *(const u16x8*)(q0 + (size_t)2 * W * CIN);
                u16x8 a3 = *(const u16x8*)(q0 + (size_t)2 * W * CIN + CIN);
#pragma unroll
                for (int j = 0; j < 8; ++j)
                    v[j] = f2bf(fmaxf(fmaxf(bf2f(a0[j]), bf2f(a1[j])),
                                      fmaxf(bf2f(a2[j]), bf2f(a3[j]))));
            } else {
                v = *(const u16x8*)(in + (((size_t)(b * H + yg) * W + xg) * CIN + g * 8));
            }
        }
        *(u16x8*)(&smem[g * PS + (t * TWd + u) * 8]) = v;
    }
    __syncthreads();

    const int p = wv * 32 + (lane & 31);
    const int r = p / W;
    const int x = p % W;

    f32x16 acc[MT];
#pragma unroll
    for (int mt = 0; mt < MT; ++mt)
#pragma unroll
        for (int i = 0; i < 16; ++i) acc[mt][i] = 0.f;

    const unsigned short* wbase = wpk + lane * 8;

#pragma unroll
    for (int s = 0; s < 9; ++s) {
        const int dy = s / 3, dx = s % 3;
#pragma unroll
        for (int kst = 0; kst < KST; ++kst) {
            const int g = kst * 2 + q;
            bf16x8 bfrag = *(const bf16x8*)(&smem[g * PS + ((r + dy) * TWd + (x + dx)) * 8]);
#pragma unroll
            for (int mt = 0; mt < MT; ++mt) {
                bf16x8 a = *(const bf16x8*)(wbase + ((s * KST + kst) * MT + mt) * 512);
                acc[mt] = __builtin_amdgcn_mfma_f32_32x32x16_bf16(a, bfrag, acc[mt], 0, 0, 0);
            }
        }
    }

    size_t base = ((size_t)(b * H + y0 + r) * W + x) * COUT;
#pragma unroll
    for (int mt = 0; mt < MT; ++mt)
#pragma unroll
        for (int rg = 0; rg < 4; ++rg) {
            int oc = mt * 32 + 8 * rg + 4 * q;
            unsigned short s0 = f2bf(fmaxf(acc[mt][rg * 4 + 0] + bias[oc + 0], 0.f));
            unsigned short s1 = f2bf(fmaxf(acc[mt][rg * 4 + 1] + bias[oc + 1], 0.f));
            unsigned short s2 = f2bf(fmaxf(acc[mt][rg * 4 + 2] + bias[oc + 2], 0.f));
            unsigned short s3 = f2bf(fmaxf(acc[mt][rg * 4 + 3] + bias[oc + 3], 0.f));
            *(uint2*)(out + base + oc) = make_uint2(pack2(s0, s1), pack2(s2, s3));
        }
}

// ---------------------------------------------------------------------------
// convU: 3x3 conv with FUSED upsample+concat staging (decoder stages 6,7).
// ---------------------------------------------------------------------------
template<int UPC, int CSKIP, int COUT, int H, int W, int ROWS>
__global__ __launch_bounds__(256)
void convU_mfma(const unsigned short* __restrict__ up,
                const unsigned short* __restrict__ skip,
                const unsigned short* __restrict__ wpk,
                const float* __restrict__ bias,
                unsigned short* __restrict__ out)
{
    constexpr int CIN = UPC + CSKIP;
    constexpr int G = CIN / 8;
    constexpr int GU = UPC / 8;
    constexpr int KST = CIN / 16;
    constexpr int MT = COUT / 32;
    constexpr int TR = ROWS + 2;
    constexpr int TWd = W + 2;
    constexpr int PS = TR * TWd * 8 + 8;
    __shared__ __align__(16) unsigned short smem[G * PS];

    const int tid  = threadIdx.x;
    const int lane = tid & 63;
    const int wv   = tid >> 6;
    const int q    = lane >> 5;
    const int y0   = blockIdx.x * ROWS;
    const int b    = blockIdx.y;

    for (int i = tid; i < G * TR * TWd; i += 256) {
        int g = i % G;
        int u = (i / G) % TWd;
        int t = i / (G * TWd);
        int yg = y0 + t - 1, xg = u - 1;
        u16x8 v = {0, 0, 0, 0, 0, 0, 0, 0};
        if (yg >= 0 && yg < H && xg >= 0 && xg < W) {
            if (g < GU) {
                int i00, i01, i10, i11; float wy, wx;
                bilin_setup(yg, xg, H / 2, W / 2, i00, i01, i10, i11, wy, wx);
                v = bilin8(up + (size_t)b * (H / 2) * (W / 2) * UPC + g * 8,
                           i00, i01, i10, i11, wy, wx, UPC);
            } else {
                v = *(const u16x8*)(skip + (((size_t)(b * H + yg) * W + xg) * CSKIP
                                            + (g - GU) * 8));
            }
        }
        *(u16x8*)(&smem[g * PS + (t * TWd + u) * 8]) = v;
    }
    __syncthreads();

    const int p = wv * 32 + (lane & 31);
    const int r = p / W;
    const int x = p % W;

    f32x16 acc[MT];
#pragma unroll
    for (int mt = 0; mt < MT; ++mt)
#pragma unroll
        for (int i = 0; i < 16; ++i) acc[mt][i] = 0.f;

    const unsigned short* wbase = wpk + lane * 8;

#pragma unroll
    for (int s = 0; s < 9; ++s) {
        const int dy = s / 3, dx = s % 3;
#pragma unroll
        for (int kst = 0; kst < KST; ++kst) {
            const int g = kst * 2 + q;
            bf16x8 bfrag = *(const bf16x8*)(&smem[g * PS + ((r + dy) * TWd + (x + dx)) * 8]);
#pragma unroll
            for (int mt = 0; mt < MT; ++mt) {
                bf16x8 a = *(const bf16x8*)(wbase + ((s * KST + kst) * MT + mt) * 512);
                acc[mt] = __builtin_amdgcn_mfma_f32_32x32x16_bf16(a, bfrag, acc[mt], 0, 0, 0);
            }
        }
    }

    size_t base = ((size_t)(b * H + y0 + r) * W + x) * COUT;
#pragma unroll
    for (int mt = 0; mt < MT; ++mt)
#pragma unroll
        for (int rg = 0; rg < 4; ++rg) {
            int oc = mt * 32 + 8 * rg + 4 * q;
            unsigned short s0 = f2bf(fmaxf(acc[mt][rg * 4 + 0] + bias[oc + 0], 0.f));
            unsigned short s1 = f2bf(fmaxf(acc[mt][rg * 4 + 1] + bias[oc + 1], 0.f));
            unsigned short s2 = f2bf(fmaxf(acc[mt][rg * 4 + 2] + bias[oc + 2], 0.f));
            unsigned short s3 = f2bf(fmaxf(acc[mt][rg * 4 + 3] + bias[oc + 3], 0.f));
            *(uint2*)(out + base + oc) = make_uint2(pack2(s0, s1), pack2(s2, s3));
        }
}

// ---------------------------------------------------------------------------
// Fused conv1 (5x5, relu -> x1t NHWC bf16) + conv_i (3x3 -> xin NCHW bf16).
// ---------------------------------------------------------------------------
__global__ __launch_bounds__(256)
void conv1i_mfma(const unsigned short* __restrict__ imgT,
                 const unsigned short* __restrict__ wpk1,
                 const unsigned short* __restrict__ wpki,
                 const float* __restrict__ b1, const float* __restrict__ bi,
                 unsigned short* __restrict__ x1t, unsigned short* __restrict__ xin)
{
    __shared__ __align__(16) unsigned short smem[2 * 5 * 132 * 8];

    const int tid  = threadIdx.x;
    const int lane = tid & 63;
    const int wv   = tid >> 6;
    const int n    = lane & 31;
    const int q    = lane >> 5;
    const int y    = blockIdx.x >> 1;
    const int x0   = (blockIdx.x & 1) * 128;
    const int b    = blockIdx.y;

    for (int i = tid; i < 5 * 132 * 2; i += 256) {
        int r   = i / 264;
        int rem = i - r * 264;
        int xi  = rem >> 1;
        int g   = rem & 1;
        int yg = y + r - 2;
        int xg = x0 - 2 + xi;
        uint4 v = make_uint4(0, 0, 0, 0);
        if (yg >= 0 && yg < 256 && xg >= 0 && xg < 256)
            v = *(const uint4*)(imgT + (((size_t)(b * 256 + yg) * 256 + xg) * 16 + g * 8));
        *(uint4*)(&smem[((g * 5 + r) * 132 + xi) * 8]) = v;
    }
    __syncthreads();

    f32x16 acc1, acci;
#pragma unroll
    for (int i = 0; i < 16; ++i) { acc1[i] = 0.f; acci[i] = 0.f; }

    const int pxl = wv * 32 + n;
    const unsigned short* wb1 = wpk1 + lane * 8;
    const unsigned short* wbi = wpki + lane * 8;

#pragma unroll
    for (int s = 0; s < 25; ++s) {
        const int dy = s / 5, dx = s % 5;
        bf16x8 bfrag = *(const bf16x8*)(&smem[((q * 5 + dy) * 132 + pxl + dx) * 8]);
        bf16x8 a = *(const bf16x8*)(wb1 + s * 512);
        acc1 = __builtin_amdgcn_mfma_f32_32x32x16_bf16(a, bfrag, acc1, 0, 0, 0);
    }
#pragma unroll
    for (int s = 0; s < 9; ++s) {
        const int dy = s / 3, dx = s % 3;
        bf16x8 bfrag = *(const bf16x8*)(&smem[((q * 5 + dy + 1) * 132 + pxl + dx + 1) * 8]);
        bf16x8 a = *(const bf16x8*)(wbi + s * 512);
        acci = __builtin_amdgcn_mfma_f32_32x32x16_bf16(a, bfrag, acci, 0, 0, 0);
    }

    const int px = x0 + pxl;
    size_t base1 = ((size_t)(b * 256 + y) * 256 + px) * 16;
#pragma unroll
    for (int rg = 0; rg < 2; ++rg) {
        int oc = 8 * rg + 4 * q;
        unsigned short s0 = f2bf(fmaxf(acc1[rg * 4 + 0] + b1[oc + 0], 0.f));
        unsigned short s1 = f2bf(fmaxf(acc1[rg * 4 + 1] + b1[oc + 1], 0.f));
        unsigned short s2 = f2bf(fmaxf(acc1[rg * 4 + 2] + b1[oc + 2], 0.f));
        unsigned short s3 = f2bf(fmaxf(acc1[rg * 4 + 3] + b1[oc + 3], 0.f));
        *(uint2*)(x1t + base1 + oc) = make_uint2(pack2(s0, s1), pack2(s2, s3));
    }
#pragma unroll
    for (int reg = 0; reg < 8; ++reg) {
        int row = (reg & 3) + 8 * (reg >> 2) + 4 * q;
        xin[((size_t)(b * 16 + row) * 256 + y) * 256 + px] = f2bf(acci[reg] + bi[row]);
    }
}

// ---------------------------------------------------------------------------
// conv8 MFMA: ROWS=2, 64-px strips. Cin=64, Cout=32, relu -> x8t NHWC bf16.
// ---------------------------------------------------------------------------
__global__ __launch_bounds__(256)
void conv8_mfma(const unsigned short* __restrict__ cat8t,
                const unsigned short* __restrict__ wpk8,
                const float* __restrict__ bias,
                unsigned short* __restrict__ x8t)
{
    __shared__ __align__(16) unsigned short smem[8 * 4 * 66 * 8];

    const int tid  = threadIdx.x;
    const int lane = tid & 63;
    const int wv   = tid >> 6;
    const int n    = lane & 31;
    const int q    = lane >> 5;
    const int x0   = (blockIdx.x & 1) * 64;
    const int yp   = blockIdx.x >> 1;       // 0..63
    const int b    = blockIdx.y;

    for (int i = tid; i < 8 * 4 * 66; i += 256) {
        int t   = i / 528;              // row 0..3
        int rem = i - t * 528;
        int xi  = rem >> 3;             // 0..65
        int g   = rem & 7;
        int yg = 2 * yp + t - 1;
        int xg = x0 - 1 + xi;
        uint4 v = make_uint4(0, 0, 0, 0);
        if (yg >= 0 && yg < 128 && xg >= 0 && xg < 128)
            v = *(const uint4*)(cat8t + (((size_t)(b * 128 + yg) * 128 + xg) * 64 + g * 8));
        *(uint4*)(&smem[((g * 4 + t) * 66 + xi) * 8]) = v;
    }
    __syncthreads();

    const int rr  = wv >> 1;
    const int pxl = (wv & 1) * 32 + n;

    f32x16 acc;
#pragma unroll
    for (int i = 0; i < 16; ++i) acc[i] = 0.f;

    const unsigned short* wbase = wpk8 + lane * 8;

#pragma unroll
    for (int s = 0; s < 9; ++s) {
        const int dy = s / 3, dx = s % 3;
#pragma unroll
        for (int kst = 0; kst < 4; ++kst) {
            const int g = kst * 2 + q;
            bf16x8 bfrag = *(const bf16x8*)(&smem[((g * 4 + rr + dy) * 66 + pxl + dx) * 8]);
            bf16x8 a = *(const bf16x8*)(wbase + (s * 4 + kst) * 512);
            acc = __builtin_amdgcn_mfma_f32_32x32x16_bf16(a, bfrag, acc, 0, 0, 0);
        }
    }

    size_t base = ((size_t)(b * 128 + 2 * yp + rr) * 128 + x0 + pxl) * 32;
#pragma unroll
    for (int rg = 0; rg < 4; ++rg) {
        int oc0 = 8 * rg + 4 * q;
        unsigned short s0 = f2bf(fmaxf(acc[rg * 4 + 0] + bias[oc0 + 0], 0.f));
        unsigned short s1 = f2bf(fmaxf(acc[rg * 4 + 1] + bias[oc0 + 1], 0.f));
        unsigned short s2 = f2bf(fmaxf(acc[rg * 4 + 2] + bias[oc0 + 2], 0.f));
        unsigned short s3 = f2bf(fmaxf(acc[rg * 4 + 3] + bias[oc0 + 3], 0.f));
        *(uint2*)(x8t + base + oc0) = make_uint2(pack2(s0, s1), pack2(s2, s3));
    }
}

// ---------------------------------------------------------------------------
// conv9 MFMA: ROWS=2, 64-px strips; staging pure copies from x8u + x1t.
// Grid must be 4 strips x 128 row-pairs = 512 blocks (R11 bug: was 1024,
// rows 256..511 overflowed into the next channel plane).
// ---------------------------------------------------------------------------
__global__ __launch_bounds__(256)
void conv9f_mfma(const unsigned short* __restrict__ x8u,
                 const unsigned short* __restrict__ x1t,
                 const unsigned short* __restrict__ wpk,
                 const float* __restrict__ bias,
                 unsigned short* __restrict__ fm)
{
    __shared__ __align__(16) unsigned short smem[6 * 4 * 66 * 8];

    const int tid  = threadIdx.x;
    const int lane = tid & 63;
    const int wv   = tid >> 6;
    const int n    = lane & 31;
    const int q    = lane >> 5;
    const int x0   = (blockIdx.x & 3) * 64;
    const int yp   = blockIdx.x >> 2;       // 0..127
    const int b    = blockIdx.y;

    for (int i = tid; i < 6 * 4 * 66; i += 256) {
        int t   = i / 396;              // row 0..3
        int rem = i - t * 396;
        int xi  = rem / 6;              // 0..65
        int g   = rem - xi * 6;
        int yg = 2 * yp + t - 1;
        int xg = x0 - 1 + xi;
        uint4 v = make_uint4(0, 0, 0, 0);
        if (yg >= 0 && yg < 256 && xg >= 0 && xg < 256) {
            if (g < 4)
                v = *(const uint4*)(x8u + (((size_t)(b * 256 + yg) * 256 + xg) * 32 + g * 8));
            else
                v = *(const uint4*)(x1t + (((size_t)(b * 256 + yg) * 256 + xg) * 16 + (g - 4) * 8));
        }
        *(uint4*)(&smem[((g * 4 + t) * 66 + xi) * 8]) = v;
    }
    __syncthreads();

    const int rr  = wv >> 1;
    const int pxl = (wv & 1) * 32 + n;

    f32x16 acc0, acc1;
#pragma unroll
    for (int i = 0; i < 16; ++i) { acc0[i] = 0.f; acc1[i] = 0.f; }

    const unsigned short* wbase = wpk + lane * 8;

#pragma unroll
    for (int s = 0; s < 9; ++s) {
        const int dy = s / 3, dx = s % 3;
#pragma unroll
        for (int kst = 0; kst < 3; ++kst) {
            const int g = kst * 2 + q;
            bf16x8 bfrag = *(const bf16x8*)(&smem[((g * 4 + rr + dy) * 66 + pxl + dx) * 8]);
            bf16x8 a0 = *(const bf16x8*)(wbase + ((s * 3 + kst) * 2 + 0) * 512);
            bf16x8 a1 = *(const bf16x8*)(wbase + ((s * 3 + kst) * 2 + 1) * 512);
            acc0 = __builtin_amdgcn_mfma_f32_32x32x16_bf16(a0, bfrag, acc0, 0, 0, 0);
            acc1 = __builtin_amdgcn_mfma_f32_32x32x16_bf16(a1, bfrag, acc1, 0, 0, 0);
        }
    }

    const int y  = 2 * yp + rr;
    const int px = x0 + pxl;
#pragma unroll
    for (int reg = 0; reg < 16; ++reg) {
        int row = (reg & 3) + 8 * (reg >> 2) + 4 * q;
        int oc0 = row, oc1 = 32 + row;
        fm[(((size_t)b * 64 + oc0) * 256 + y) * 256 + px] = f2bf(fast_tanh(acc0[reg] + bias[oc0]));
        fm[(((size_t)b * 64 + oc1) * 256 + y) * 256 + px] = f2bf(fast_tanh(acc1[reg] + bias[oc1]));
    }
}

// ---------------------------------------------------------------------------
// Segmented W-direction LRNN pair -> rnnW NCHW bf16 (conflict-free LDS).
// ---------------------------------------------------------------------------
__device__ __forceinline__ int X2C(int x) { return x + (x >> 5); }

__global__ __launch_bounds__(256)
void lrnn_w_seg(const unsigned short* __restrict__ X, const unsigned short* __restrict__ FM,
                unsigned short* __restrict__ rnnW)
{
    __shared__ float tx[3][16][264];
    __shared__ unsigned short outm[2][16][256];
    __shared__ float segres[2][16][8][4];
    __shared__ float hin[2][16][8][2];

    const int tid = threadIdx.x;
    const int bid = blockIdx.x;
    const int yt = bid & 15;
    const int c  = (bid >> 4) & 15;
    const int b  = bid >> 8;
    const int y0 = yt * 16;

    const size_t xb  = ((size_t)(b * 16 + c) * 256 + y0) * 256;
    const size_t p1b = ((size_t)(b * 64 + c) * 256 + y0) * 256;
    const size_t p2b = ((size_t)(b * 64 + 32 + c) * 256 + y0) * 256;

    for (int i = tid; i < 1536; i += 256) {
        int s = i >> 9;
        int r = i & 511;
        int y = r >> 5;
        int g = r & 31;
        const unsigned short* sp = (s == 0) ? (X + xb) : (s == 1 ? FM + p1b : FM + p2b);
        u16x8 v = *(const u16x8*)(sp + (size_t)y * 256 + g * 8);
        int c0 = X2C(g * 8);
#pragma unroll
        for (int j = 0; j < 8; ++j) tx[s][y][c0 + j] = bf2f(v[j]);
    }
    __syncthreads();

    const int y  = tid & 15;
    const int sg = (tid >> 4) & 7;
    const int d  = tid >> 7;

    {   // pass 1
        float h1 = 0.f, h2 = 0.f, A1 = 1.f, A2 = 1.f;
        if (d == 0) {
            int cs = X2C(sg * 32);
#pragma unroll
            for (int i = 0; i < 32; ++i) {
                float xv = tx[0][y][cs + i], p1 = tx[1][y][cs + i], p2 = tx[2][y][cs + i];
                h1 = fmaf(p1, h1 - xv, xv); A1 *= p1;
                h2 = fmaf(p2, h2 - xv, xv); A2 *= p2;
            }
        } else {
            int cs = X2C(255 - sg * 32);
#pragma unroll
            for (int i = 0; i < 32; ++i) {
                float xv = tx[0][y][cs - i], p1 = tx[1][y][cs - i], p2 = tx[2][y][cs - i];
                h1 = fmaf(p1, h1 - xv, xv); A1 *= p1;
                h2 = fmaf(p2, h2 - xv, xv); A2 *= p2;
            }
        }
        segres[d][y][sg][0] = h1; segres[d][y][sg][1] = A1;
        segres[d][y][sg][2] = h2; segres[d][y][sg][3] = A2;
    }
    __syncthreads();

    if (tid < 32) {
        int yy = tid & 15, dd = tid >> 4;
        float c1 = 0.f, c2 = 0.f;
        for (int s = 0; s < 8; ++s) {
            hin[dd][yy][s][0] = c1;
            hin[dd][yy][s][1] = c2;
            c1 = segres[dd][yy][s][0] + segres[dd][yy][s][1] * c1;
            c2 = segres[dd][yy][s][2] + segres[dd][yy][s][3] * c2;
        }
    }
    __syncthreads();

    {   // pass 2
        float h1 = hin[d][y][sg][0], h2 = hin[d][y][sg][1];
        if (d == 0) {
            int cs = X2C(sg * 32);
            int xs = sg * 32;
#pragma unroll
            for (int i = 0; i < 32; ++i) {
                float xv = tx[0][y][cs + i], p1 = tx[1][y][cs + i], p2 = tx[2][y][cs + i];
                h1 = fmaf(p1, h1 - xv, xv);
                h2 = fmaf(p2, h2 - xv, xv);
                outm[0][y][xs + i] = f2bf(fmaxf(h1, h2));
            }
        } else {
            int cs = X2C(255 - sg * 32);
#pragma unroll
            for (int i = 0; i < 32; ++i) {
                int t = sg * 32 + i;
                float xv = tx[0][y][cs - i], p1 = tx[1][y][cs - i], p2 = tx[2][y][cs - i];
                h1 = fmaf(p1, h1 - xv, xv);
                h2 = fmaf(p2, h2 - xv, xv);
                outm[1][y][t] = f2bf(fmaxf(h1, h2));
            }
        }
    }
    __syncthreads();

    for (int i = tid; i < 4096; i += 256) {
        int x = i & 255, yy = i >> 8;
        float m = fmaxf(bf2f(outm[0][yy][x]), bf2f(outm[1][yy][x]));
        rnnW[xb + (size_t)yy * 256 + x] = f2bf(m);
    }
}

// ---------------------------------------------------------------------------
// Segmented H-direction LRNN pair -> rnnH NCHW bf16 (conflict-free LDS).
// ---------------------------------------------------------------------------
__global__ __launch_bounds__(256)
void lrnn_h_seg(const unsigned short* __restrict__ X, const unsigned short* __restrict__ FM,
                unsigned short* __restrict__ rnnH)
{
    __shared__ float tx[3][264][17];
    __shared__ unsigned short outm[2][256][16];
    __shared__ float segres[2][16][8][4];
    __shared__ float hin[2][16][8][2];

    const int tid = threadIdx.x;
    const int bid = blockIdx.x;
    const int xt = bid & 15;
    const int c  = (bid >> 4) & 15;
    const int b  = bid >> 8;
    const int x0 = xt * 16;

    const size_t xb  = (size_t)(b * 16 + c) * 65536 + x0;
    const size_t p1b = (size_t)(b * 64 + 16 + c) * 65536 + x0;
    const size_t p2b = (size_t)(b * 64 + 48 + c) * 65536 + x0;

    for (int i = tid; i < 1536; i += 256) {
        int s = i >> 9;
        int r = i & 511;
        int y = r >> 1;
        int g = r & 1;
        const unsigned short* sp = (s == 0) ? (X + xb) : (s == 1 ? FM + p1b : FM + p2b);
        u16x8 v = *(const u16x8*)(sp + (size_t)y * 256 + g * 8);
        int pr = y + (y >> 5);
#pragma unroll
        for (int j = 0; j < 8; ++j) tx[s][pr][g * 8 + j] = bf2f(v[j]);
    }
    __syncthreads();

    const int x  = tid & 15;
    const int sg = (tid >> 4) & 7;
    const int d  = tid >> 7;

    {   // pass 1
        float h1 = 0.f, h2 = 0.f, A1 = 1.f, A2 = 1.f;
        if (d == 0) {
            int rs = X2C(sg * 32);
#pragma unroll
            for (int i = 0; i < 32; ++i) {
                float xv = tx[0][rs + i][x], p1 = tx[1][rs + i][x], p2 = tx[2][rs + i][x];
                h1 = fmaf(p1, h1 - xv, xv); A1 *= p1;
                h2 = fmaf(p2, h2 - xv, xv); A2 *= p2;
            }
        } else {
            int rs = X2C(255 - sg * 32);
#pragma unroll
            for (int i = 0; i < 32; ++i) {
                float xv = tx[0][rs - i][x], p1 = tx[1][rs - i][x], p2 = tx[2][rs - i][x];
                h1 = fmaf(p1, h1 - xv, xv); A1 *= p1;
                h2 = fmaf(p2, h2 - xv, xv); A2 *= p2;
            }
        }
        segres[d][x][sg][0] = h1; segres[d][x][sg][1] = A1;
        segres[d][x][sg][2] = h2; segres[d][x][sg][3] = A2;
    }
    __syncthreads();

    if (tid < 32) {
        int xx = tid & 15, dd = tid >> 4;
        float c1 = 0.f, c2 = 0.f;
        for (int s = 0; s < 8; ++s) {
            hin[dd][xx][s][0] = c1;
            hin[dd][xx][s][1] = c2;
            c1 = segres[dd][xx][s][0] + segres[dd][xx][s][1] * c1;
            c2 = segres[dd][xx][s][2] + segres[dd][xx][s][3] * c2;
        }
    }
    __syncthreads();

    {   // pass 2
        float h1 = hin[d][x][sg][0], h2 = hin[d][x][sg][1];
        if (d == 0) {
            int rs = X2C(sg * 32);
            int ys = sg * 32;
#pragma unroll
            for (int i = 0; i < 32; ++i) {
                float xv = tx[0][rs + i][x], p1 = tx[1][rs + i][x], p2 = tx[2][rs + i][x];
                h1 = fmaf(p1, h1 - xv, xv);
                h2 = fmaf(p2, h2 - xv, xv);
                outm[0][ys + i][x] = f2bf(fmaxf(h1, h2));
            }
        } else {
            int rs = X2C(255 - sg * 32);
#pragma unroll
            for (int i = 0; i < 32; ++i) {
                int t = sg * 32 + i;
                float xv = tx[0][rs - i][x], p1 = tx[1][rs - i][x], p2 = tx[2][rs - i][x];
                h1 = fmaf(p1, h1 - xv, xv);
                h2 = fmaf(p2, h2 - xv, xv);
                outm[1][t][x] = f2bf(fmaxf(h1, h2));
            }
        }
    }
    __syncthreads();

    for (int i = tid; i < 4096; i += 256) {
        int xx = i & 15, yy = i >> 4;
        float m = fmaxf(bf2f(outm[0][yy][xx]), bf2f(outm[1][yy][xx]));
        rnnH[xb + (size_t)yy * 256 + xx] = f2bf(m);
    }
}

// ---------------------------------------------------------------------------
// Output head MFMA: max(rnnW, rnnH) from NCHW bf16 -> 3x3 conv (Cin16,
// Cout3), sigmoid -> d_out NCHW fp32.
// ---------------------------------------------------------------------------
__global__ __launch_bounds__(256)
void convo_mfma(const unsigned short* __restrict__ rnnW,
                const unsigned short* __restrict__ rnnH,
                const unsigned short* __restrict__ wpko,
                const float* __restrict__ bo,
                float* __restrict__ outp)
{
    __shared__ __align__(16) unsigned short smem[2 * 3 * 130 * 8];

    const int tid  = threadIdx.x;
    const int lane = tid & 63;
    const int wv   = tid >> 6;
    const int n    = lane & 31;
    const int q    = lane >> 5;
    const int y    = blockIdx.x >> 1;
    const int x0   = (blockIdx.x & 1) * 128;
    const int b    = blockIdx.y;

    for (int i = tid; i < 3 * 16 * 130; i += 256) {
        int xi = i % 130;
        int t  = i / 130;
        int ch = t & 15;
        int r  = t >> 4;
        int yg = y + r - 1;
        int xg = x0 - 1 + xi;
        unsigned short m = 0;
        if (yg >= 0 && yg < 256 && xg >= 0 && xg < 256) {
            size_t off = (size_t)(b * 16 + ch) * 65536 + yg * 256 + xg;
            m = f2bf(fmaxf(bf2f(rnnW[off]), bf2f(rnnH[off])));
        }
        int g = ch >> 3, j = ch & 7;
        smem[((g * 3 + r) * 130 + xi) * 8 + j] = m;
    }
    __syncthreads();

    f32x16 acc;
#pragma unroll
    for (int i = 0; i < 16; ++i) acc[i] = 0.f;

    const int pxl = wv * 32 + n;
    const unsigned short* wbase = wpko + lane * 8;

#pragma unroll
    for (int s = 0; s < 9; ++s) {
        const int dy = s / 3, dx = s % 3;
        bf16x8 bfrag = *(const bf16x8*)(&smem[((q * 3 + dy) * 130 + pxl + dx) * 8]);
        bf16x8 a = *(const bf16x8*)(wbase + s * 512);
        acc = __builtin_amdgcn_mfma_f32_32x32x16_bf16(a, bfrag, acc, 0, 0, 0);
    }

    const int px = x0 + pxl;
    if (q == 0) {
#pragma unroll
        for (int oc = 0; oc < 3; ++oc) {
            float r = acc[oc] + bo[oc];
            outp[((size_t)(b * 3 + oc) * 256 + y) * 256 + px] = 1.f / (1.f + __expf(-r));
        }
    }
}

// ---------------------------------------------------------------------------
extern "C" void kernel_launch(void* const* d_in, const int* in_sizes, int n_in,
                              void* d_out, int out_size, void* d_ws, size_t ws_size,
                              hipStream_t stream)
{
    const float* img = (const float*)d_in[0];
    const float* w1 = (const float*)d_in[1];  const float* b1 = (const float*)d_in[2];
    const float* w2 = (const float*)d_in[3];  const float* b2 = (const float*)d_in[4];
    const float* w3 = (const float*)d_in[5];  const float* b3 = (const float*)d_in[6];
    const float* w4 = (const float*)d_in[7];  const float* b4 = (const float*)d_in[8];
    const float* w5 = (const float*)d_in[9];  const float* b5 = (const float*)d_in[10];
    const float* w6 = (const float*)d_in[11]; const float* b6 = (const float*)d_in[12];
    const float* w7 = (const float*)d_in[13]; const float* b7 = (const float*)d_in[14];
    const float* w8 = (const float*)d_in[15]; const float* b8 = (const float*)d_in[16];
    const float* w9 = (const float*)d_in[17]; const float* b9 = (const float*)d_in[18];
    const float* wi = (const float*)d_in[19]; const float* bi = (const float*)d_in[20];
    const float* wo = (const float*)d_in[21]; const float* bo = (const float*)d_in[22];

    char* wsb = (char*)d_ws;
    const size_t MB = (size_t)(1u << 20);
    unsigned short* imgT  = (unsigned short*)(wsb);             // [0,16) dead after conv1i
    unsigned short* x1t   = (unsigned short*)(wsb + 16 * MB);   // [16,32) till conv9f
    unsigned short* x2t   = (unsigned short*)(wsb + 32 * MB);   // [32,40) till cat8
    unsigned short* x3t   = (unsigned short*)(wsb + 40 * MB);   // [40,42) till conv7
    unsigned short* x4t   = (unsigned short*)(wsb + 42 * MB);   // [42,42.5) till conv6
    unsigned short* x5t   = (unsigned short*)(wsb + 43 * MB);   // [43,43.25)
    unsigned short* x6t   = (unsigned short*)(wsb + 46 * MB);   // [46,46.5)
    unsigned short* x7t   = (unsigned short*)(wsb + 51 * MB);   // [51,53)
    unsigned short* cat8t = (unsigned short*)(wsb + 54 * MB);   // [54,70)
    unsigned short* x8t   = (unsigned short*)(wsb + 70 * MB);   // [70,78)
    unsigned short* x8u   = (unsigned short*)(wsb + 78 * MB);   // [78,110) 32MB
    unsigned short* fm16  = (unsigned short*)(wsb + 112 * MB);  // [112,176) NCHW bf16
    unsigned short* xin16 = (unsigned short*)(wsb + 176 * MB);  // [176,192) NCHW bf16
    unsigned short* rnnW  = (unsigned short*)(wsb);             // [0,16)  (imgT dead)
    unsigned short* rnnH  = (unsigned short*)(wsb + 16 * MB);   // [16,32) (x1t dead)
    unsigned short* wpk9 = (unsigned short*)(wsb + 192 * MB);
    unsigned short* wpk8 = wpk9 + 27648;
    unsigned short* wpk1 = wpk8 + 18432;
    unsigned short* wpki = wpk1 + 12800;
    unsigned short* wpko = wpki + 4608;
    unsigned short* wpk2 = wpko + 4608;
    unsigned short* wpk3 = wpk2 + 4608;
    unsigned short* wpk4 = wpk3 + 9216;
    unsigned short* wpk5 = wpk4 + 9216;
    unsigned short* wpk6 = wpk5 + 18432;
    unsigned short* wpk7 = wpk6 + 27648;
    float* outp = (float*)d_out;

    // --- single weight-pack dispatch + img transpose ---
    wprep_mega<<<608, 256, 0, stream>>>(w9, w8, w1, wi, wo, w2, w3, w4, w5, w6, w7,
                                        wpk9, wpk8, wpk1, wpki, wpko,
                                        wpk2, wpk3, wpk4, wpk5, wpk6, wpk7);
    imgT_bf16<<<2048, 256, 0, stream>>>(img, imgT);

    // --- fused conv1 (relu -> x1t NHWC) + input projection (xin16 NCHW bf16) ---
    { dim3 grd(512, 8);
      conv1i_mfma<<<grd, 256, 0, stream>>>(imgT, wpk1, wpki, b1, bi, x1t, xin16); }

    // --- encoder: pools fused into conv staging ---
    convN_mfma<16, 32, 128, 128, 1, 1><<<dim3(128, 8), 256, 0, stream>>>(x1t, wpk2, b2, x2t);
    convN_mfma<32, 32, 64, 64, 2, 1><<<dim3(32, 8), 256, 0, stream>>>(x2t, wpk3, b3, x3t);
    convN_mfma<32, 32, 32, 32, 4, 1><<<dim3(8, 8), 256, 0, stream>>>(x3t, wpk4, b4, x4t);
    convN_mfma<32, 64, 16, 16, 8, 1><<<dim3(2, 8), 256, 0, stream>>>(x4t, wpk5, b5, x5t);

    // --- decoder: upcat fused into conv6/conv7 staging ---
    convU_mfma<64, 32, 32, 32, 32, 4><<<dim3(8, 8), 256, 0, stream>>>(x5t, x4t, wpk6, b6, x6t);
    convU_mfma<32, 32, 32, 64, 64, 2><<<dim3(32, 8), 256, 0, stream>>>(x6t, x3t, wpk7, b7, x7t);
    upcat_nhwc2<<<4096, 256, 0, stream>>>(x7t, x2t, cat8t, 32, 32, 128, 128);
    { dim3 grd(128, 8);
      conv8_mfma<<<grd, 256, 0, stream>>>(cat8t, wpk8, b8, x8t); }

    // --- stage 9: upsample once, then copy-staged ROWS=2 conv9 (512 blocks!) ---
    upx8_kernel<<<8192, 256, 0, stream>>>(x8t, x8u);
    { dim3 grd(512, 8);
      conv9f_mfma<<<grd, 256, 0, stream>>>(x8u, x1t, wpk9, b9, fm16); }

    // --- spatial RNN: segmented scans ---
    lrnn_w_seg<<<2048, 256, 0, stream>>>(xin16, fm16, rnnW);
    lrnn_h_seg<<<2048, 256, 0, stream>>>(xin16, fm16, rnnH);

    // --- output head ---
    { dim3 grd(512, 8);
      convo_mfma<<<grd, 256, 0, stream>>>(rnnW, rnnH, wpko, bo, outp); }
}